// Round 5
// baseline (1005.976 us; speedup 1.0000x reference)
//
#include <hip/hip_runtime.h>

typedef unsigned short ushort_t;
typedef unsigned int uint_t;
typedef __attribute__((ext_vector_type(8))) short v8s;   // 8 bf16 MFMA A/B frag
typedef __attribute__((ext_vector_type(4))) float v4f;   // MFMA C/D frag
typedef __attribute__((ext_vector_type(2))) float v2f;   // packed f32 pair

#define HD 128
#define LSTR 136
#define MFMA16(a, b, c) __builtin_amdgcn_mfma_f32_16x16x32_bf16((a), (b), (c), 0, 0, 0)

__device__ __forceinline__ float b2f(ushort_t u) {
    union { uint_t i; float f; } v; v.i = ((uint_t)u) << 16; return v.f;
}
__device__ __forceinline__ ushort_t f2b(float f) {
    union { float f; uint_t i; } v; v.f = f;
    uint_t u = v.i;
    return (ushort_t)((u + 0x7FFFu + ((u >> 16) & 1u)) >> 16);
}
__device__ __forceinline__ v2f b2f2(uint_t u) {
    union { uint_t i; float f; } lo, hi;
    lo.i = u << 16; hi.i = u & 0xFFFF0000u;
    v2f r; r.x = lo.f; r.y = hi.f; return r;
}

// ================= CSR build =================

__global__ __launch_bounds__(256) void k_hist(const int* __restrict__ ids,
        int* __restrict__ deg, int M, int stride) {
    int i = blockIdx.x * blockDim.x + threadIdx.x;
    if (i >= M) return;
    int id = ids[(size_t)i * stride];
    if (id >= 0) atomicAdd(&deg[id], 1);
}

__device__ __forceinline__ void scan_map(int b, int T0, int TN, int& a, int& t) {
    if (b < T0) { a = 0; t = b; }
    else { int r = b - T0; a = 1 + r / TN; t = r % TN; }
}

__global__ __launch_bounds__(1024) void k_scan_up(
        const int* d0, const int* d1, const int* d2, const int* d3,
        int* s0, int* s1, int* s2, int* s3,
        int* __restrict__ tsum, int T0, int TN, int nSK, int nN) {
    int a, t;
    scan_map(blockIdx.x, T0, TN, a, t);
    const int* d = (a == 0) ? d0 : (a == 1) ? d1 : (a == 2) ? d2 : d3;
    int* s = (a == 0) ? s0 : (a == 1) ? s1 : (a == 2) ? s2 : s3;
    int n = (a == 0) ? nSK : nN;
    __shared__ int wsum[16];
    int tdx = threadIdx.x, lane = tdx & 63, wv = tdx >> 6;
    int i = t * 1024 + tdx;
    int v = (i < n) ? d[i] : 0;
    int x = v;
    #pragma unroll
    for (int off = 1; off < 64; off <<= 1) {
        int y = __shfl_up(x, off);
        if (lane >= off) x += y;
    }
    if (lane == 63) wsum[wv] = x;
    __syncthreads();
    int wo = 0, tot = 0;
    #pragma unroll
    for (int ww = 0; ww < 16; ++ww) {
        int sv = wsum[ww];
        if (ww < wv) wo += sv;
        tot += sv;
    }
    if (i < n) s[i] = wo + (x - v);
    if (tdx == 0) tsum[a * 128 + t] = tot;
}

__global__ __launch_bounds__(256) void k_scan_mid(
        const int* __restrict__ tsum, int* __restrict__ toff,
        int* s0, int* s1, int* s2, int* s3, int T0, int TN, int nSK, int nN) {
    int a = threadIdx.x >> 6, lane = threadIdx.x & 63;
    int T = (a == 0) ? T0 : TN;
    const int* ts = tsum + a * 128;
    int* to = toff + a * 128;
    int carry = 0;
    for (int base = 0; base < T; base += 64) {
        int idx = base + lane;
        int v = (idx < T) ? ts[idx] : 0;
        int x = v;
        #pragma unroll
        for (int off = 1; off < 64; off <<= 1) {
            int y = __shfl_up(x, off);
            if (lane >= off) x += y;
        }
        if (idx < T) to[idx] = carry + (x - v);
        carry += __shfl(x, 63);
    }
    if (lane == 0) {
        int* s = (a == 0) ? s0 : (a == 1) ? s1 : (a == 2) ? s2 : s3;
        s[(a == 0) ? nSK : nN] = carry;
    }
}

__global__ __launch_bounds__(1024) void k_scan_down(
        int* s0, int* s1, int* s2, int* s3,
        const int* __restrict__ toff, int T0, int TN, int nSK, int nN) {
    int a, t;
    scan_map(blockIdx.x, T0, TN, a, t);
    int* s = (a == 0) ? s0 : (a == 1) ? s1 : (a == 2) ? s2 : s3;
    int n = (a == 0) ? nSK : nN;
    int i = t * 1024 + threadIdx.x;
    if (i < n) s[i] += toff[a * 128 + t];
}

__global__ __launch_bounds__(256) void k_fill(const int* __restrict__ ids,
        const int* __restrict__ start, int* __restrict__ cursor,
        int* __restrict__ slots, int M, int stride) {
    int i = blockIdx.x * blockDim.x + threadIdx.x;
    if (i >= M) return;
    int id = ids[(size_t)i * stride];
    if (id < 0) return;
    int pos = start[id] + atomicAdd(&cursor[id], 1);
    slots[pos] = i * stride;
}

__global__ __launch_bounds__(256) void k_fill_edges(const int* __restrict__ dst,
        const int* __restrict__ src, const int* __restrict__ bids,
        const int* __restrict__ start, int* __restrict__ cursor,
        int* __restrict__ slots, int E) {
    int e = blockIdx.x * blockDim.x + threadIdx.x;
    if (e >= E) return;
    int d = dst[e];
    if (d < 0) return;
    int pos = start[d] + atomicAdd(&cursor[d], 1);
    slots[pos] = src[e] | (bids[e] << 20);
}

__global__ __launch_bounds__(256) void k_gstart(const int* __restrict__ batch,
        int* __restrict__ gs, int N, int G) {
    int n = blockIdx.x * blockDim.x + threadIdx.x;
    if (n > N) return;
    int bn = (n < N) ? batch[n] : G;
    int bp = (n == 0) ? -1 : batch[n - 1];
    for (int g = bp + 1; g <= bn; ++g)
        if (g <= G) gs[g] = n;
}

// ================= weight/bias prep =================

__global__ __launch_bounds__(256) void k_convert_w(
        const float* lW1, const float* lW2, const float* gW1, const float* gW2,
        const float* skipW, const float* vvW, const float* kkW,
        const float* lbn_g, const float* gbn_g,
        ushort_t* __restrict__ wbuf, int L) {
    int idx = blockIdx.x * blockDim.x + threadIdx.x;
    int total = 7 * L * 16384;
    if (idx >= total) return;
    int fam = idx / (L * 16384);
    int r = idx % (L * 16384);
    int l = r / 16384, e = r % 16384, n = e / 128;
    const float* src;
    float sc = 1.0f;
    switch (fam) {
        case 0: src = lW1; break;
        case 1: src = lW2; sc = lbn_g[l * 128 + n]; break;
        case 2: src = gW1; break;
        case 3: src = gW2; sc = gbn_g[l * 128 + n]; break;
        case 4: src = skipW; break;
        case 5: src = vvW; break;
        default: src = kkW; break;
    }
    wbuf[idx] = f2b(src[(size_t)l * 16384 + e] * sc);
}

__global__ __launch_bounds__(256) void k_bias(
        const float* lb2, const float* lbn_g, const float* lbn_b,
        const float* skipb, const float* vvb, const float* kkb,
        const float* gb2, const float* gbn_g, const float* gbn_b,
        float* __restrict__ cb, float* __restrict__ b2g, int total) {
    int i = blockIdx.x * blockDim.x + threadIdx.x;
    if (i >= total) return;
    cb[i] = lb2[i] * lbn_g[i] + lbn_b[i] + skipb[i] + vvb[i] + kkb[i];
    b2g[i] = gb2[i] * gbn_g[i] + gbn_b[i];
}

// extended bond table: rows 0-15 = f32 copy, row 16 = -1e30 (relu kill row)
__global__ __launch_bounds__(256) void k_btabx(const float* __restrict__ bt,
        float* __restrict__ btx, int nreal) {
    int i = blockIdx.x * blockDim.x + threadIdx.x;
    if (i >= nreal + HD) return;
    btx[i] = (i < nreal) ? bt[i] : -1e30f;
}

// ================= elementwise =================

__global__ __launch_bounds__(256) void k_vf(const int* __restrict__ node_ids,
        float* __restrict__ vf, int SK) {
    int i = blockIdx.x * blockDim.x + threadIdx.x;
    if (i < SK) vf[i] = (node_ids[i] >= 0) ? 1.0f : 0.0f;
}

__global__ __launch_bounds__(256) void k_init_h(const float* __restrict__ at,
        const float* __restrict__ rt, const int* __restrict__ atom_ids,
        const float* __restrict__ vf, ushort_t* __restrict__ h, int SK) {
    int t = blockIdx.x * blockDim.x + threadIdx.x;
    int i = t >> 6, lane = t & 63;
    if (i >= SK) return;
    float2 a = ((const float2*)(at + (size_t)atom_ids[i] * HD))[lane];
    int role = ((i & 15) == 0) ? 1 : 0;
    float2 r = ((const float2*)(rt + (size_t)role * HD))[lane];
    float m = vf[i];
    uint_t o = (uint_t)f2b((a.x + r.x) * m) | ((uint_t)f2b((a.y + r.y) * m) << 16);
    *(uint_t*)(h + (size_t)i * HD + lane * 2) = o;
}

// ---- R4: single-row scalar-walk (R2 shape) + one masked batch per row.
//      Fixed-width batch (BATCH per stream, sized to degree dist); fake edges
//      clamp slot to last real edge; their contribution is killed via LDS btab
//      row 16 (-1e30, relu->0) or zero row X[SK] (segmean). Bond table lives
//      entirely in LDS (8.7 KB) -> bond reads leave the vmem/vmcnt path. ----

template<int BATCH>
__device__ __forceinline__ void gine_row_b(const char* __restrict__ Xb,
        const float* __restrict__ Lq, const int* __restrict__ slots,
        int s0, int s1, int row, char* __restrict__ outz,
        uint_t xo, uint_t lane2) {
    const v2f z = {0.f, 0.f};
    v2f a = z;
    int p = s0;
    while (p < s1) {
        int c = s1 - p;
        int e[BATCH];
        #pragma unroll
        for (int j = 0; j < BATCH; ++j)
            e[j] = slots[(j < c) ? (p + j) : (s1 - 1)];
        uint_t u[BATCH];
        #pragma unroll
        for (int j = 0; j < BATCH; ++j)
            u[j] = *(const uint_t*)(Xb + (((uint_t)(e[j] & 0xFFFFF)) << 8) + xo);
        #pragma unroll
        for (int j = 0; j < BATCH; ++j) {
            uint_t brow = (j < c) ? ((uint_t)e[j] >> 20) : 16u;
            float2 q = *(const float2*)(Lq + brow * 128u + lane2);
            v2f qv; qv.x = q.x; qv.y = q.y;
            a += __builtin_elementwise_max(b2f2(u[j]) + qv, z);
        }
        p += BATCH;
    }
    uint_t su = *(const uint_t*)(Xb + (((uint_t)row) << 8) + xo);
    v2f o = b2f2(su) + a;
    *(uint_t*)(outz + (((uint_t)row) << 8) + xo) =
        (uint_t)f2b(o.x) | ((uint_t)f2b(o.y) << 16);
}

template<int BATCH>
__device__ __forceinline__ void segmean_row_b(const char* __restrict__ Xb,
        const int* __restrict__ slots, int s0, int s1, int row, int ZR,
        char* __restrict__ out, uint_t xo) {
    float inv = 1.0f / fmaxf((float)(s1 - s0), 1.0f);
    v2f a = {0.f, 0.f};
    int p = s0;
    while (p < s1) {
        int c = s1 - p;
        int r[BATCH];
        #pragma unroll
        for (int j = 0; j < BATCH; ++j) {
            int rv = slots[(j < c) ? (p + j) : (s1 - 1)];
            r[j] = (j < c) ? rv : ZR;
        }
        uint_t u[BATCH];
        #pragma unroll
        for (int j = 0; j < BATCH; ++j)
            u[j] = *(const uint_t*)(Xb + (((uint_t)r[j]) << 8) + xo);
        #pragma unroll
        for (int j = 0; j < BATCH; ++j)
            a += b2f2(u[j]);
        p += BATCH;
    }
    *(uint_t*)(out + (((uint_t)row) << 8) + xo) =
        (uint_t)f2b(a.x * inv) | ((uint_t)f2b(a.y * inv) << 16);
}

// combined: waves [0,SK) intra-GINE; [SK,SK+N) node segmean; [SK+N,SK+2N) root segmean
__global__ __launch_bounds__(256) void k_gather_all5(const ushort_t* __restrict__ X,
        const float* __restrict__ btabx,
        const int* __restrict__ startI, const int* __restrict__ slotI,
        ushort_t* __restrict__ outz, int SK,
        const int* __restrict__ startN, const int* __restrict__ slotN,
        ushort_t* __restrict__ nmean,
        const int* __restrict__ startR, const int* __restrict__ slotR,
        ushort_t* __restrict__ rootm, int N) {
    __shared__ float sQ[17 * HD];
    for (int i = threadIdx.x; i < 17 * HD / 4; i += 256)
        ((float4*)sQ)[i] = ((const float4*)btabx)[i];
    __syncthreads();
    int w = __builtin_amdgcn_readfirstlane((blockIdx.x * 256 + threadIdx.x) >> 6);
    uint_t lane = threadIdx.x & 63;
    uint_t xo = lane * 4u, lane2 = lane * 2u;
    const char* Xb = (const char*)X;
    if (w < SK) {
        gine_row_b<8>(Xb, sQ, slotI, startI[w], startI[w + 1], w,
                      (char*)outz, xo, lane2);
    } else if (w < SK + N) {
        int r = w - SK;
        segmean_row_b<4>(Xb, slotN, startN[r], startN[r + 1], r, SK,
                         (char*)nmean, xo);
    } else if (w < SK + 2 * N) {
        int r = w - SK - N;
        segmean_row_b<2>(Xb, slotR, startR[r], startR[r + 1], r, SK,
                         (char*)rootm, xo);
    }
}

__global__ __launch_bounds__(256) void k_gine_z5(const ushort_t* __restrict__ X,
        const float* __restrict__ btabx, const int* __restrict__ start,
        const int* __restrict__ slots, ushort_t* __restrict__ outz, int Nrows) {
    __shared__ float sQ[17 * HD];
    for (int i = threadIdx.x; i < 17 * HD / 4; i += 256)
        ((float4*)sQ)[i] = ((const float4*)btabx)[i];
    __syncthreads();
    int w = __builtin_amdgcn_readfirstlane((blockIdx.x * 256 + threadIdx.x) >> 6);
    if (w >= Nrows) return;
    uint_t lane = threadIdx.x & 63;
    gine_row_b<16>((const char*)X, sQ, slots, start[w], start[w + 1], w,
                   (char*)outz, lane * 4u, lane * 2u);
}

__global__ __launch_bounds__(256) void k_segmean5(const ushort_t* __restrict__ X,
        const int* __restrict__ start, const int* __restrict__ slots,
        ushort_t* __restrict__ out, int Nrows, int ZR) {
    int w = __builtin_amdgcn_readfirstlane((blockIdx.x * 256 + threadIdx.x) >> 6);
    if (w >= Nrows) return;
    uint_t lane = threadIdx.x & 63;
    segmean_row_b<4>((const char*)X, slots, start[w], start[w + 1], w, ZR,
                     (char*)out, lane * 4u);
}

// sorted-batch pool: one block per group, contiguous node range, no atomics
__global__ __launch_bounds__(256) void k_pool2(const ushort_t* __restrict__ xsum,
        const int* __restrict__ gs, float* __restrict__ out) {
    int g = blockIdx.x;
    int t = threadIdx.x, wv = t >> 6, lane = t & 63;
    int n0 = gs[g], n1 = gs[g + 1];
    float a0 = 0.f, a1 = 0.f;
    for (int n = n0 + wv; n < n1; n += 4) {
        uint_t u = *(const uint_t*)(xsum + (size_t)n * HD + lane * 2);
        a0 += b2f((ushort_t)(u & 0xFFFF));
        a1 += b2f((ushort_t)(u >> 16));
    }
    __shared__ float red[4][128];
    red[wv][lane * 2] = a0;
    red[wv][lane * 2 + 1] = a1;
    __syncthreads();
    if (wv == 0) {
        float s0 = red[0][lane * 2] + red[1][lane * 2]
                 + red[2][lane * 2] + red[3][lane * 2];
        float s1 = red[0][lane * 2 + 1] + red[1][lane * 2 + 1]
                 + red[2][lane * 2 + 1] + red[3][lane * 2 + 1];
        *(float2*)(out + (size_t)g * HD + lane * 2) = make_float2(s0, s1);
    }
}

// ---- stage one 128x128 bf16 weight into padded LDS (R9 champion form) ----
__device__ __forceinline__ void stage_w(ushort_t* Wl, const ushort_t* Wb, int t) {
    #pragma unroll
    for (int it = 0; it < 8; ++it) {
        int idx = it * 256 + t;
        uint4 v = *(const uint4*)(Wb + (size_t)idx * 8);
        int row = idx >> 4, col = (idx & 15) * 8;
        *(uint4*)&Wl[row * LSTR + col] = v;
    }
}

// ================= GEMM: C = maybe_relu(A @ W^T + bias) =================
__global__ __launch_bounds__(256) void k_gemm1(const ushort_t* __restrict__ A,
        const ushort_t* __restrict__ Wb, const float* __restrict__ bias,
        ushort_t* __restrict__ C, int M, int relu_flag) {
    __shared__ ushort_t Wl[128 * LSTR];
    const int t = threadIdx.x;
    stage_w(Wl, Wb, t);
    int lane = t & 63, wave = t >> 6;
    int m = lane & 15, quad = lane >> 4;
    int row = blockIdx.x * 64 + wave * 16 + m;
    int ar = row < M ? row : M - 1;
    const v8s* Ar = (const v8s*)(A + (size_t)ar * HD);
    v8s bfrag[4];
    #pragma unroll
    for (int c = 0; c < 4; ++c) bfrag[c] = Ar[c * 4 + quad];
    __syncthreads();
    v4f acc[8];
    #pragma unroll
    for (int nt = 0; nt < 8; ++nt) acc[nt] = (v4f){0.f, 0.f, 0.f, 0.f};
    #pragma unroll
    for (int nt = 0; nt < 8; ++nt) {
        #pragma unroll
        for (int c = 0; c < 4; ++c) {
            v8s wf = *(const v8s*)&Wl[(nt * 16 + m) * LSTR + c * 32 + quad * 8];
            acc[nt] = MFMA16(wf, bfrag[c], acc[nt]);
        }
    }
    if (row < M) {
        ushort_t* Cr = C + (size_t)row * HD;
        #pragma unroll
        for (int nt = 0; nt < 8; ++nt) {
            int col = nt * 16 + quad * 4;
            float4 b = *(const float4*)(bias + col);
            float v0 = acc[nt][0] + b.x, v1 = acc[nt][1] + b.y;
            float v2 = acc[nt][2] + b.z, v3 = acc[nt][3] + b.w;
            if (relu_flag) {
                v0 = fmaxf(v0, 0.f); v1 = fmaxf(v1, 0.f);
                v2 = fmaxf(v2, 0.f); v3 = fmaxf(v3, 0.f);
            }
            uint2 o;
            o.x = (uint_t)f2b(v0) | ((uint_t)f2b(v1) << 16);
            o.y = (uint_t)f2b(v2) | ((uint_t)f2b(v3) << 16);
            *(uint2*)(Cr + col) = o;
        }
    }
}

// ================= fused 4-GEMM tail =================
__global__ __launch_bounds__(256) void k_gemm_fused(
        const ushort_t* __restrict__ hmid, const ushort_t* __restrict__ h,
        const ushort_t* __restrict__ rootm, const ushort_t* __restrict__ h2,
        const int* __restrict__ node_ids, const float* __restrict__ vf,
        const ushort_t* __restrict__ W2g, const ushort_t* __restrict__ Wsk,
        const ushort_t* __restrict__ Wvv, const ushort_t* __restrict__ Wkk,
        const float* __restrict__ cb, ushort_t* __restrict__ hout, int M) {
    __shared__ ushort_t Wl[128 * LSTR];
    const int t = threadIdx.x;
    int lane = t & 63, wave = t >> 6;
    int m = lane & 15, quad = lane >> 4;
    int row = blockIdx.x * 64 + wave * 16 + m;
    int nid = node_ids[row];
    int nc = nid > 0 ? nid : 0;
    const ushort_t* Asrc[4];
    Asrc[0] = hmid + (size_t)row * HD;
    Asrc[1] = h + (size_t)row * HD;
    Asrc[2] = rootm + (size_t)nc * HD;
    Asrc[3] = h + (size_t)(row & ~15) * HD;
    const ushort_t* Ws[4] = {W2g, Wsk, Wvv, Wkk};
    v4f acc[8];
    #pragma unroll
    for (int nt = 0; nt < 8; ++nt) acc[nt] = (v4f){0.f, 0.f, 0.f, 0.f};
    for (int ph = 0; ph < 4; ++ph) {
        if (ph) __syncthreads();
        stage_w(Wl, Ws[ph], t);
        const v8s* Ar = (const v8s*)Asrc[ph];
        v8s bfrag[4];
        #pragma unroll
        for (int c = 0; c < 4; ++c) bfrag[c] = Ar[c * 4 + quad];
        __syncthreads();
        #pragma unroll
        for (int nt = 0; nt < 8; ++nt) {
            #pragma unroll
            for (int c = 0; c < 4; ++c) {
                v8s wf = *(const v8s*)&Wl[(nt * 16 + m) * LSTR + c * 32 + quad * 8];
                acc[nt] = MFMA16(wf, bfrag[c], acc[nt]);
            }
        }
    }
    float vfm = vf[row];
    const ushort_t* h2r = h2 + (size_t)nc * HD;
    ushort_t* Cr = hout + (size_t)row * HD;
    #pragma unroll
    for (int nt = 0; nt < 8; ++nt) {
        int col = nt * 16 + quad * 4;
        float4 b = *(const float4*)(cb + col);
        uint2 hh = *(const uint2*)(h2r + col);
        float v0 = acc[nt][0] + b.x + b2f((ushort_t)(hh.x & 0xFFFF));
        float v1 = acc[nt][1] + b.y + b2f((ushort_t)(hh.x >> 16));
        float v2 = acc[nt][2] + b.z + b2f((ushort_t)(hh.y & 0xFFFF));
        float v3 = acc[nt][3] + b.w + b2f((ushort_t)(hh.y >> 16));
        v0 = fmaxf(v0, 0.f) * vfm; v1 = fmaxf(v1, 0.f) * vfm;
        v2 = fmaxf(v2, 0.f) * vfm; v3 = fmaxf(v3, 0.f) * vfm;
        uint2 o;
        o.x = (uint_t)f2b(v0) | ((uint_t)f2b(v1) << 16);
        o.y = (uint_t)f2b(v2) | ((uint_t)f2b(v3) << 16);
        *(uint2*)(Cr + col) = o;
    }
}

// ================= launcher =================

extern "C" void kernel_launch(void* const* d_in, const int* in_sizes, int n_in,
                              void* d_out, int out_size, void* d_ws, size_t ws_size,
                              hipStream_t stream) {
    (void)n_in; (void)ws_size;
    const float* atom_table = (const float*)d_in[0];
    const float* bond_table = (const float*)d_in[1];
    const float* role_table = (const float*)d_in[2];
    const float* lW1 = (const float*)d_in[3];
    const float* lb1 = (const float*)d_in[4];
    const float* lW2 = (const float*)d_in[5];
    const float* lb2 = (const float*)d_in[6];
    const float* gW1 = (const float*)d_in[7];
    const float* gb1 = (const float*)d_in[8];
    const float* gW2 = (const float*)d_in[9];
    const float* gb2 = (const float*)d_in[10];
    const float* lbn_g = (const float*)d_in[11];
    const float* lbn_b = (const float*)d_in[12];
    const float* gbn_g = (const float*)d_in[13];
    const float* gbn_b = (const float*)d_in[14];
    const float* skipW = (const float*)d_in[15];
    const float* skipb = (const float*)d_in[16];
    const float* vvW = (const float*)d_in[17];
    const float* vvb = (const float*)d_in[18];
    const float* kkW = (const float*)d_in[19];
    const float* kkb = (const float*)d_in[20];
    const int* atom_ids = (const int*)d_in[21];
    const int* bond_ids_intra = (const int*)d_in[22];
    const int* bond_ids_global = (const int*)d_in[23];
    const int* intra_ei = (const int*)d_in[24];
    const int* node_ids = (const int*)d_in[25];
    const int* edge_index = (const int*)d_in[26];
    const int* batch = (const int*)d_in[28];

    const int SK = in_sizes[21];
    const int EI = in_sizes[22];
    const int EG = in_sizes[23];
    const int N  = in_sizes[28];
    const int L  = in_sizes[4] / HD;
    const int S  = SK / 16;
    const int G  = out_size / HD;

    // ---- workspace layout (hA/hB have one extra always-zero row at idx SK) ----
    ushort_t* us = (ushort_t*)d_ws;
    ushort_t* hA    = us;
    ushort_t* hB    = hA + (size_t)(SK + 1) * HD;
    ushort_t* hmid  = hB + (size_t)(SK + 1) * HD;
    ushort_t* nmean = hmid + (size_t)SK * HD;
    ushort_t* nz    = nmean + (size_t)N * HD;
    ushort_t* nmid  = nz + (size_t)N * HD;
    ushort_t* h2    = nmid + (size_t)N * HD;
    ushort_t* rootm = h2 + (size_t)N * HD;
    ushort_t* wbuf  = rootm + (size_t)N * HD;
    float* fp = (float*)(wbuf + (size_t)7 * L * 16384);
    float* vf  = fp;
    float* cb  = vf + SK;
    float* b2g = cb + (size_t)L * 128;
    float* btabx = b2g + (size_t)L * 128;      // 17 * HD floats
    int* ip = (int*)(btabx + 17 * HD);
    int* degI   = ip;
    int* degG   = degI + SK;
    int* degN   = degG + N;
    int* degR   = degN + N;
    int* startI = degR + N;
    int* startG = startI + SK + 1;
    int* startN = startG + N + 1;
    int* startR = startN + N + 1;
    int* slotI  = startR + N + 1;
    int* slotG  = slotI + EI;
    int* slotN  = slotG + EG;
    int* slotR  = slotN + SK;
    int* tsum   = slotR + S;        // 4*128
    int* toff   = tsum + 512;       // 4*128
    int* gs     = toff + 512;       // G+1

    const int B = 256;
    const int gwAll = ((SK + 2 * N) * 64 + B - 1) / B;
    const int gwN   = (N * 64 + B - 1) / B;
    const int ggSK  = (SK + 63) / 64;
    const int ggN   = (N + 63) / 64;
    const int* intra_src = intra_ei;
    const int* intra_dst = intra_ei + EI;
    const int* glob_src  = edge_index;
    const int* glob_dst  = edge_index + EG;

    // ---- weight/bias prep ----
    int wtot = 7 * L * 16384;
    k_convert_w<<<(wtot + B - 1) / B, B, 0, stream>>>(lW1, lW2, gW1, gW2, skipW,
            vvW, kkW, lbn_g, gbn_g, wbuf, L);
    k_bias<<<(L * 128 + B - 1) / B, B, 0, stream>>>(lb2, lbn_g, lbn_b, skipb, vvb,
            kkb, gb2, gbn_g, gbn_b, cb, b2g, L * 128);
    k_btabx<<<(17 * HD + B - 1) / B, B, 0, stream>>>(bond_table, btabx, 16 * HD);

    // ---- CSR build ----
    hipMemsetAsync(degI, 0, (size_t)(SK + 3 * N) * sizeof(int), stream);
    k_hist<<<(EI + B - 1) / B, B, 0, stream>>>(intra_dst, degI, EI, 1);
    k_hist<<<(EG + B - 1) / B, B, 0, stream>>>(glob_dst, degG, EG, 1);
    k_hist<<<(SK + B - 1) / B, B, 0, stream>>>(node_ids, degN, SK, 1);
    k_hist<<<(S + B - 1) / B, B, 0, stream>>>(node_ids, degR, S, 16);
    const int T0 = (SK + 1023) / 1024, TN = (N + 1023) / 1024;
    const int nsb = T0 + 3 * TN;
    k_scan_up<<<nsb, 1024, 0, stream>>>(degI, degG, degN, degR,
            startI, startG, startN, startR, tsum, T0, TN, SK, N);
    k_scan_mid<<<1, 256, 0, stream>>>(tsum, toff, startI, startG, startN, startR,
            T0, TN, SK, N);
    k_scan_down<<<nsb, 1024, 0, stream>>>(startI, startG, startN, startR,
            toff, T0, TN, SK, N);
    hipMemsetAsync(degI, 0, (size_t)(SK + 3 * N) * sizeof(int), stream);
    k_fill_edges<<<(EI + B - 1) / B, B, 0, stream>>>(intra_dst, intra_src,
            bond_ids_intra, startI, degI, slotI, EI);
    k_fill_edges<<<(EG + B - 1) / B, B, 0, stream>>>(glob_dst, glob_src,
            bond_ids_global, startG, degG, slotG, EG);
    k_fill<<<(SK + B - 1) / B, B, 0, stream>>>(node_ids, startN, degN, slotN, SK, 1);
    k_fill<<<(S + B - 1) / B, B, 0, stream>>>(node_ids, startR, degR, slotR, S, 16);
    k_gstart<<<(N + 1 + B - 1) / B, B, 0, stream>>>(batch, gs, N, G);

    // ---- init ----
    k_vf<<<(SK + B - 1) / B, B, 0, stream>>>(node_ids, vf, SK);
    k_init_h<<<(SK * 64 + B - 1) / B, B, 0, stream>>>(atom_table, role_table,
            atom_ids, vf, hA, SK);
    hipMemsetAsync(hA + (size_t)SK * HD, 0, HD * sizeof(ushort_t), stream);
    hipMemsetAsync(hB + (size_t)SK * HD, 0, HD * sizeof(ushort_t), stream);

    ushort_t* hcur = hA;
    ushort_t* zb   = hB;
    auto WB = [&](int fam, int l) { return wbuf + ((size_t)(fam * L + l)) * 16384; };

    for (int l = 0; l < L; ++l) {
        const size_t lb = (size_t)l * HD;
        // 1) combined: zb = hcur + intra agg; nmean = node segmean; rootm = root segmean
        k_gather_all5<<<gwAll, B, 0, stream>>>(hcur, btabx,
                startI, slotI, zb, SK, startN, slotN, nmean,
                startR, slotR, rootm, N);
        // 2) hmid = relu(zb @ lW1^T + lb1)
        k_gemm1<<<ggSK, B, 0, stream>>>(zb, WB(0, l), lb1 + lb, hmid, SK, 1);
        // 3) nz = nmean + global-GINE agg
        k_gine_z5<<<gwN, B, 0, stream>>>(nmean, btabx, startG, slotG, nz, N);
        // 4) nmid = relu(nz @ gW1^T + gb1)
        k_gemm1<<<ggN, B, 0, stream>>>(nz, WB(2, l), gb1 + lb, nmid, N, 1);
        // 5) h2 = nmid @ (gW2*gbn_g)^T + (gb2*gbn_g + gbn_b)
        k_gemm1<<<ggN, B, 0, stream>>>(nmid, WB(3, l), b2g + lb, h2, N, 0);
        // 6) fused 4-GEMM tail -> zb
        k_gemm_fused<<<ggSK, B, 0, stream>>>(hmid, hcur, rootm, h2, node_ids, vf,
                WB(1, l), WB(4, l), WB(5, l), WB(6, l), cb + lb, zb, SK);
        ushort_t* tmp = hcur; hcur = zb; zb = tmp;
    }

    // final: node_embs = seg_mean(hcur); out = sorted-group sum (no atomics)
    k_segmean5<<<gwN, B, 0, stream>>>(hcur, startN, slotN, nmean, N, SK);
    k_pool2<<<G, B, 0, stream>>>(nmean, gs, (float*)d_out);
}

// Round 6
// 990.734 us; speedup vs baseline: 1.0154x; 1.0154x over previous
//
#include <hip/hip_runtime.h>

typedef unsigned short ushort_t;
typedef unsigned int uint_t;
typedef __attribute__((ext_vector_type(8))) short v8s;   // 8 bf16 MFMA A/B frag
typedef __attribute__((ext_vector_type(4))) float v4f;   // MFMA C/D frag
typedef __attribute__((ext_vector_type(2))) float v2f;   // packed f32 pair

#define HD 128
#define LSTR 136
#define MFMA16(a, b, c) __builtin_amdgcn_mfma_f32_16x16x32_bf16((a), (b), (c), 0, 0, 0)

__device__ __forceinline__ float b2f(ushort_t u) {
    union { uint_t i; float f; } v; v.i = ((uint_t)u) << 16; return v.f;
}
__device__ __forceinline__ ushort_t f2b(float f) {
    union { float f; uint_t i; } v; v.f = f;
    uint_t u = v.i;
    return (ushort_t)((u + 0x7FFFu + ((u >> 16) & 1u)) >> 16);
}
__device__ __forceinline__ v2f b2f2(uint_t u) {
    union { uint_t i; float f; } lo, hi;
    lo.i = u << 16; hi.i = u & 0xFFFF0000u;
    v2f r; r.x = lo.f; r.y = hi.f; return r;
}

// XCD-bijective chunked block swizzle (m204 form): consecutive work chunks
// land on the SAME XCD -> molecule-local X reads hit that XCD's L2.
__device__ __forceinline__ int xcd_swz(int bid, int nwg) {
    int q = nwg >> 3, r = nwg & 7;
    int x = bid & 7, j = bid >> 3;
    return (x < r ? x * (q + 1) : r * (q + 1) + (x - r) * q) + j;
}

// ================= CSR build =================

__global__ __launch_bounds__(256) void k_hist(const int* __restrict__ ids,
        int* __restrict__ deg, int M, int stride) {
    int i = blockIdx.x * blockDim.x + threadIdx.x;
    if (i >= M) return;
    int id = ids[(size_t)i * stride];
    if (id >= 0) atomicAdd(&deg[id], 1);
}

__device__ __forceinline__ void scan_map(int b, int T0, int TN, int& a, int& t) {
    if (b < T0) { a = 0; t = b; }
    else { int r = b - T0; a = 1 + r / TN; t = r % TN; }
}

__global__ __launch_bounds__(1024) void k_scan_up(
        const int* d0, const int* d1, const int* d2, const int* d3,
        int* s0, int* s1, int* s2, int* s3,
        int* __restrict__ tsum, int T0, int TN, int nSK, int nN) {
    int a, t;
    scan_map(blockIdx.x, T0, TN, a, t);
    const int* d = (a == 0) ? d0 : (a == 1) ? d1 : (a == 2) ? d2 : d3;
    int* s = (a == 0) ? s0 : (a == 1) ? s1 : (a == 2) ? s2 : s3;
    int n = (a == 0) ? nSK : nN;
    __shared__ int wsum[16];
    int tdx = threadIdx.x, lane = tdx & 63, wv = tdx >> 6;
    int i = t * 1024 + tdx;
    int v = (i < n) ? d[i] : 0;
    int x = v;
    #pragma unroll
    for (int off = 1; off < 64; off <<= 1) {
        int y = __shfl_up(x, off);
        if (lane >= off) x += y;
    }
    if (lane == 63) wsum[wv] = x;
    __syncthreads();
    int wo = 0, tot = 0;
    #pragma unroll
    for (int ww = 0; ww < 16; ++ww) {
        int sv = wsum[ww];
        if (ww < wv) wo += sv;
        tot += sv;
    }
    if (i < n) s[i] = wo + (x - v);
    if (tdx == 0) tsum[a * 128 + t] = tot;
}

__global__ __launch_bounds__(256) void k_scan_mid(
        const int* __restrict__ tsum, int* __restrict__ toff,
        int* s0, int* s1, int* s2, int* s3, int T0, int TN, int nSK, int nN) {
    int a = threadIdx.x >> 6, lane = threadIdx.x & 63;
    int T = (a == 0) ? T0 : TN;
    const int* ts = tsum + a * 128;
    int* to = toff + a * 128;
    int carry = 0;
    for (int base = 0; base < T; base += 64) {
        int idx = base + lane;
        int v = (idx < T) ? ts[idx] : 0;
        int x = v;
        #pragma unroll
        for (int off = 1; off < 64; off <<= 1) {
            int y = __shfl_up(x, off);
            if (lane >= off) x += y;
        }
        if (idx < T) to[idx] = carry + (x - v);
        carry += __shfl(x, 63);
    }
    if (lane == 0) {
        int* s = (a == 0) ? s0 : (a == 1) ? s1 : (a == 2) ? s2 : s3;
        s[(a == 0) ? nSK : nN] = carry;
    }
}

__global__ __launch_bounds__(1024) void k_scan_down(
        int* s0, int* s1, int* s2, int* s3,
        const int* __restrict__ toff, int T0, int TN, int nSK, int nN) {
    int a, t;
    scan_map(blockIdx.x, T0, TN, a, t);
    int* s = (a == 0) ? s0 : (a == 1) ? s1 : (a == 2) ? s2 : s3;
    int n = (a == 0) ? nSK : nN;
    int i = t * 1024 + threadIdx.x;
    if (i < n) s[i] += toff[a * 128 + t];
}

__global__ __launch_bounds__(256) void k_fill(const int* __restrict__ ids,
        const int* __restrict__ start, int* __restrict__ cursor,
        int* __restrict__ slots, int M, int stride) {
    int i = blockIdx.x * blockDim.x + threadIdx.x;
    if (i >= M) return;
    int id = ids[(size_t)i * stride];
    if (id < 0) return;
    int pos = start[id] + atomicAdd(&cursor[id], 1);
    slots[pos] = i * stride;
}

__global__ __launch_bounds__(256) void k_fill_edges(const int* __restrict__ dst,
        const int* __restrict__ src, const int* __restrict__ bids,
        const int* __restrict__ start, int* __restrict__ cursor,
        int* __restrict__ slots, int E) {
    int e = blockIdx.x * blockDim.x + threadIdx.x;
    if (e >= E) return;
    int d = dst[e];
    if (d < 0) return;
    int pos = start[d] + atomicAdd(&cursor[d], 1);
    slots[pos] = src[e] | (bids[e] << 20);
}

__global__ __launch_bounds__(256) void k_gstart(const int* __restrict__ batch,
        int* __restrict__ gs, int N, int G) {
    int n = blockIdx.x * blockDim.x + threadIdx.x;
    if (n > N) return;
    int bn = (n < N) ? batch[n] : G;
    int bp = (n == 0) ? -1 : batch[n - 1];
    for (int g = bp + 1; g <= bn; ++g)
        if (g <= G) gs[g] = n;
}

// ================= weight/bias prep =================

__global__ __launch_bounds__(256) void k_convert_w(
        const float* lW1, const float* lW2, const float* gW1, const float* gW2,
        const float* skipW, const float* vvW, const float* kkW,
        const float* lbn_g, const float* gbn_g,
        ushort_t* __restrict__ wbuf, int L) {
    int idx = blockIdx.x * blockDim.x + threadIdx.x;
    int total = 7 * L * 16384;
    if (idx >= total) return;
    int fam = idx / (L * 16384);
    int r = idx % (L * 16384);
    int l = r / 16384, e = r % 16384, n = e / 128;
    const float* src;
    float sc = 1.0f;
    switch (fam) {
        case 0: src = lW1; break;
        case 1: src = lW2; sc = lbn_g[l * 128 + n]; break;
        case 2: src = gW1; break;
        case 3: src = gW2; sc = gbn_g[l * 128 + n]; break;
        case 4: src = skipW; break;
        case 5: src = vvW; break;
        default: src = kkW; break;
    }
    wbuf[idx] = f2b(src[(size_t)l * 16384 + e] * sc);
}

__global__ __launch_bounds__(256) void k_bias(
        const float* lb2, const float* lbn_g, const float* lbn_b,
        const float* skipb, const float* vvb, const float* kkb,
        const float* gb2, const float* gbn_g, const float* gbn_b,
        float* __restrict__ cb, float* __restrict__ b2g, int total) {
    int i = blockIdx.x * blockDim.x + threadIdx.x;
    if (i >= total) return;
    cb[i] = lb2[i] * lbn_g[i] + lbn_b[i] + skipb[i] + vvb[i] + kkb[i];
    b2g[i] = gb2[i] * gbn_g[i] + gbn_b[i];
}

// extended bond table: rows 0-15 = f32 copy, row 16 = -1e30 (relu kill row)
__global__ __launch_bounds__(256) void k_btabx(const float* __restrict__ bt,
        float* __restrict__ btx, int nreal) {
    int i = blockIdx.x * blockDim.x + threadIdx.x;
    if (i >= nreal + HD) return;
    btx[i] = (i < nreal) ? bt[i] : -1e30f;
}

// ================= elementwise =================

__global__ __launch_bounds__(256) void k_vf(const int* __restrict__ node_ids,
        float* __restrict__ vf, int SK) {
    int i = blockIdx.x * blockDim.x + threadIdx.x;
    if (i < SK) vf[i] = (node_ids[i] >= 0) ? 1.0f : 0.0f;
}

__global__ __launch_bounds__(256) void k_init_h(const float* __restrict__ at,
        const float* __restrict__ rt, const int* __restrict__ atom_ids,
        const float* __restrict__ vf, ushort_t* __restrict__ h, int SK) {
    int t = blockIdx.x * blockDim.x + threadIdx.x;
    int i = t >> 6, lane = t & 63;
    if (i >= SK) return;
    float2 a = ((const float2*)(at + (size_t)atom_ids[i] * HD))[lane];
    int role = ((i & 15) == 0) ? 1 : 0;
    float2 r = ((const float2*)(rt + (size_t)role * HD))[lane];
    float m = vf[i];
    uint_t o = (uint_t)f2b((a.x + r.x) * m) | ((uint_t)f2b((a.y + r.y) * m) << 16);
    *(uint_t*)(h + (size_t)i * HD + lane * 2) = o;
}

// ---- R6 gather: single-row scalar walk, masked batches with scalar-branched
//      width (no per-block LDS staging, no cross-row lockstep). Slot loads are
//      CONTIGUOUS (s_load_dwordx8/16) with clamp-after-load scalar selects;
//      fake edges read slots[p] / bond row 16 (-1e30, relu kills) / zero row
//      X[SK] (segmean). Over-read past a slots array stays inside workspace. ----

template<int B_>
__device__ __forceinline__ void gine_batch(const char* __restrict__ Xb,
        const char* __restrict__ Bb, const int* __restrict__ slots,
        int p, int c, uint_t xo, uint_t bo, v2f& a) {
    const v2f z = {0.f, 0.f};
    int raw[B_];
    #pragma unroll
    for (int j = 0; j < B_; ++j) raw[j] = slots[p + j];
    int e[B_];
    #pragma unroll
    for (int j = 0; j < B_; ++j) e[j] = (j < c) ? raw[j] : raw[0];
    uint_t u[B_];
    #pragma unroll
    for (int j = 0; j < B_; ++j)
        u[j] = *(const uint_t*)(Xb + (((uint_t)(e[j] & 0xFFFFF)) << 8) + xo);
    #pragma unroll
    for (int j = 0; j < B_; ++j) {
        uint_t brow = (j < c) ? ((uint_t)e[j] >> 20) : 16u;
        float2 q = *(const float2*)(Bb + (brow << 9) + bo);
        v2f qv; qv.x = q.x; qv.y = q.y;
        a += __builtin_elementwise_max(b2f2(u[j]) + qv, z);
    }
}

__device__ __forceinline__ void gine_row_m(const char* __restrict__ Xb,
        const char* __restrict__ Bb, const int* __restrict__ slots,
        int s0, int s1, int row, char* __restrict__ outz, uint_t xo, uint_t bo) {
    v2f a = {0.f, 0.f};
    int p = s0;
    while (p < s1) {
        int c = s1 - p;
        if (c > 8)      { gine_batch<16>(Xb, Bb, slots, p, c, xo, bo, a); p += 16; }
        else if (c > 4) { gine_batch<8>(Xb, Bb, slots, p, c, xo, bo, a); p += 8; }
        else            { gine_batch<4>(Xb, Bb, slots, p, c, xo, bo, a); p += 4; }
    }
    uint_t su = *(const uint_t*)(Xb + (((uint_t)row) << 8) + xo);
    v2f o = b2f2(su) + a;
    *(uint_t*)(outz + (((uint_t)row) << 8) + xo) =
        (uint_t)f2b(o.x) | ((uint_t)f2b(o.y) << 16);
}

template<int B_>
__device__ __forceinline__ void segmean_batch(const char* __restrict__ Xb,
        const int* __restrict__ slots, int p, int c, int ZR, uint_t xo, v2f& a) {
    int raw[B_];
    #pragma unroll
    for (int j = 0; j < B_; ++j) raw[j] = slots[p + j];
    int r[B_];
    #pragma unroll
    for (int j = 0; j < B_; ++j) r[j] = (j < c) ? raw[j] : ZR;
    uint_t u[B_];
    #pragma unroll
    for (int j = 0; j < B_; ++j)
        u[j] = *(const uint_t*)(Xb + (((uint_t)r[j]) << 8) + xo);
    #pragma unroll
    for (int j = 0; j < B_; ++j)
        a += b2f2(u[j]);
}

__device__ __forceinline__ void segmean_row_m(const char* __restrict__ Xb,
        const int* __restrict__ slots, int s0, int s1, int row, int ZR,
        char* __restrict__ out, uint_t xo) {
    float inv = 1.0f / fmaxf((float)(s1 - s0), 1.0f);
    v2f a = {0.f, 0.f};
    int p = s0;
    while (p < s1) {
        int c = s1 - p;
        if (c > 4)      { segmean_batch<8>(Xb, slots, p, c, ZR, xo, a); p += 8; }
        else if (c > 2) { segmean_batch<4>(Xb, slots, p, c, ZR, xo, a); p += 4; }
        else            { segmean_batch<2>(Xb, slots, p, c, ZR, xo, a); p += 2; }
    }
    *(uint_t*)(out + (((uint_t)row) << 8) + xo) =
        (uint_t)f2b(a.x * inv) | ((uint_t)f2b(a.y * inv) << 16);
}

// combined: waves [0,SK) intra-GINE; [SK,SK+N) node segmean; [SK+N,SK+2N) root segmean
__global__ __launch_bounds__(256) void k_gather_all6(const ushort_t* __restrict__ X,
        const float* __restrict__ btabx,
        const int* __restrict__ startI, const int* __restrict__ slotI,
        ushort_t* __restrict__ outz, int SK,
        const int* __restrict__ startN, const int* __restrict__ slotN,
        ushort_t* __restrict__ nmean,
        const int* __restrict__ startR, const int* __restrict__ slotR,
        ushort_t* __restrict__ rootm, int N) {
    int bid = xcd_swz(blockIdx.x, gridDim.x);
    int w = __builtin_amdgcn_readfirstlane((bid * 256 + (int)threadIdx.x) >> 6);
    uint_t lane = threadIdx.x & 63;
    uint_t xo = lane * 4u, bo = lane * 8u;
    const char* Xb = (const char*)X;
    const char* Bb = (const char*)btabx;
    if (w < SK) {
        gine_row_m(Xb, Bb, slotI, startI[w], startI[w + 1], w, (char*)outz, xo, bo);
    } else if (w < SK + N) {
        int r = w - SK;
        segmean_row_m(Xb, slotN, startN[r], startN[r + 1], r, SK, (char*)nmean, xo);
    } else if (w < SK + 2 * N) {
        int r = w - SK - N;
        segmean_row_m(Xb, slotR, startR[r], startR[r + 1], r, SK, (char*)rootm, xo);
    }
}

__global__ __launch_bounds__(256) void k_gine_z6(const ushort_t* __restrict__ X,
        const float* __restrict__ btabx, const int* __restrict__ start,
        const int* __restrict__ slots, ushort_t* __restrict__ outz, int Nrows) {
    int bid = xcd_swz(blockIdx.x, gridDim.x);
    int w = __builtin_amdgcn_readfirstlane((bid * 256 + (int)threadIdx.x) >> 6);
    if (w >= Nrows) return;
    uint_t lane = threadIdx.x & 63;
    gine_row_m((const char*)X, (const char*)btabx, slots, start[w], start[w + 1],
               w, (char*)outz, lane * 4u, lane * 8u);
}

__global__ __launch_bounds__(256) void k_segmean6(const ushort_t* __restrict__ X,
        const int* __restrict__ start, const int* __restrict__ slots,
        ushort_t* __restrict__ out, int Nrows, int ZR) {
    int w = __builtin_amdgcn_readfirstlane((blockIdx.x * 256 + threadIdx.x) >> 6);
    if (w >= Nrows) return;
    uint_t lane = threadIdx.x & 63;
    segmean_row_m((const char*)X, slots, start[w], start[w + 1], w, ZR,
                  (char*)out, lane * 4u);
}

// sorted-batch pool: one block per group, contiguous node range, no atomics
__global__ __launch_bounds__(256) void k_pool2(const ushort_t* __restrict__ xsum,
        const int* __restrict__ gs, float* __restrict__ out) {
    int g = blockIdx.x;
    int t = threadIdx.x, wv = t >> 6, lane = t & 63;
    int n0 = gs[g], n1 = gs[g + 1];
    float a0 = 0.f, a1 = 0.f;
    for (int n = n0 + wv; n < n1; n += 4) {
        uint_t u = *(const uint_t*)(xsum + (size_t)n * HD + lane * 2);
        a0 += b2f((ushort_t)(u & 0xFFFF));
        a1 += b2f((ushort_t)(u >> 16));
    }
    __shared__ float red[4][128];
    red[wv][lane * 2] = a0;
    red[wv][lane * 2 + 1] = a1;
    __syncthreads();
    if (wv == 0) {
        float s0 = red[0][lane * 2] + red[1][lane * 2]
                 + red[2][lane * 2] + red[3][lane * 2];
        float s1 = red[0][lane * 2 + 1] + red[1][lane * 2 + 1]
                 + red[2][lane * 2 + 1] + red[3][lane * 2 + 1];
        *(float2*)(out + (size_t)g * HD + lane * 2) = make_float2(s0, s1);
    }
}

// ---- stage one 128x128 bf16 weight into padded LDS (R9 champion form) ----
__device__ __forceinline__ void stage_w(ushort_t* Wl, const ushort_t* Wb, int t) {
    #pragma unroll
    for (int it = 0; it < 8; ++it) {
        int idx = it * 256 + t;
        uint4 v = *(const uint4*)(Wb + (size_t)idx * 8);
        int row = idx >> 4, col = (idx & 15) * 8;
        *(uint4*)&Wl[row * LSTR + col] = v;
    }
}

// ================= GEMM: C = maybe_relu(A @ W^T + bias) =================
__global__ __launch_bounds__(256) void k_gemm1(const ushort_t* __restrict__ A,
        const ushort_t* __restrict__ Wb, const float* __restrict__ bias,
        ushort_t* __restrict__ C, int M, int relu_flag) {
    __shared__ ushort_t Wl[128 * LSTR];
    const int t = threadIdx.x;
    stage_w(Wl, Wb, t);
    int lane = t & 63, wave = t >> 6;
    int m = lane & 15, quad = lane >> 4;
    int row = blockIdx.x * 64 + wave * 16 + m;
    int ar = row < M ? row : M - 1;
    const v8s* Ar = (const v8s*)(A + (size_t)ar * HD);
    v8s bfrag[4];
    #pragma unroll
    for (int c = 0; c < 4; ++c) bfrag[c] = Ar[c * 4 + quad];
    __syncthreads();
    v4f acc[8];
    #pragma unroll
    for (int nt = 0; nt < 8; ++nt) acc[nt] = (v4f){0.f, 0.f, 0.f, 0.f};
    #pragma unroll
    for (int nt = 0; nt < 8; ++nt) {
        #pragma unroll
        for (int c = 0; c < 4; ++c) {
            v8s wf = *(const v8s*)&Wl[(nt * 16 + m) * LSTR + c * 32 + quad * 8];
            acc[nt] = MFMA16(wf, bfrag[c], acc[nt]);
        }
    }
    if (row < M) {
        ushort_t* Cr = C + (size_t)row * HD;
        #pragma unroll
        for (int nt = 0; nt < 8; ++nt) {
            int col = nt * 16 + quad * 4;
            float4 b = *(const float4*)(bias + col);
            float v0 = acc[nt][0] + b.x, v1 = acc[nt][1] + b.y;
            float v2 = acc[nt][2] + b.z, v3 = acc[nt][3] + b.w;
            if (relu_flag) {
                v0 = fmaxf(v0, 0.f); v1 = fmaxf(v1, 0.f);
                v2 = fmaxf(v2, 0.f); v3 = fmaxf(v3, 0.f);
            }
            uint2 o;
            o.x = (uint_t)f2b(v0) | ((uint_t)f2b(v1) << 16);
            o.y = (uint_t)f2b(v2) | ((uint_t)f2b(v3) << 16);
            *(uint2*)(Cr + col) = o;
        }
    }
}

// ================= fused 4-GEMM tail =================
__global__ __launch_bounds__(256) void k_gemm_fused(
        const ushort_t* __restrict__ hmid, const ushort_t* __restrict__ h,
        const ushort_t* __restrict__ rootm, const ushort_t* __restrict__ h2,
        const int* __restrict__ node_ids, const float* __restrict__ vf,
        const ushort_t* __restrict__ W2g, const ushort_t* __restrict__ Wsk,
        const ushort_t* __restrict__ Wvv, const ushort_t* __restrict__ Wkk,
        const float* __restrict__ cb, ushort_t* __restrict__ hout, int M) {
    __shared__ ushort_t Wl[128 * LSTR];
    const int t = threadIdx.x;
    int lane = t & 63, wave = t >> 6;
    int m = lane & 15, quad = lane >> 4;
    int row = blockIdx.x * 64 + wave * 16 + m;
    int nid = node_ids[row];
    int nc = nid > 0 ? nid : 0;
    const ushort_t* Asrc[4];
    Asrc[0] = hmid + (size_t)row * HD;
    Asrc[1] = h + (size_t)row * HD;
    Asrc[2] = rootm + (size_t)nc * HD;
    Asrc[3] = h + (size_t)(row & ~15) * HD;
    const ushort_t* Ws[4] = {W2g, Wsk, Wvv, Wkk};
    v4f acc[8];
    #pragma unroll
    for (int nt = 0; nt < 8; ++nt) acc[nt] = (v4f){0.f, 0.f, 0.f, 0.f};
    for (int ph = 0; ph < 4; ++ph) {
        if (ph) __syncthreads();
        stage_w(Wl, Ws[ph], t);
        const v8s* Ar = (const v8s*)Asrc[ph];
        v8s bfrag[4];
        #pragma unroll
        for (int c = 0; c < 4; ++c) bfrag[c] = Ar[c * 4 + quad];
        __syncthreads();
        #pragma unroll
        for (int nt = 0; nt < 8; ++nt) {
            #pragma unroll
            for (int c = 0; c < 4; ++c) {
                v8s wf = *(const v8s*)&Wl[(nt * 16 + m) * LSTR + c * 32 + quad * 8];
                acc[nt] = MFMA16(wf, bfrag[c], acc[nt]);
            }
        }
    }
    float vfm = vf[row];
    const ushort_t* h2r = h2 + (size_t)nc * HD;
    ushort_t* Cr = hout + (size_t)row * HD;
    #pragma unroll
    for (int nt = 0; nt < 8; ++nt) {
        int col = nt * 16 + quad * 4;
        float4 b = *(const float4*)(cb + col);
        uint2 hh = *(const uint2*)(h2r + col);
        float v0 = acc[nt][0] + b.x + b2f((ushort_t)(hh.x & 0xFFFF));
        float v1 = acc[nt][1] + b.y + b2f((ushort_t)(hh.x >> 16));
        float v2 = acc[nt][2] + b.z + b2f((ushort_t)(hh.y & 0xFFFF));
        float v3 = acc[nt][3] + b.w + b2f((ushort_t)(hh.y >> 16));
        v0 = fmaxf(v0, 0.f) * vfm; v1 = fmaxf(v1, 0.f) * vfm;
        v2 = fmaxf(v2, 0.f) * vfm; v3 = fmaxf(v3, 0.f) * vfm;
        uint2 o;
        o.x = (uint_t)f2b(v0) | ((uint_t)f2b(v1) << 16);
        o.y = (uint_t)f2b(v2) | ((uint_t)f2b(v3) << 16);
        *(uint2*)(Cr + col) = o;
    }
}

// ================= launcher =================

extern "C" void kernel_launch(void* const* d_in, const int* in_sizes, int n_in,
                              void* d_out, int out_size, void* d_ws, size_t ws_size,
                              hipStream_t stream) {
    (void)n_in; (void)ws_size;
    const float* atom_table = (const float*)d_in[0];
    const float* bond_table = (const float*)d_in[1];
    const float* role_table = (const float*)d_in[2];
    const float* lW1 = (const float*)d_in[3];
    const float* lb1 = (const float*)d_in[4];
    const float* lW2 = (const float*)d_in[5];
    const float* lb2 = (const float*)d_in[6];
    const float* gW1 = (const float*)d_in[7];
    const float* gb1 = (const float*)d_in[8];
    const float* gW2 = (const float*)d_in[9];
    const float* gb2 = (const float*)d_in[10];
    const float* lbn_g = (const float*)d_in[11];
    const float* lbn_b = (const float*)d_in[12];
    const float* gbn_g = (const float*)d_in[13];
    const float* gbn_b = (const float*)d_in[14];
    const float* skipW = (const float*)d_in[15];
    const float* skipb = (const float*)d_in[16];
    const float* vvW = (const float*)d_in[17];
    const float* vvb = (const float*)d_in[18];
    const float* kkW = (const float*)d_in[19];
    const float* kkb = (const float*)d_in[20];
    const int* atom_ids = (const int*)d_in[21];
    const int* bond_ids_intra = (const int*)d_in[22];
    const int* bond_ids_global = (const int*)d_in[23];
    const int* intra_ei = (const int*)d_in[24];
    const int* node_ids = (const int*)d_in[25];
    const int* edge_index = (const int*)d_in[26];
    const int* batch = (const int*)d_in[28];

    const int SK = in_sizes[21];
    const int EI = in_sizes[22];
    const int EG = in_sizes[23];
    const int N  = in_sizes[28];
    const int L  = in_sizes[4] / HD;
    const int S  = SK / 16;
    const int G  = out_size / HD;

    // ---- workspace layout (hA/hB have one extra always-zero row at idx SK) ----
    ushort_t* us = (ushort_t*)d_ws;
    ushort_t* hA    = us;
    ushort_t* hB    = hA + (size_t)(SK + 1) * HD;
    ushort_t* hmid  = hB + (size_t)(SK + 1) * HD;
    ushort_t* nmean = hmid + (size_t)SK * HD;
    ushort_t* nz    = nmean + (size_t)N * HD;
    ushort_t* nmid  = nz + (size_t)N * HD;
    ushort_t* h2    = nmid + (size_t)N * HD;
    ushort_t* rootm = h2 + (size_t)N * HD;
    ushort_t* wbuf  = rootm + (size_t)N * HD;
    float* fp = (float*)(wbuf + (size_t)7 * L * 16384);
    float* vf  = fp;
    float* cb  = vf + SK;
    float* b2g = cb + (size_t)L * 128;
    float* btabx = b2g + (size_t)L * 128;      // 17 * HD floats
    int* ip = (int*)(btabx + 17 * HD);
    int* degI   = ip;
    int* degG   = degI + SK;
    int* degN   = degG + N;
    int* degR   = degN + N;
    int* startI = degR + N;
    int* startG = startI + SK + 1;
    int* startN = startG + N + 1;
    int* startR = startN + N + 1;
    int* slotI  = startR + N + 1;
    int* slotG  = slotI + EI;
    int* slotN  = slotG + EG;
    int* slotR  = slotN + SK;
    int* tsum   = slotR + S;        // 4*128
    int* toff   = tsum + 512;       // 4*128
    int* gs     = toff + 512;       // G+1

    const int B = 256;
    const int gwAll = ((SK + 2 * N) * 64 + B - 1) / B;
    const int gwN   = (N * 64 + B - 1) / B;
    const int ggSK  = (SK + 63) / 64;
    const int ggN   = (N + 63) / 64;
    const int* intra_src = intra_ei;
    const int* intra_dst = intra_ei + EI;
    const int* glob_src  = edge_index;
    const int* glob_dst  = edge_index + EG;

    // ---- weight/bias prep ----
    int wtot = 7 * L * 16384;
    k_convert_w<<<(wtot + B - 1) / B, B, 0, stream>>>(lW1, lW2, gW1, gW2, skipW,
            vvW, kkW, lbn_g, gbn_g, wbuf, L);
    k_bias<<<(L * 128 + B - 1) / B, B, 0, stream>>>(lb2, lbn_g, lbn_b, skipb, vvb,
            kkb, gb2, gbn_g, gbn_b, cb, b2g, L * 128);
    k_btabx<<<(17 * HD + B - 1) / B, B, 0, stream>>>(bond_table, btabx, 16 * HD);

    // ---- CSR build ----
    hipMemsetAsync(degI, 0, (size_t)(SK + 3 * N) * sizeof(int), stream);
    k_hist<<<(EI + B - 1) / B, B, 0, stream>>>(intra_dst, degI, EI, 1);
    k_hist<<<(EG + B - 1) / B, B, 0, stream>>>(glob_dst, degG, EG, 1);
    k_hist<<<(SK + B - 1) / B, B, 0, stream>>>(node_ids, degN, SK, 1);
    k_hist<<<(S + B - 1) / B, B, 0, stream>>>(node_ids, degR, S, 16);
    const int T0 = (SK + 1023) / 1024, TN = (N + 1023) / 1024;
    const int nsb = T0 + 3 * TN;
    k_scan_up<<<nsb, 1024, 0, stream>>>(degI, degG, degN, degR,
            startI, startG, startN, startR, tsum, T0, TN, SK, N);
    k_scan_mid<<<1, 256, 0, stream>>>(tsum, toff, startI, startG, startN, startR,
            T0, TN, SK, N);
    k_scan_down<<<nsb, 1024, 0, stream>>>(startI, startG, startN, startR,
            toff, T0, TN, SK, N);
    hipMemsetAsync(degI, 0, (size_t)(SK + 3 * N) * sizeof(int), stream);
    k_fill_edges<<<(EI + B - 1) / B, B, 0, stream>>>(intra_dst, intra_src,
            bond_ids_intra, startI, degI, slotI, EI);
    k_fill_edges<<<(EG + B - 1) / B, B, 0, stream>>>(glob_dst, glob_src,
            bond_ids_global, startG, degG, slotG, EG);
    k_fill<<<(SK + B - 1) / B, B, 0, stream>>>(node_ids, startN, degN, slotN, SK, 1);
    k_fill<<<(S + B - 1) / B, B, 0, stream>>>(node_ids, startR, degR, slotR, S, 16);
    k_gstart<<<(N + 1 + B - 1) / B, B, 0, stream>>>(batch, gs, N, G);

    // ---- init ----
    k_vf<<<(SK + B - 1) / B, B, 0, stream>>>(node_ids, vf, SK);
    k_init_h<<<(SK * 64 + B - 1) / B, B, 0, stream>>>(atom_table, role_table,
            atom_ids, vf, hA, SK);
    hipMemsetAsync(hA + (size_t)SK * HD, 0, HD * sizeof(ushort_t), stream);
    hipMemsetAsync(hB + (size_t)SK * HD, 0, HD * sizeof(ushort_t), stream);

    ushort_t* hcur = hA;
    ushort_t* zb   = hB;
    auto WB = [&](int fam, int l) { return wbuf + ((size_t)(fam * L + l)) * 16384; };

    for (int l = 0; l < L; ++l) {
        const size_t lb = (size_t)l * HD;
        // 1) combined: zb = hcur + intra agg; nmean = node segmean; rootm = root segmean
        k_gather_all6<<<gwAll, B, 0, stream>>>(hcur, btabx,
                startI, slotI, zb, SK, startN, slotN, nmean,
                startR, slotR, rootm, N);
        // 2) hmid = relu(zb @ lW1^T + lb1)
        k_gemm1<<<ggSK, B, 0, stream>>>(zb, WB(0, l), lb1 + lb, hmid, SK, 1);
        // 3) nz = nmean + global-GINE agg
        k_gine_z6<<<gwN, B, 0, stream>>>(nmean, btabx, startG, slotG, nz, N);
        // 4) nmid = relu(nz @ gW1^T + gb1)
        k_gemm1<<<ggN, B, 0, stream>>>(nz, WB(2, l), gb1 + lb, nmid, N, 1);
        // 5) h2 = nmid @ (gW2*gbn_g)^T + (gb2*gbn_g + gbn_b)
        k_gemm1<<<ggN, B, 0, stream>>>(nmid, WB(3, l), b2g + lb, h2, N, 0);
        // 6) fused 4-GEMM tail -> zb
        k_gemm_fused<<<ggSK, B, 0, stream>>>(hmid, hcur, rootm, h2, node_ids, vf,
                WB(1, l), WB(4, l), WB(5, l), WB(6, l), cb + lb, zb, SK);
        ushort_t* tmp = hcur; hcur = zb; zb = tmp;
    }

    // final: node_embs = seg_mean(hcur); out = sorted-group sum (no atomics)
    k_segmean6<<<gwN, B, 0, stream>>>(hcur, startN, slotN, nmean, N, SK);
    k_pool2<<<G, B, 0, stream>>>(nmean, gs, (float*)d_out);
}

// Round 7
// 872.591 us; speedup vs baseline: 1.1529x; 1.1354x over previous
//
#include <hip/hip_runtime.h>

typedef unsigned short ushort_t;
typedef unsigned int uint_t;
typedef __attribute__((ext_vector_type(8))) short v8s;   // 8 bf16 MFMA A/B frag
typedef __attribute__((ext_vector_type(4))) float v4f;   // MFMA C/D frag
typedef __attribute__((ext_vector_type(2))) float v2f;   // packed f32 pair

#define HD 128
#define LSTR 136
#define MFMA16(a, b, c) __builtin_amdgcn_mfma_f32_16x16x32_bf16((a), (b), (c), 0, 0, 0)

__device__ __forceinline__ float b2f(ushort_t u) {
    union { uint_t i; float f; } v; v.i = ((uint_t)u) << 16; return v.f;
}
__device__ __forceinline__ ushort_t f2b(float f) {
    union { float f; uint_t i; } v; v.f = f;
    uint_t u = v.i;
    return (ushort_t)((u + 0x7FFFu + ((u >> 16) & 1u)) >> 16);
}
__device__ __forceinline__ v2f b2f2(uint_t u) {
    union { uint_t i; float f; } lo, hi;
    lo.i = u << 16; hi.i = u & 0xFFFF0000u;
    v2f r; r.x = lo.f; r.y = hi.f; return r;
}

// ================= CSR build =================

__global__ __launch_bounds__(256) void k_hist(const int* __restrict__ ids,
        int* __restrict__ deg, int M, int stride) {
    int i = blockIdx.x * blockDim.x + threadIdx.x;
    if (i >= M) return;
    int id = ids[(size_t)i * stride];
    if (id >= 0) atomicAdd(&deg[id], 1);
}

__device__ __forceinline__ void scan_map(int b, int T0, int TN, int& a, int& t) {
    if (b < T0) { a = 0; t = b; }
    else { int r = b - T0; a = 1 + r / TN; t = r % TN; }
}

__global__ __launch_bounds__(1024) void k_scan_up(
        const int* d0, const int* d1, const int* d2, const int* d3,
        int* s0, int* s1, int* s2, int* s3,
        int* __restrict__ tsum, int T0, int TN, int nSK, int nN) {
    int a, t;
    scan_map(blockIdx.x, T0, TN, a, t);
    const int* d = (a == 0) ? d0 : (a == 1) ? d1 : (a == 2) ? d2 : d3;
    int* s = (a == 0) ? s0 : (a == 1) ? s1 : (a == 2) ? s2 : s3;
    int n = (a == 0) ? nSK : nN;
    __shared__ int wsum[16];
    int tdx = threadIdx.x, lane = tdx & 63, wv = tdx >> 6;
    int i = t * 1024 + tdx;
    int v = (i < n) ? d[i] : 0;
    int x = v;
    #pragma unroll
    for (int off = 1; off < 64; off <<= 1) {
        int y = __shfl_up(x, off);
        if (lane >= off) x += y;
    }
    if (lane == 63) wsum[wv] = x;
    __syncthreads();
    int wo = 0, tot = 0;
    #pragma unroll
    for (int ww = 0; ww < 16; ++ww) {
        int sv = wsum[ww];
        if (ww < wv) wo += sv;
        tot += sv;
    }
    if (i < n) s[i] = wo + (x - v);
    if (tdx == 0) tsum[a * 128 + t] = tot;
}

__global__ __launch_bounds__(256) void k_scan_mid(
        const int* __restrict__ tsum, int* __restrict__ toff,
        int* s0, int* s1, int* s2, int* s3, int T0, int TN, int nSK, int nN) {
    int a = threadIdx.x >> 6, lane = threadIdx.x & 63;
    int T = (a == 0) ? T0 : TN;
    const int* ts = tsum + a * 128;
    int* to = toff + a * 128;
    int carry = 0;
    for (int base = 0; base < T; base += 64) {
        int idx = base + lane;
        int v = (idx < T) ? ts[idx] : 0;
        int x = v;
        #pragma unroll
        for (int off = 1; off < 64; off <<= 1) {
            int y = __shfl_up(x, off);
            if (lane >= off) x += y;
        }
        if (idx < T) to[idx] = carry + (x - v);
        carry += __shfl(x, 63);
    }
    if (lane == 0) {
        int* s = (a == 0) ? s0 : (a == 1) ? s1 : (a == 2) ? s2 : s3;
        s[(a == 0) ? nSK : nN] = carry;
    }
}

__global__ __launch_bounds__(1024) void k_scan_down(
        int* s0, int* s1, int* s2, int* s3,
        const int* __restrict__ toff, int T0, int TN, int nSK, int nN) {
    int a, t;
    scan_map(blockIdx.x, T0, TN, a, t);
    int* s = (a == 0) ? s0 : (a == 1) ? s1 : (a == 2) ? s2 : s3;
    int n = (a == 0) ? nSK : nN;
    int i = t * 1024 + threadIdx.x;
    if (i < n) s[i] += toff[a * 128 + t];
}

__global__ __launch_bounds__(256) void k_fill(const int* __restrict__ ids,
        const int* __restrict__ start, int* __restrict__ cursor,
        int* __restrict__ slots, int M, int stride) {
    int i = blockIdx.x * blockDim.x + threadIdx.x;
    if (i >= M) return;
    int id = ids[(size_t)i * stride];
    if (id < 0) return;
    int pos = start[id] + atomicAdd(&cursor[id], 1);
    slots[pos] = i * stride;
}

__global__ __launch_bounds__(256) void k_fill_edges(const int* __restrict__ dst,
        const int* __restrict__ src, const int* __restrict__ bids,
        const int* __restrict__ start, int* __restrict__ cursor,
        int* __restrict__ slots, int E) {
    int e = blockIdx.x * blockDim.x + threadIdx.x;
    if (e >= E) return;
    int d = dst[e];
    if (d < 0) return;
    int pos = start[d] + atomicAdd(&cursor[d], 1);
    slots[pos] = src[e] | (bids[e] << 20);
}

__global__ __launch_bounds__(256) void k_gstart(const int* __restrict__ batch,
        int* __restrict__ gs, int N, int G) {
    int n = blockIdx.x * blockDim.x + threadIdx.x;
    if (n > N) return;
    int bn = (n < N) ? batch[n] : G;
    int bp = (n == 0) ? -1 : batch[n - 1];
    for (int g = bp + 1; g <= bn; ++g)
        if (g <= G) gs[g] = n;
}

// ================= weight/bias prep =================

__global__ __launch_bounds__(256) void k_convert_w(
        const float* lW1, const float* lW2, const float* gW1, const float* gW2,
        const float* skipW, const float* vvW, const float* kkW,
        const float* lbn_g, const float* gbn_g,
        ushort_t* __restrict__ wbuf, int L) {
    int idx = blockIdx.x * blockDim.x + threadIdx.x;
    int total = 7 * L * 16384;
    if (idx >= total) return;
    int fam = idx / (L * 16384);
    int r = idx % (L * 16384);
    int l = r / 16384, e = r % 16384, n = e / 128;
    const float* src;
    float sc = 1.0f;
    switch (fam) {
        case 0: src = lW1; break;
        case 1: src = lW2; sc = lbn_g[l * 128 + n]; break;
        case 2: src = gW1; break;
        case 3: src = gW2; sc = gbn_g[l * 128 + n]; break;
        case 4: src = skipW; break;
        case 5: src = vvW; break;
        default: src = kkW; break;
    }
    wbuf[idx] = f2b(src[(size_t)l * 16384 + e] * sc);
}

__global__ __launch_bounds__(256) void k_bias(
        const float* lb2, const float* lbn_g, const float* lbn_b,
        const float* skipb, const float* vvb, const float* kkb,
        const float* gb2, const float* gbn_g, const float* gbn_b,
        float* __restrict__ cb, float* __restrict__ b2g, int total) {
    int i = blockIdx.x * blockDim.x + threadIdx.x;
    if (i >= total) return;
    cb[i] = lb2[i] * lbn_g[i] + lbn_b[i] + skipb[i] + vvb[i] + kkb[i];
    b2g[i] = gb2[i] * gbn_g[i] + gbn_b[i];
}

// ================= elementwise =================

__global__ __launch_bounds__(256) void k_vf(const int* __restrict__ node_ids,
        float* __restrict__ vf, int SK) {
    int i = blockIdx.x * blockDim.x + threadIdx.x;
    if (i < SK) vf[i] = (node_ids[i] >= 0) ? 1.0f : 0.0f;
}

__global__ __launch_bounds__(256) void k_init_h(const float* __restrict__ at,
        const float* __restrict__ rt, const int* __restrict__ atom_ids,
        const float* __restrict__ vf, ushort_t* __restrict__ h, int SK) {
    int t = blockIdx.x * blockDim.x + threadIdx.x;
    int i = t >> 6, lane = t & 63;
    if (i >= SK) return;
    float2 a = ((const float2*)(at + (size_t)atom_ids[i] * HD))[lane];
    int role = ((i & 15) == 0) ? 1 : 0;
    float2 r = ((const float2*)(rt + (size_t)role * HD))[lane];
    float m = vf[i];
    uint_t o = (uint_t)f2b((a.x + r.x) * m) | ((uint_t)f2b((a.y + r.y) * m) << 16);
    *(uint_t*)(h + (size_t)i * HD + lane * 2) = o;
}

// ---- R2 champion scalar-walk gather: ONE row per wave, row index in SGPR via
//      readfirstlane. start/slots loads + address decode on the scalar pipe;
//      X/btab loads are global_load with SGPR base + constant per-lane voffset.
//      8/4/2/1 batch structure (proven fastest across R3-R6 variants). ----

#define HE(i) int e##i = slots[p + i];
#define HX(i) uint_t u##i = *(const uint_t*)(Xb + (((uint_t)(e##i & 0xFFFFF)) << 8) + xo);
#define HQ(i) float2 q##i = *(const float2*)(Bb + (((uint_t)e##i >> 20) << 9) + bo);
#define HA(i) { v2f qv; qv.x = q##i.x; qv.y = q##i.y; \
                a += __builtin_elementwise_max(b2f2(u##i) + qv, z); }

__device__ __forceinline__ void gine_row_s(const char* __restrict__ Xb,
        const char* __restrict__ Bb, const int* __restrict__ slots,
        int s0, int s1, int row, ushort_t* __restrict__ outz, uint_t xo, uint_t bo) {
    const v2f z = {0.f, 0.f};
    v2f a = z;
    int p = s0;
    for (; p + 7 < s1; p += 8) {
        HE(0) HE(1) HE(2) HE(3) HE(4) HE(5) HE(6) HE(7)
        HX(0) HX(1) HX(2) HX(3) HX(4) HX(5) HX(6) HX(7)
        HQ(0) HQ(1) HQ(2) HQ(3) HQ(4) HQ(5) HQ(6) HQ(7)
        HA(0) HA(1) HA(2) HA(3) HA(4) HA(5) HA(6) HA(7)
    }
    if (p + 3 < s1) {
        HE(0) HE(1) HE(2) HE(3)
        HX(0) HX(1) HX(2) HX(3)
        HQ(0) HQ(1) HQ(2) HQ(3)
        HA(0) HA(1) HA(2) HA(3)
        p += 4;
    }
    if (p + 1 < s1) {
        HE(0) HE(1)
        HX(0) HX(1)
        HQ(0) HQ(1)
        HA(0) HA(1)
        p += 2;
    }
    if (p < s1) {
        HE(0)
        HX(0)
        HQ(0)
        HA(0)
    }
    uint_t su = *(const uint_t*)(Xb + (((uint_t)row) << 8) + xo);
    v2f sv = b2f2(su);
    float f0 = a.x + sv.x, f1 = a.y + sv.y;
    *(uint_t*)((char*)outz + (((uint_t)row) << 8) + xo) =
        (uint_t)f2b(f0) | ((uint_t)f2b(f1) << 16);
}

#define SE(i) int r##i = slots[p + i];
#define SX(i) uint_t u##i = *(const uint_t*)(Xb + (((uint_t)r##i) << 8) + xo);
#define SA(i) a += b2f2(u##i);

__device__ __forceinline__ void segmean_row_s(const char* __restrict__ Xb,
        const int* __restrict__ slots, int s0, int s1, int row,
        ushort_t* __restrict__ out, uint_t xo) {
    float inv = 1.0f / fmaxf((float)(s1 - s0), 1.0f);
    const v2f z = {0.f, 0.f};
    v2f a = z;
    int p = s0;
    for (; p + 7 < s1; p += 8) {
        SE(0) SE(1) SE(2) SE(3) SE(4) SE(5) SE(6) SE(7)
        SX(0) SX(1) SX(2) SX(3) SX(4) SX(5) SX(6) SX(7)
        SA(0) SA(1) SA(2) SA(3) SA(4) SA(5) SA(6) SA(7)
    }
    if (p + 3 < s1) {
        SE(0) SE(1) SE(2) SE(3)
        SX(0) SX(1) SX(2) SX(3)
        SA(0) SA(1) SA(2) SA(3)
        p += 4;
    }
    if (p + 1 < s1) {
        SE(0) SE(1)
        SX(0) SX(1)
        SA(0) SA(1)
        p += 2;
    }
    if (p < s1) {
        SE(0)
        SX(0)
        SA(0)
    }
    *(uint_t*)((char*)out + (((uint_t)row) << 8) + xo) =
        (uint_t)f2b(a.x * inv) | ((uint_t)f2b(a.y * inv) << 16);
}

// combined: waves [0,SK) intra-GINE; [SK,SK+N) node segmean; [SK+N,SK+2N) root segmean
__global__ __launch_bounds__(256) void k_gather_all3(const ushort_t* __restrict__ X,
        const float* __restrict__ btab,
        const int* __restrict__ startI, const int* __restrict__ slotI,
        ushort_t* __restrict__ outz, int SK,
        const int* __restrict__ startN, const int* __restrict__ slotN,
        ushort_t* __restrict__ nmean,
        const int* __restrict__ startR, const int* __restrict__ slotR,
        ushort_t* __restrict__ rootm, int N) {
    int w = __builtin_amdgcn_readfirstlane((blockIdx.x * 256 + threadIdx.x) >> 6);
    uint_t lane = threadIdx.x & 63;
    uint_t xo = lane * 4u, bo = lane * 8u;
    const char* Xb = (const char*)X;
    if (w < SK) {
        gine_row_s(Xb, (const char*)btab, slotI, startI[w], startI[w + 1], w,
                   outz, xo, bo);
    } else if (w < SK + N) {
        int r = w - SK;
        segmean_row_s(Xb, slotN, startN[r], startN[r + 1], r, nmean, xo);
    } else if (w < SK + 2 * N) {
        int r = w - SK - N;
        segmean_row_s(Xb, slotR, startR[r], startR[r + 1], r, rootm, xo);
    }
}

__global__ __launch_bounds__(256) void k_gine_z3(const ushort_t* __restrict__ X,
        const float* __restrict__ btab, const int* __restrict__ start,
        const int* __restrict__ slots, ushort_t* __restrict__ outz, int Nrows) {
    int w = __builtin_amdgcn_readfirstlane((blockIdx.x * 256 + threadIdx.x) >> 6);
    if (w >= Nrows) return;
    uint_t lane = threadIdx.x & 63;
    gine_row_s((const char*)X, (const char*)btab, slots, start[w], start[w + 1],
               w, outz, lane * 4u, lane * 8u);
}

__global__ __launch_bounds__(256) void k_segmean3(const ushort_t* __restrict__ X,
        const int* __restrict__ start, const int* __restrict__ slots,
        ushort_t* __restrict__ out, int Nrows) {
    int w = __builtin_amdgcn_readfirstlane((blockIdx.x * 256 + threadIdx.x) >> 6);
    if (w >= Nrows) return;
    uint_t lane = threadIdx.x & 63;
    segmean_row_s((const char*)X, slots, start[w], start[w + 1], w, out, lane * 4u);
}

// sorted-batch pool: one block per group, contiguous node range, no atomics
__global__ __launch_bounds__(256) void k_pool2(const ushort_t* __restrict__ xsum,
        const int* __restrict__ gs, float* __restrict__ out) {
    int g = blockIdx.x;
    int t = threadIdx.x, wv = t >> 6, lane = t & 63;
    int n0 = gs[g], n1 = gs[g + 1];
    float a0 = 0.f, a1 = 0.f;
    for (int n = n0 + wv; n < n1; n += 4) {
        uint_t u = *(const uint_t*)(xsum + (size_t)n * HD + lane * 2);
        a0 += b2f((ushort_t)(u & 0xFFFF));
        a1 += b2f((ushort_t)(u >> 16));
    }
    __shared__ float red[4][128];
    red[wv][lane * 2] = a0;
    red[wv][lane * 2 + 1] = a1;
    __syncthreads();
    if (wv == 0) {
        float s0 = red[0][lane * 2] + red[1][lane * 2]
                 + red[2][lane * 2] + red[3][lane * 2];
        float s1 = red[0][lane * 2 + 1] + red[1][lane * 2 + 1]
                 + red[2][lane * 2 + 1] + red[3][lane * 2 + 1];
        *(float2*)(out + (size_t)g * HD + lane * 2) = make_float2(s0, s1);
    }
}

// ---- stage one 128x128 bf16 weight into padded LDS (R9 champion form) ----
__device__ __forceinline__ void stage_w(ushort_t* Wl, const ushort_t* Wb, int t) {
    #pragma unroll
    for (int it = 0; it < 8; ++it) {
        int idx = it * 256 + t;
        uint4 v = *(const uint4*)(Wb + (size_t)idx * 8);
        int row = idx >> 4, col = (idx & 15) * 8;
        *(uint4*)&Wl[row * LSTR + col] = v;
    }
}

// ================= GEMM: C = maybe_relu(A @ W^T + bias) =================
__global__ __launch_bounds__(256) void k_gemm1(const ushort_t* __restrict__ A,
        const ushort_t* __restrict__ Wb, const float* __restrict__ bias,
        ushort_t* __restrict__ C, int M, int relu_flag) {
    __shared__ ushort_t Wl[128 * LSTR];
    const int t = threadIdx.x;
    stage_w(Wl, Wb, t);
    int lane = t & 63, wave = t >> 6;
    int m = lane & 15, quad = lane >> 4;
    int row = blockIdx.x * 64 + wave * 16 + m;
    int ar = row < M ? row : M - 1;
    const v8s* Ar = (const v8s*)(A + (size_t)ar * HD);
    v8s bfrag[4];
    #pragma unroll
    for (int c = 0; c < 4; ++c) bfrag[c] = Ar[c * 4 + quad];
    __syncthreads();
    v4f acc[8];
    #pragma unroll
    for (int nt = 0; nt < 8; ++nt) acc[nt] = (v4f){0.f, 0.f, 0.f, 0.f};
    #pragma unroll
    for (int nt = 0; nt < 8; ++nt) {
        #pragma unroll
        for (int c = 0; c < 4; ++c) {
            v8s wf = *(const v8s*)&Wl[(nt * 16 + m) * LSTR + c * 32 + quad * 8];
            acc[nt] = MFMA16(wf, bfrag[c], acc[nt]);
        }
    }
    if (row < M) {
        ushort_t* Cr = C + (size_t)row * HD;
        #pragma unroll
        for (int nt = 0; nt < 8; ++nt) {
            int col = nt * 16 + quad * 4;
            float4 b = *(const float4*)(bias + col);
            float v0 = acc[nt][0] + b.x, v1 = acc[nt][1] + b.y;
            float v2 = acc[nt][2] + b.z, v3 = acc[nt][3] + b.w;
            if (relu_flag) {
                v0 = fmaxf(v0, 0.f); v1 = fmaxf(v1, 0.f);
                v2 = fmaxf(v2, 0.f); v3 = fmaxf(v3, 0.f);
            }
            uint2 o;
            o.x = (uint_t)f2b(v0) | ((uint_t)f2b(v1) << 16);
            o.y = (uint_t)f2b(v2) | ((uint_t)f2b(v3) << 16);
            *(uint2*)(Cr + col) = o;
        }
    }
}

// ========== fused double GEMM: C = (relu(A@W1^T+b1)) @ W2^T + b2 ==========
// nmid lives in LDS (reuses Wl between phases); saves the nmid global
// round-trip + one launch + one A-staging pass vs two k_gemm1 calls.
__global__ __launch_bounds__(256) void k_gemm2(const ushort_t* __restrict__ A,
        const ushort_t* __restrict__ W1b, const float* __restrict__ b1,
        const ushort_t* __restrict__ W2b, const float* __restrict__ b2,
        ushort_t* __restrict__ C, int M) {
    __shared__ ushort_t Wl[128 * LSTR];
    const int t = threadIdx.x;
    stage_w(Wl, W1b, t);
    int lane = t & 63, wave = t >> 6;
    int m = lane & 15, quad = lane >> 4;
    int row = blockIdx.x * 64 + wave * 16 + m;
    int ar = row < M ? row : M - 1;
    const v8s* Ar = (const v8s*)(A + (size_t)ar * HD);
    v8s bfrag[4];
    #pragma unroll
    for (int c = 0; c < 4; ++c) bfrag[c] = Ar[c * 4 + quad];
    __syncthreads();
    v4f acc[8];
    #pragma unroll
    for (int nt = 0; nt < 8; ++nt) acc[nt] = (v4f){0.f, 0.f, 0.f, 0.f};
    #pragma unroll
    for (int nt = 0; nt < 8; ++nt) {
        #pragma unroll
        for (int c = 0; c < 4; ++c) {
            v8s wf = *(const v8s*)&Wl[(nt * 16 + m) * LSTR + c * 32 + quad * 8];
            acc[nt] = MFMA16(wf, bfrag[c], acc[nt]);
        }
    }
    __syncthreads();                       // all waves done reading W1
    // write nmid = relu(acc+b1) as bf16 into Wl[0 .. 64*LSTR)
    int lrow = wave * 16 + m;
    #pragma unroll
    for (int nt = 0; nt < 8; ++nt) {
        int col = nt * 16 + quad * 4;
        float4 b = *(const float4*)(b1 + col);
        float v0 = fmaxf(acc[nt][0] + b.x, 0.f);
        float v1 = fmaxf(acc[nt][1] + b.y, 0.f);
        float v2 = fmaxf(acc[nt][2] + b.z, 0.f);
        float v3 = fmaxf(acc[nt][3] + b.w, 0.f);
        uint2 o;
        o.x = (uint_t)f2b(v0) | ((uint_t)f2b(v1) << 16);
        o.y = (uint_t)f2b(v2) | ((uint_t)f2b(v3) << 16);
        *(uint2*)&Wl[lrow * LSTR + col] = o;
    }
    // intra-wave: this wave reads only its own 16 rows (written by itself)
    v8s bfrag2[4];
    #pragma unroll
    for (int c = 0; c < 4; ++c)
        bfrag2[c] = *(const v8s*)&Wl[lrow * LSTR + c * 32 + quad * 8];
    __syncthreads();                       // all waves read nmid before W2 overwrites
    stage_w(Wl, W2b, t);
    #pragma unroll
    for (int nt = 0; nt < 8; ++nt) acc[nt] = (v4f){0.f, 0.f, 0.f, 0.f};
    __syncthreads();
    #pragma unroll
    for (int nt = 0; nt < 8; ++nt) {
        #pragma unroll
        for (int c = 0; c < 4; ++c) {
            v8s wf = *(const v8s*)&Wl[(nt * 16 + m) * LSTR + c * 32 + quad * 8];
            acc[nt] = MFMA16(wf, bfrag2[c], acc[nt]);
        }
    }
    if (row < M) {
        ushort_t* Cr = C + (size_t)row * HD;
        #pragma unroll
        for (int nt = 0; nt < 8; ++nt) {
            int col = nt * 16 + quad * 4;
            float4 b = *(const float4*)(b2 + col);
            float v0 = acc[nt][0] + b.x, v1 = acc[nt][1] + b.y;
            float v2 = acc[nt][2] + b.z, v3 = acc[nt][3] + b.w;
            uint2 o;
            o.x = (uint_t)f2b(v0) | ((uint_t)f2b(v1) << 16);
            o.y = (uint_t)f2b(v2) | ((uint_t)f2b(v3) << 16);
            *(uint2*)(Cr + col) = o;
        }
    }
}

// ================= fused 4-GEMM tail =================
__global__ __launch_bounds__(256) void k_gemm_fused(
        const ushort_t* __restrict__ hmid, const ushort_t* __restrict__ h,
        const ushort_t* __restrict__ rootm, const ushort_t* __restrict__ h2,
        const int* __restrict__ node_ids, const float* __restrict__ vf,
        const ushort_t* __restrict__ W2g, const ushort_t* __restrict__ Wsk,
        const ushort_t* __restrict__ Wvv, const ushort_t* __restrict__ Wkk,
        const float* __restrict__ cb, ushort_t* __restrict__ hout, int M) {
    __shared__ ushort_t Wl[128 * LSTR];
    const int t = threadIdx.x;
    int lane = t & 63, wave = t >> 6;
    int m = lane & 15, quad = lane >> 4;
    int row = blockIdx.x * 64 + wave * 16 + m;
    int nid = node_ids[row];
    int nc = nid > 0 ? nid : 0;
    const ushort_t* Asrc[4];
    Asrc[0] = hmid + (size_t)row * HD;
    Asrc[1] = h + (size_t)row * HD;
    Asrc[2] = rootm + (size_t)nc * HD;
    Asrc[3] = h + (size_t)(row & ~15) * HD;
    const ushort_t* Ws[4] = {W2g, Wsk, Wvv, Wkk};
    v4f acc[8];
    #pragma unroll
    for (int nt = 0; nt < 8; ++nt) acc[nt] = (v4f){0.f, 0.f, 0.f, 0.f};
    for (int ph = 0; ph < 4; ++ph) {
        if (ph) __syncthreads();
        stage_w(Wl, Ws[ph], t);
        const v8s* Ar = (const v8s*)Asrc[ph];
        v8s bfrag[4];
        #pragma unroll
        for (int c = 0; c < 4; ++c) bfrag[c] = Ar[c * 4 + quad];
        __syncthreads();
        #pragma unroll
        for (int nt = 0; nt < 8; ++nt) {
            #pragma unroll
            for (int c = 0; c < 4; ++c) {
                v8s wf = *(const v8s*)&Wl[(nt * 16 + m) * LSTR + c * 32 + quad * 8];
                acc[nt] = MFMA16(wf, bfrag[c], acc[nt]);
            }
        }
    }
    float vfm = vf[row];
    const ushort_t* h2r = h2 + (size_t)nc * HD;
    ushort_t* Cr = hout + (size_t)row * HD;
    #pragma unroll
    for (int nt = 0; nt < 8; ++nt) {
        int col = nt * 16 + quad * 4;
        float4 b = *(const float4*)(cb + col);
        uint2 hh = *(const uint2*)(h2r + col);
        float v0 = acc[nt][0] + b.x + b2f((ushort_t)(hh.x & 0xFFFF));
        float v1 = acc[nt][1] + b.y + b2f((ushort_t)(hh.x >> 16));
        float v2 = acc[nt][2] + b.z + b2f((ushort_t)(hh.y & 0xFFFF));
        float v3 = acc[nt][3] + b.w + b2f((ushort_t)(hh.y >> 16));
        v0 = fmaxf(v0, 0.f) * vfm; v1 = fmaxf(v1, 0.f) * vfm;
        v2 = fmaxf(v2, 0.f) * vfm; v3 = fmaxf(v3, 0.f) * vfm;
        uint2 o;
        o.x = (uint_t)f2b(v0) | ((uint_t)f2b(v1) << 16);
        o.y = (uint_t)f2b(v2) | ((uint_t)f2b(v3) << 16);
        *(uint2*)(Cr + col) = o;
    }
}

// ================= launcher =================

extern "C" void kernel_launch(void* const* d_in, const int* in_sizes, int n_in,
                              void* d_out, int out_size, void* d_ws, size_t ws_size,
                              hipStream_t stream) {
    (void)n_in; (void)ws_size;
    const float* atom_table = (const float*)d_in[0];
    const float* bond_table = (const float*)d_in[1];
    const float* role_table = (const float*)d_in[2];
    const float* lW1 = (const float*)d_in[3];
    const float* lb1 = (const float*)d_in[4];
    const float* lW2 = (const float*)d_in[5];
    const float* lb2 = (const float*)d_in[6];
    const float* gW1 = (const float*)d_in[7];
    const float* gb1 = (const float*)d_in[8];
    const float* gW2 = (const float*)d_in[9];
    const float* gb2 = (const float*)d_in[10];
    const float* lbn_g = (const float*)d_in[11];
    const float* lbn_b = (const float*)d_in[12];
    const float* gbn_g = (const float*)d_in[13];
    const float* gbn_b = (const float*)d_in[14];
    const float* skipW = (const float*)d_in[15];
    const float* skipb = (const float*)d_in[16];
    const float* vvW = (const float*)d_in[17];
    const float* vvb = (const float*)d_in[18];
    const float* kkW = (const float*)d_in[19];
    const float* kkb = (const float*)d_in[20];
    const int* atom_ids = (const int*)d_in[21];
    const int* bond_ids_intra = (const int*)d_in[22];
    const int* bond_ids_global = (const int*)d_in[23];
    const int* intra_ei = (const int*)d_in[24];
    const int* node_ids = (const int*)d_in[25];
    const int* edge_index = (const int*)d_in[26];
    const int* batch = (const int*)d_in[28];

    const int SK = in_sizes[21];
    const int EI = in_sizes[22];
    const int EG = in_sizes[23];
    const int N  = in_sizes[28];
    const int L  = in_sizes[4] / HD;
    const int S  = SK / 16;
    const int G  = out_size / HD;

    // ---- workspace layout ----
    ushort_t* us = (ushort_t*)d_ws;
    ushort_t* hA    = us;
    ushort_t* hB    = hA + (size_t)SK * HD;
    ushort_t* hmid  = hB + (size_t)SK * HD;
    ushort_t* nmean = hmid + (size_t)SK * HD;
    ushort_t* nz    = nmean + (size_t)N * HD;
    ushort_t* nmid  = nz + (size_t)N * HD;
    ushort_t* h2    = nmid + (size_t)N * HD;
    ushort_t* rootm = h2 + (size_t)N * HD;
    ushort_t* wbuf  = rootm + (size_t)N * HD;
    float* fp = (float*)(wbuf + (size_t)7 * L * 16384);
    float* vf  = fp;
    float* cb  = vf + SK;
    float* b2g = cb + (size_t)L * 128;
    int* ip = (int*)(b2g + (size_t)L * 128);
    int* degI   = ip;
    int* degG   = degI + SK;
    int* degN   = degG + N;
    int* degR   = degN + N;
    int* startI = degR + N;
    int* startG = startI + SK + 1;
    int* startN = startG + N + 1;
    int* startR = startN + N + 1;
    int* slotI  = startR + N + 1;
    int* slotG  = slotI + EI;
    int* slotN  = slotG + EG;
    int* slotR  = slotN + SK;
    int* tsum   = slotR + S;        // 4*128
    int* toff   = tsum + 512;       // 4*128
    int* gs     = toff + 512;       // G+1

    const int B = 256;
    const int gwAll = ((SK + 2 * N) * 64 + B - 1) / B;
    const int gwN   = (N * 64 + B - 1) / B;
    const int ggSK  = (SK + 63) / 64;
    const int ggN   = (N + 63) / 64;
    const int* intra_src = intra_ei;
    const int* intra_dst = intra_ei + EI;
    const int* glob_src  = edge_index;
    const int* glob_dst  = edge_index + EG;

    // ---- weight/bias prep ----
    int wtot = 7 * L * 16384;
    k_convert_w<<<(wtot + B - 1) / B, B, 0, stream>>>(lW1, lW2, gW1, gW2, skipW,
            vvW, kkW, lbn_g, gbn_g, wbuf, L);
    k_bias<<<(L * 128 + B - 1) / B, B, 0, stream>>>(lb2, lbn_g, lbn_b, skipb, vvb,
            kkb, gb2, gbn_g, gbn_b, cb, b2g, L * 128);

    // ---- CSR build ----
    hipMemsetAsync(degI, 0, (size_t)(SK + 3 * N) * sizeof(int), stream);
    k_hist<<<(EI + B - 1) / B, B, 0, stream>>>(intra_dst, degI, EI, 1);
    k_hist<<<(EG + B - 1) / B, B, 0, stream>>>(glob_dst, degG, EG, 1);
    k_hist<<<(SK + B - 1) / B, B, 0, stream>>>(node_ids, degN, SK, 1);
    k_hist<<<(S + B - 1) / B, B, 0, stream>>>(node_ids, degR, S, 16);
    const int T0 = (SK + 1023) / 1024, TN = (N + 1023) / 1024;
    const int nsb = T0 + 3 * TN;
    k_scan_up<<<nsb, 1024, 0, stream>>>(degI, degG, degN, degR,
            startI, startG, startN, startR, tsum, T0, TN, SK, N);
    k_scan_mid<<<1, 256, 0, stream>>>(tsum, toff, startI, startG, startN, startR,
            T0, TN, SK, N);
    k_scan_down<<<nsb, 1024, 0, stream>>>(startI, startG, startN, startR,
            toff, T0, TN, SK, N);
    hipMemsetAsync(degI, 0, (size_t)(SK + 3 * N) * sizeof(int), stream);
    k_fill_edges<<<(EI + B - 1) / B, B, 0, stream>>>(intra_dst, intra_src,
            bond_ids_intra, startI, degI, slotI, EI);
    k_fill_edges<<<(EG + B - 1) / B, B, 0, stream>>>(glob_dst, glob_src,
            bond_ids_global, startG, degG, slotG, EG);
    k_fill<<<(SK + B - 1) / B, B, 0, stream>>>(node_ids, startN, degN, slotN, SK, 1);
    k_fill<<<(S + B - 1) / B, B, 0, stream>>>(node_ids, startR, degR, slotR, S, 16);
    k_gstart<<<(N + 1 + B - 1) / B, B, 0, stream>>>(batch, gs, N, G);

    // ---- init ----
    k_vf<<<(SK + B - 1) / B, B, 0, stream>>>(node_ids, vf, SK);
    k_init_h<<<(SK * 64 + B - 1) / B, B, 0, stream>>>(atom_table, role_table,
            atom_ids, vf, hA, SK);

    ushort_t* hcur = hA;
    ushort_t* zb   = hB;
    auto WB = [&](int fam, int l) { return wbuf + ((size_t)(fam * L + l)) * 16384; };

    for (int l = 0; l < L; ++l) {
        const size_t lb = (size_t)l * HD;
        // 1) combined: zb = hcur + intra agg; nmean = node segmean; rootm = root segmean
        k_gather_all3<<<gwAll, B, 0, stream>>>(hcur, bond_table,
                startI, slotI, zb, SK, startN, slotN, nmean,
                startR, slotR, rootm, N);
        // 2) hmid = relu(zb @ lW1^T + lb1)
        k_gemm1<<<ggSK, B, 0, stream>>>(zb, WB(0, l), lb1 + lb, hmid, SK, 1);
        // 3) nz = nmean + global-GINE agg
        k_gine_z3<<<gwN, B, 0, stream>>>(nmean, bond_table, startG, slotG, nz, N);
        // 4+5) h2 = relu(nz @ gW1^T + gb1) @ (gW2*gbn_g)^T + (gb2*gbn_g + gbn_b)
        k_gemm2<<<ggN, B, 0, stream>>>(nz, WB(2, l), gb1 + lb,
                WB(3, l), b2g + lb, h2, N);
        // 6) fused 4-GEMM tail -> zb
        k_gemm_fused<<<ggSK, B, 0, stream>>>(hmid, hcur, rootm, h2, node_ids, vf,
                WB(1, l), WB(4, l), WB(5, l), WB(6, l), cb + lb, zb, SK);
        ushort_t* tmp = hcur; hcur = zb; zb = tmp;
    }

    // final: node_embs = seg_mean(hcur); out = sorted-group sum (no atomics)
    k_segmean3<<<gwN, B, 0, stream>>>(hcur, startN, slotN, nmean, N);
    k_pool2<<<G, B, 0, stream>>>(nmean, gs, (float*)d_out);
}

// Round 9
// 870.655 us; speedup vs baseline: 1.1554x; 1.0022x over previous
//
#include <hip/hip_runtime.h>

typedef unsigned short ushort_t;
typedef unsigned int uint_t;
typedef __attribute__((ext_vector_type(8))) short v8s;   // 8 bf16 MFMA A/B frag
typedef __attribute__((ext_vector_type(4))) float v4f;   // MFMA C/D frag
typedef __attribute__((ext_vector_type(2))) float v2f;   // packed f32 pair

#define HD 128
#define MFMA16(a, b, c) __builtin_amdgcn_mfma_f32_16x16x32_bf16((a), (b), (c), 0, 0, 0)

__device__ __forceinline__ float b2f(ushort_t u) {
    union { uint_t i; float f; } v; v.i = ((uint_t)u) << 16; return v.f;
}
__device__ __forceinline__ ushort_t f2b(float f) {
    union { float f; uint_t i; } v; v.f = f;
    uint_t u = v.i;
    return (ushort_t)((u + 0x7FFFu + ((u >> 16) & 1u)) >> 16);
}
__device__ __forceinline__ v2f b2f2(uint_t u) {
    union { uint_t i; float f; } lo, hi;
    lo.i = u << 16; hi.i = u & 0xFFFF0000u;
    v2f r; r.x = lo.f; r.y = hi.f; return r;
}

// ================= CSR build =================

__global__ __launch_bounds__(256) void k_hist(const int* __restrict__ ids,
        int* __restrict__ deg, int M, int stride) {
    int i = blockIdx.x * blockDim.x + threadIdx.x;
    if (i >= M) return;
    int id = ids[(size_t)i * stride];
    if (id >= 0) atomicAdd(&deg[id], 1);
}

__device__ __forceinline__ void scan_map(int b, int T0, int TN, int& a, int& t) {
    if (b < T0) { a = 0; t = b; }
    else { int r = b - T0; a = 1 + r / TN; t = r % TN; }
}

__global__ __launch_bounds__(1024) void k_scan_up(
        const int* d0, const int* d1, const int* d2, const int* d3,
        int* s0, int* s1, int* s2, int* s3,
        int* __restrict__ tsum, int T0, int TN, int nSK, int nN) {
    int a, t;
    scan_map(blockIdx.x, T0, TN, a, t);
    const int* d = (a == 0) ? d0 : (a == 1) ? d1 : (a == 2) ? d2 : d3;
    int* s = (a == 0) ? s0 : (a == 1) ? s1 : (a == 2) ? s2 : s3;
    int n = (a == 0) ? nSK : nN;
    __shared__ int wsum[16];
    int tdx = threadIdx.x, lane = tdx & 63, wv = tdx >> 6;
    int i = t * 1024 + tdx;
    int v = (i < n) ? d[i] : 0;
    int x = v;
    #pragma unroll
    for (int off = 1; off < 64; off <<= 1) {
        int y = __shfl_up(x, off);
        if (lane >= off) x += y;
    }
    if (lane == 63) wsum[wv] = x;
    __syncthreads();
    int wo = 0, tot = 0;
    #pragma unroll
    for (int ww = 0; ww < 16; ++ww) {
        int sv = wsum[ww];
        if (ww < wv) wo += sv;
        tot += sv;
    }
    if (i < n) s[i] = wo + (x - v);
    if (tdx == 0) tsum[a * 128 + t] = tot;
}

__global__ __launch_bounds__(256) void k_scan_mid(
        const int* __restrict__ tsum, int* __restrict__ toff,
        int* s0, int* s1, int* s2, int* s3, int T0, int TN, int nSK, int nN) {
    int a = threadIdx.x >> 6, lane = threadIdx.x & 63;
    int T = (a == 0) ? T0 : TN;
    const int* ts = tsum + a * 128;
    int* to = toff + a * 128;
    int carry = 0;
    for (int base = 0; base < T; base += 64) {
        int idx = base + lane;
        int v = (idx < T) ? ts[idx] : 0;
        int x = v;
        #pragma unroll
        for (int off = 1; off < 64; off <<= 1) {
            int y = __shfl_up(x, off);
            if (lane >= off) x += y;
        }
        if (idx < T) to[idx] = carry + (x - v);
        carry += __shfl(x, 63);
    }
    if (lane == 0) {
        int* s = (a == 0) ? s0 : (a == 1) ? s1 : (a == 2) ? s2 : s3;
        s[(a == 0) ? nSK : nN] = carry;
    }
}

__global__ __launch_bounds__(1024) void k_scan_down(
        int* s0, int* s1, int* s2, int* s3,
        const int* __restrict__ toff, int T0, int TN, int nSK, int nN) {
    int a, t;
    scan_map(blockIdx.x, T0, TN, a, t);
    int* s = (a == 0) ? s0 : (a == 1) ? s1 : (a == 2) ? s2 : s3;
    int n = (a == 0) ? nSK : nN;
    int i = t * 1024 + threadIdx.x;
    if (i < n) s[i] += toff[a * 128 + t];
}

__global__ __launch_bounds__(256) void k_fill(const int* __restrict__ ids,
        const int* __restrict__ start, int* __restrict__ cursor,
        int* __restrict__ slots, int M, int stride) {
    int i = blockIdx.x * blockDim.x + threadIdx.x;
    if (i >= M) return;
    int id = ids[(size_t)i * stride];
    if (id < 0) return;
    int pos = start[id] + atomicAdd(&cursor[id], 1);
    slots[pos] = i * stride;
}

__global__ __launch_bounds__(256) void k_fill_edges(const int* __restrict__ dst,
        const int* __restrict__ src, const int* __restrict__ bids,
        const int* __restrict__ start, int* __restrict__ cursor,
        int* __restrict__ slots, int E) {
    int e = blockIdx.x * blockDim.x + threadIdx.x;
    if (e >= E) return;
    int d = dst[e];
    if (d < 0) return;
    int pos = start[d] + atomicAdd(&cursor[d], 1);
    slots[pos] = src[e] | (bids[e] << 20);
}

__global__ __launch_bounds__(256) void k_gstart(const int* __restrict__ batch,
        int* __restrict__ gs, int N, int G) {
    int n = blockIdx.x * blockDim.x + threadIdx.x;
    if (n > N) return;
    int bn = (n < N) ? batch[n] : G;
    int bp = (n == 0) ? -1 : batch[n - 1];
    for (int g = bp + 1; g <= bn; ++g)
        if (g <= G) gs[g] = n;
}

// ================= weight/bias prep =================

__global__ __launch_bounds__(256) void k_convert_w(
        const float* lW1, const float* lW2, const float* gW1, const float* gW2,
        const float* skipW, const float* vvW, const float* kkW,
        const float* lbn_g, const float* gbn_g,
        ushort_t* __restrict__ wbuf, int L) {
    int idx = blockIdx.x * blockDim.x + threadIdx.x;
    int total = 7 * L * 16384;
    if (idx >= total) return;
    int fam = idx / (L * 16384);
    int r = idx % (L * 16384);
    int l = r / 16384, e = r % 16384, n = e / 128;
    const float* src;
    float sc = 1.0f;
    switch (fam) {
        case 0: src = lW1; break;
        case 1: src = lW2; sc = lbn_g[l * 128 + n]; break;
        case 2: src = gW1; break;
        case 3: src = gW2; sc = gbn_g[l * 128 + n]; break;
        case 4: src = skipW; break;
        case 5: src = vvW; break;
        default: src = kkW; break;
    }
    wbuf[idx] = f2b(src[(size_t)l * 16384 + e] * sc);
}

__global__ __launch_bounds__(256) void k_bias(
        const float* lb2, const float* lbn_g, const float* lbn_b,
        const float* skipb, const float* vvb, const float* kkb,
        const float* gb2, const float* gbn_g, const float* gbn_b,
        float* __restrict__ cb, float* __restrict__ b2g, int total) {
    int i = blockIdx.x * blockDim.x + threadIdx.x;
    if (i >= total) return;
    cb[i] = lb2[i] * lbn_g[i] + lbn_b[i] + skipb[i] + vvb[i] + kkb[i];
    b2g[i] = gb2[i] * gbn_g[i] + gbn_b[i];
}

// ================= elementwise =================

__global__ __launch_bounds__(256) void k_vf(const int* __restrict__ node_ids,
        float* __restrict__ vf, int SK) {
    int i = blockIdx.x * blockDim.x + threadIdx.x;
    if (i < SK) vf[i] = (node_ids[i] >= 0) ? 1.0f : 0.0f;
}

__global__ __launch_bounds__(256) void k_init_h(const float* __restrict__ at,
        const float* __restrict__ rt, const int* __restrict__ atom_ids,
        const float* __restrict__ vf, ushort_t* __restrict__ h, int SK) {
    int t = blockIdx.x * blockDim.x + threadIdx.x;
    int i = t >> 6, lane = t & 63;
    if (i >= SK) return;
    float2 a = ((const float2*)(at + (size_t)atom_ids[i] * HD))[lane];
    int role = ((i & 15) == 0) ? 1 : 0;
    float2 r = ((const float2*)(rt + (size_t)role * HD))[lane];
    float m = vf[i];
    uint_t o = (uint_t)f2b((a.x + r.x) * m) | ((uint_t)f2b((a.y + r.y) * m) << 16);
    *(uint_t*)(h + (size_t)i * HD + lane * 2) = o;
}

// ---- R2 champion scalar-walk gather: ONE row per wave, row index in SGPR via
//      readfirstlane. start/slots loads + address decode on the scalar pipe;
//      X/btab loads are global_load with SGPR base + constant per-lane voffset.
//      Intra rows (deg~4): 8/4/2/1; global rows (deg~16): 16/8/4/2/1 (R8). ----

#define HE(i) int e##i = slots[p + i];
#define HX(i) uint_t u##i = *(const uint_t*)(Xb + (((uint_t)(e##i & 0xFFFFF)) << 8) + xo);
#define HQ(i) float2 q##i = *(const float2*)(Bb + (((uint_t)e##i >> 20) << 9) + bo);
#define HA(i) { v2f qv; qv.x = q##i.x; qv.y = q##i.y; \
                a += __builtin_elementwise_max(b2f2(u##i) + qv, z); }

__device__ __forceinline__ void gine_tail(const char* __restrict__ Xb,
        const char* __restrict__ Bb, const int* __restrict__ slots,
        int p, int s1, v2f& a, uint_t xo, uint_t bo) {
    const v2f z = {0.f, 0.f};
    for (; p + 7 < s1; p += 8) {
        HE(0) HE(1) HE(2) HE(3) HE(4) HE(5) HE(6) HE(7)
        HX(0) HX(1) HX(2) HX(3) HX(4) HX(5) HX(6) HX(7)
        HQ(0) HQ(1) HQ(2) HQ(3) HQ(4) HQ(5) HQ(6) HQ(7)
        HA(0) HA(1) HA(2) HA(3) HA(4) HA(5) HA(6) HA(7)
    }
    if (p + 3 < s1) {
        HE(0) HE(1) HE(2) HE(3)
        HX(0) HX(1) HX(2) HX(3)
        HQ(0) HQ(1) HQ(2) HQ(3)
        HA(0) HA(1) HA(2) HA(3)
        p += 4;
    }
    if (p + 1 < s1) {
        HE(0) HE(1)
        HX(0) HX(1)
        HQ(0) HQ(1)
        HA(0) HA(1)
        p += 2;
    }
    if (p < s1) {
        HE(0)
        HX(0)
        HQ(0)
        HA(0)
    }
}

__device__ __forceinline__ void gine_finish(const char* __restrict__ Xb,
        int row, v2f a, ushort_t* __restrict__ outz, uint_t xo) {
    uint_t su = *(const uint_t*)(Xb + (((uint_t)row) << 8) + xo);
    v2f sv = b2f2(su);
    float f0 = a.x + sv.x, f1 = a.y + sv.y;
    *(uint_t*)((char*)outz + (((uint_t)row) << 8) + xo) =
        (uint_t)f2b(f0) | ((uint_t)f2b(f1) << 16);
}

__device__ __forceinline__ void gine_row_s(const char* __restrict__ Xb,
        const char* __restrict__ Bb, const int* __restrict__ slots,
        int s0, int s1, int row, ushort_t* __restrict__ outz, uint_t xo, uint_t bo) {
    v2f a = {0.f, 0.f};
    gine_tail(Xb, Bb, slots, s0, s1, a, xo, bo);
    gine_finish(Xb, row, a, outz, xo);
}

// deg~16 variant: 16-edge leading block keeps 16 X-chains in flight per round
__device__ __forceinline__ void gine_row_s16(const char* __restrict__ Xb,
        const char* __restrict__ Bb, const int* __restrict__ slots,
        int s0, int s1, int row, ushort_t* __restrict__ outz, uint_t xo, uint_t bo) {
    const v2f z = {0.f, 0.f};
    v2f a = z;
    int p = s0;
    for (; p + 15 < s1; p += 16) {
        HE(0) HE(1) HE(2) HE(3) HE(4) HE(5) HE(6) HE(7)
        HE(8) HE(9) HE(10) HE(11) HE(12) HE(13) HE(14) HE(15)
        HX(0) HX(1) HX(2) HX(3) HX(4) HX(5) HX(6) HX(7)
        HX(8) HX(9) HX(10) HX(11) HX(12) HX(13) HX(14) HX(15)
        HQ(0) HQ(1) HQ(2) HQ(3) HQ(4) HQ(5) HQ(6) HQ(7)
        HA(0) HA(1) HA(2) HA(3) HA(4) HA(5) HA(6) HA(7)
        HQ(8) HQ(9) HQ(10) HQ(11) HQ(12) HQ(13) HQ(14) HQ(15)
        HA(8) HA(9) HA(10) HA(11) HA(12) HA(13) HA(14) HA(15)
    }
    gine_tail(Xb, Bb, slots, p, s1, a, xo, bo);
    gine_finish(Xb, row, a, outz, xo);
}

#define SE(i) int r##i = slots[p + i];
#define SX(i) uint_t u##i = *(const uint_t*)(Xb + (((uint_t)r##i) << 8) + xo);
#define SA(i) a += b2f2(u##i);

__device__ __forceinline__ void segmean_row_s(const char* __restrict__ Xb,
        const int* __restrict__ slots, int s0, int s1, int row,
        ushort_t* __restrict__ out, uint_t xo) {
    float inv = 1.0f / fmaxf((float)(s1 - s0), 1.0f);
    const v2f z = {0.f, 0.f};
    v2f a = z;
    int p = s0;
    for (; p + 7 < s1; p += 8) {
        SE(0) SE(1) SE(2) SE(3) SE(4) SE(5) SE(6) SE(7)
        SX(0) SX(1) SX(2) SX(3) SX(4) SX(5) SX(6) SX(7)
        SA(0) SA(1) SA(2) SA(3) SA(4) SA(5) SA(6) SA(7)
    }
    if (p + 3 < s1) {
        SE(0) SE(1) SE(2) SE(3)
        SX(0) SX(1) SX(2) SX(3)
        SA(0) SA(1) SA(2) SA(3)
        p += 4;
    }
    if (p + 1 < s1) {
        SE(0) SE(1)
        SX(0) SX(1)
        SA(0) SA(1)
        p += 2;
    }
    if (p < s1) {
        SE(0)
        SX(0)
        SA(0)
    }
    *(uint_t*)((char*)out + (((uint_t)row) << 8) + xo) =
        (uint_t)f2b(a.x * inv) | ((uint_t)f2b(a.y * inv) << 16);
}

// combined: waves [0,SK) intra-GINE; [SK,SK+N) node segmean; [SK+N,SK+2N) root segmean
__global__ __launch_bounds__(256) void k_gather_all3(const ushort_t* __restrict__ X,
        const float* __restrict__ btab,
        const int* __restrict__ startI, const int* __restrict__ slotI,
        ushort_t* __restrict__ outz, int SK,
        const int* __restrict__ startN, const int* __restrict__ slotN,
        ushort_t* __restrict__ nmean,
        const int* __restrict__ startR, const int* __restrict__ slotR,
        ushort_t* __restrict__ rootm, int N) {
    int w = __builtin_amdgcn_readfirstlane((blockIdx.x * 256 + threadIdx.x) >> 6);
    uint_t lane = threadIdx.x & 63;
    uint_t xo = lane * 4u, bo = lane * 8u;
    const char* Xb = (const char*)X;
    if (w < SK) {
        gine_row_s(Xb, (const char*)btab, slotI, startI[w], startI[w + 1], w,
                   outz, xo, bo);
    } else if (w < SK + N) {
        int r = w - SK;
        segmean_row_s(Xb, slotN, startN[r], startN[r + 1], r, nmean, xo);
    } else if (w < SK + 2 * N) {
        int r = w - SK - N;
        segmean_row_s(Xb, slotR, startR[r], startR[r + 1], r, rootm, xo);
    }
}

__global__ __launch_bounds__(256) void k_gine_z7(const ushort_t* __restrict__ X,
        const float* __restrict__ btab, const int* __restrict__ start,
        const int* __restrict__ slots, ushort_t* __restrict__ outz, int Nrows) {
    int w = __builtin_amdgcn_readfirstlane((blockIdx.x * 256 + threadIdx.x) >> 6);
    if (w >= Nrows) return;
    uint_t lane = threadIdx.x & 63;
    gine_row_s16((const char*)X, (const char*)btab, slots, start[w], start[w + 1],
                 w, outz, lane * 4u, lane * 8u);
}

__global__ __launch_bounds__(256) void k_segmean3(const ushort_t* __restrict__ X,
        const int* __restrict__ start, const int* __restrict__ slots,
        ushort_t* __restrict__ out, int Nrows) {
    int w = __builtin_amdgcn_readfirstlane((blockIdx.x * 256 + threadIdx.x) >> 6);
    if (w >= Nrows) return;
    uint_t lane = threadIdx.x & 63;
    segmean_row_s((const char*)X, slots, start[w], start[w + 1], w, out, lane * 4u);
}

// sorted-batch pool: one block per group, contiguous node range, no atomics
__global__ __launch_bounds__(256) void k_pool2(const ushort_t* __restrict__ xsum,
        const int* __restrict__ gs, float* __restrict__ out) {
    int g = blockIdx.x;
    int t = threadIdx.x, wv = t >> 6, lane = t & 63;
    int n0 = gs[g], n1 = gs[g + 1];
    float a0 = 0.f, a1 = 0.f;
    for (int n = n0 + wv; n < n1; n += 4) {
        uint_t u = *(const uint_t*)(xsum + (size_t)n * HD + lane * 2);
        a0 += b2f((ushort_t)(u & 0xFFFF));
        a1 += b2f((ushort_t)(u >> 16));
    }
    __shared__ float red[4][128];
    red[wv][lane * 2] = a0;
    red[wv][lane * 2 + 1] = a1;
    __syncthreads();
    if (wv == 0) {
        float s0 = red[0][lane * 2] + red[1][lane * 2]
                 + red[2][lane * 2] + red[3][lane * 2];
        float s1 = red[0][lane * 2 + 1] + red[1][lane * 2 + 1]
                 + red[2][lane * 2 + 1] + red[3][lane * 2 + 1];
        *(float2*)(out + (size_t)g * HD + lane * 2) = make_float2(s0, s1);
    }
}

// ---- stage one 128x128 bf16 weight into XOR-swizzled LDS (R8: kills the
//      4.1M bank-conflict cycles the LSTR=136 pad left). 16B unit u of row r
//      lives at u^(r&7); read side uses ((c*4+quad)^(m&7)) -> uniform 8
//      lanes/bank-quad = HW minimum. ----
__device__ __forceinline__ void stage_w(ushort_t* Wl, const ushort_t* Wb, int t) {
    #pragma unroll
    for (int it = 0; it < 8; ++it) {
        int idx = it * 256 + t;
        uint4 v = *(const uint4*)(Wb + (size_t)idx * 8);
        int row = idx >> 4, u = idx & 15;
        *(uint4*)&Wl[row * 128 + ((u ^ (row & 7)) << 3)] = v;
    }
}

#define WREAD(nt, c) (*(const v8s*)&Wl[((nt) * 16 + m) * 128 + \
        ((((c) * 4 + quad) ^ msw) << 3)])

// ================= GEMM: C = maybe_relu(A @ W^T + bias) =================
__global__ __launch_bounds__(256) void k_gemm1(const ushort_t* __restrict__ A,
        const ushort_t* __restrict__ Wb, const float* __restrict__ bias,
        ushort_t* __restrict__ C, int M, int relu_flag) {
    __shared__ ushort_t Wl[128 * 128];
    const int t = threadIdx.x;
    stage_w(Wl, Wb, t);
    int lane = t & 63, wave = t >> 6;
    int m = lane & 15, quad = lane >> 4;
    int msw = m & 7;
    int row = blockIdx.x * 64 + wave * 16 + m;
    int ar = row < M ? row : M - 1;
    const v8s* Ar = (const v8s*)(A + (size_t)ar * HD);
    v8s bfrag[4];
    #pragma unroll
    for (int c = 0; c < 4; ++c) bfrag[c] = Ar[c * 4 + quad];
    __syncthreads();
    v4f acc[8];
    #pragma unroll
    for (int nt = 0; nt < 8; ++nt) acc[nt] = (v4f){0.f, 0.f, 0.f, 0.f};
    #pragma unroll
    for (int nt = 0; nt < 8; ++nt) {
        #pragma unroll
        for (int c = 0; c < 4; ++c)
            acc[nt] = MFMA16(WREAD(nt, c), bfrag[c], acc[nt]);
    }
    if (row < M) {
        ushort_t* Cr = C + (size_t)row * HD;
        #pragma unroll
        for (int nt = 0; nt < 8; ++nt) {
            int col = nt * 16 + quad * 4;
            float4 b = *(const float4*)(bias + col);
            float v0 = acc[nt][0] + b.x, v1 = acc[nt][1] + b.y;
            float v2 = acc[nt][2] + b.z, v3 = acc[nt][3] + b.w;
            if (relu_flag) {
                v0 = fmaxf(v0, 0.f); v1 = fmaxf(v1, 0.f);
                v2 = fmaxf(v2, 0.f); v3 = fmaxf(v3, 0.f);
            }
            uint2 o;
            o.x = (uint_t)f2b(v0) | ((uint_t)f2b(v1) << 16);
            o.y = (uint_t)f2b(v2) | ((uint_t)f2b(v3) << 16);
            *(uint2*)(Cr + col) = o;
        }
    }
}

// ========== fused double GEMM: C = (relu(A@W1^T+b1)) @ W2^T + b2 ==========
__global__ __launch_bounds__(256) void k_gemm2(const ushort_t* __restrict__ A,
        const ushort_t* __restrict__ W1b, const float* __restrict__ b1,
        const ushort_t* __restrict__ W2b, const float* __restrict__ b2,
        ushort_t* __restrict__ C, int M) {
    __shared__ ushort_t Wl[128 * 128];
    const int t = threadIdx.x;
    stage_w(Wl, W1b, t);
    int lane = t & 63, wave = t >> 6;
    int m = lane & 15, quad = lane >> 4;
    int msw = m & 7;
    int row = blockIdx.x * 64 + wave * 16 + m;
    int ar = row < M ? row : M - 1;
    const v8s* Ar = (const v8s*)(A + (size_t)ar * HD);
    v8s bfrag[4];
    #pragma unroll
    for (int c = 0; c < 4; ++c) bfrag[c] = Ar[c * 4 + quad];
    __syncthreads();
    v4f acc[8];
    #pragma unroll
    for (int nt = 0; nt < 8; ++nt) acc[nt] = (v4f){0.f, 0.f, 0.f, 0.f};
    #pragma unroll
    for (int nt = 0; nt < 8; ++nt) {
        #pragma unroll
        for (int c = 0; c < 4; ++c)
            acc[nt] = MFMA16(WREAD(nt, c), bfrag[c], acc[nt]);
    }
    __syncthreads();                       // all waves done reading W1
    // write nmid = relu(acc+b1) as bf16 into Wl rows [wave*16+m], swizzled
    int lrow = wave * 16 + m;
    #pragma unroll
    for (int nt = 0; nt < 8; ++nt) {
        int col = nt * 16 + quad * 4;
        float4 b = *(const float4*)(b1 + col);
        float v0 = fmaxf(acc[nt][0] + b.x, 0.f);
        float v1 = fmaxf(acc[nt][1] + b.y, 0.f);
        float v2 = fmaxf(acc[nt][2] + b.z, 0.f);
        float v3 = fmaxf(acc[nt][3] + b.w, 0.f);
        uint2 o;
        o.x = (uint_t)f2b(v0) | ((uint_t)f2b(v1) << 16);
        o.y = (uint_t)f2b(v2) | ((uint_t)f2b(v3) << 16);
        *(uint2*)&Wl[lrow * 128 + (((2 * nt + (quad >> 1)) ^ msw) << 3)
                     + ((quad & 1) << 2)] = o;
    }
    // intra-wave read-back of own rows (same swizzle)
    v8s bfrag2[4];
    #pragma unroll
    for (int c = 0; c < 4; ++c)
        bfrag2[c] = *(const v8s*)&Wl[lrow * 128 + (((c * 4 + quad) ^ msw) << 3)];
    __syncthreads();                       // all waves read nmid before W2 overwrites
    stage_w(Wl, W2b, t);
    #pragma unroll
    for (int nt = 0; nt < 8; ++nt) acc[nt] = (v4f){0.f, 0.f, 0.f, 0.f};
    __syncthreads();
    #pragma unroll
    for (int nt = 0; nt < 8; ++nt) {
        #pragma unroll
        for (int c = 0; c < 4; ++c)
            acc[nt] = MFMA16(WREAD(nt, c), bfrag2[c], acc[nt]);
    }
    if (row < M) {
        ushort_t* Cr = C + (size_t)row * HD;
        #pragma unroll
        for (int nt = 0; nt < 8; ++nt) {
            int col = nt * 16 + quad * 4;
            float4 b = *(const float4*)(b2 + col);
            float v0 = acc[nt][0] + b.x, v1 = acc[nt][1] + b.y;
            float v2 = acc[nt][2] + b.z, v3 = acc[nt][3] + b.w;
            uint2 o;
            o.x = (uint_t)f2b(v0) | ((uint_t)f2b(v1) << 16);
            o.y = (uint_t)f2b(v2) | ((uint_t)f2b(v3) << 16);
            *(uint2*)(Cr + col) = o;
        }
    }
}

// ================= fused 4-GEMM tail =================
__global__ __launch_bounds__(256) void k_gemm_fused(
        const ushort_t* __restrict__ hmid, const ushort_t* __restrict__ h,
        const ushort_t* __restrict__ rootm, const ushort_t* __restrict__ h2,
        const int* __restrict__ node_ids, const float* __restrict__ vf,
        const ushort_t* __restrict__ W2g, const ushort_t* __restrict__ Wsk,
        const ushort_t* __restrict__ Wvv, const ushort_t* __restrict__ Wkk,
        const float* __restrict__ cb, ushort_t* __restrict__ hout, int M) {
    __shared__ ushort_t Wl[128 * 128];
    const int t = threadIdx.x;
    int lane = t & 63, wave = t >> 6;
    int m = lane & 15, quad = lane >> 4;
    int msw = m & 7;
    int row = blockIdx.x * 64 + wave * 16 + m;
    int nid = node_ids[row];
    int nc = nid > 0 ? nid : 0;
    const ushort_t* Asrc[4];
    Asrc[0] = hmid + (size_t)row * HD;
    Asrc[1] = h + (size_t)row * HD;
    Asrc[2] = rootm + (size_t)nc * HD;
    Asrc[3] = h + (size_t)(row & ~15) * HD;
    const ushort_t* Ws[4] = {W2g, Wsk, Wvv, Wkk};
    v4f acc[8];
    #pragma unroll
    for (int nt = 0; nt < 8; ++nt) acc[nt] = (v4f){0.f, 0.f, 0.f, 0.f};
    for (int ph = 0; ph < 4; ++ph) {
        if (ph) __syncthreads();
        stage_w(Wl, Ws[ph], t);
        const v8s* Ar = (const v8s*)Asrc[ph];
        v8s bfrag[4];
        #pragma unroll
        for (int c = 0; c < 4; ++c) bfrag[c] = Ar[c * 4 + quad];
        __syncthreads();
        #pragma unroll
        for (int nt = 0; nt < 8; ++nt) {
            #pragma unroll
            for (int c = 0; c < 4; ++c)
                acc[nt] = MFMA16(WREAD(nt, c), bfrag[c], acc[nt]);
        }
    }
    float vfm = vf[row];
    const ushort_t* h2r = h2 + (size_t)nc * HD;
    ushort_t* Cr = hout + (size_t)row * HD;
    #pragma unroll
    for (int nt = 0; nt < 8; ++nt) {
        int col = nt * 16 + quad * 4;
        float4 b = *(const float4*)(cb + col);
        uint2 hh = *(const uint2*)(h2r + col);
        float v0 = acc[nt][0] + b.x + b2f((ushort_t)(hh.x & 0xFFFF));
        float v1 = acc[nt][1] + b.y + b2f((ushort_t)(hh.x >> 16));
        float v2 = acc[nt][2] + b.z + b2f((ushort_t)(hh.y & 0xFFFF));
        float v3 = acc[nt][3] + b.w + b2f((ushort_t)(hh.y >> 16));
        v0 = fmaxf(v0, 0.f) * vfm; v1 = fmaxf(v1, 0.f) * vfm;
        v2 = fmaxf(v2, 0.f) * vfm; v3 = fmaxf(v3, 0.f) * vfm;
        uint2 o;
        o.x = (uint_t)f2b(v0) | ((uint_t)f2b(v1) << 16);
        o.y = (uint_t)f2b(v2) | ((uint_t)f2b(v3) << 16);
        *(uint2*)(Cr + col) = o;
    }
}

// ================= launcher =================

extern "C" void kernel_launch(void* const* d_in, const int* in_sizes, int n_in,
                              void* d_out, int out_size, void* d_ws, size_t ws_size,
                              hipStream_t stream) {
    (void)n_in; (void)ws_size;
    const float* atom_table = (const float*)d_in[0];
    const float* bond_table = (const float*)d_in[1];
    const float* role_table = (const float*)d_in[2];
    const float* lW1 = (const float*)d_in[3];
    const float* lb1 = (const float*)d_in[4];
    const float* lW2 = (const float*)d_in[5];
    const float* lb2 = (const float*)d_in[6];
    const float* gW1 = (const float*)d_in[7];
    const float* gb1 = (const float*)d_in[8];
    const float* gW2 = (const float*)d_in[9];
    const float* gb2 = (const float*)d_in[10];
    const float* lbn_g = (const float*)d_in[11];
    const float* lbn_b = (const float*)d_in[12];
    const float* gbn_g = (const float*)d_in[13];
    const float* gbn_b = (const float*)d_in[14];
    const float* skipW = (const float*)d_in[15];
    const float* skipb = (const float*)d_in[16];
    const float* vvW = (const float*)d_in[17];
    const float* vvb = (const float*)d_in[18];
    const float* kkW = (const float*)d_in[19];
    const float* kkb = (const float*)d_in[20];
    const int* atom_ids = (const int*)d_in[21];
    const int* bond_ids_intra = (const int*)d_in[22];
    const int* bond_ids_global = (const int*)d_in[23];
    const int* intra_ei = (const int*)d_in[24];
    const int* node_ids = (const int*)d_in[25];
    const int* edge_index = (const int*)d_in[26];
    const int* batch = (const int*)d_in[28];

    const int SK = in_sizes[21];
    const int EI = in_sizes[22];
    const int EG = in_sizes[23];
    const int N  = in_sizes[28];
    const int L  = in_sizes[4] / HD;
    const int S  = SK / 16;
    const int G  = out_size / HD;

    // ---- workspace layout ----
    ushort_t* us = (ushort_t*)d_ws;
    ushort_t* hA    = us;
    ushort_t* hB    = hA + (size_t)SK * HD;
    ushort_t* hmid  = hB + (size_t)SK * HD;
    ushort_t* nmean = hmid + (size_t)SK * HD;
    ushort_t* nz    = nmean + (size_t)N * HD;
    ushort_t* nmid  = nz + (size_t)N * HD;
    ushort_t* h2    = nmid + (size_t)N * HD;
    ushort_t* rootm = h2 + (size_t)N * HD;
    ushort_t* wbuf  = rootm + (size_t)N * HD;
    float* fp = (float*)(wbuf + (size_t)7 * L * 16384);
    float* vf  = fp;
    float* cb  = vf + SK;
    float* b2g = cb + (size_t)L * 128;
    int* ip = (int*)(b2g + (size_t)L * 128);
    int* degI   = ip;
    int* degG   = degI + SK;
    int* degN   = degG + N;
    int* degR   = degN + N;
    int* startI = degR + N;
    int* startG = startI + SK + 1;
    int* startN = startG + N + 1;
    int* startR = startN + N + 1;
    int* slotI  = startR + N + 1;
    int* slotG  = slotI + EI;
    int* slotN  = slotG + EG;
    int* slotR  = slotN + SK;
    int* tsum   = slotR + S;        // 4*128
    int* toff   = tsum + 512;       // 4*128
    int* gs     = toff + 512;       // G+1

    const int B = 256;
    const int gwAll = ((SK + 2 * N) * 64 + B - 1) / B;
    const int gwN   = (N * 64 + B - 1) / B;
    const int ggSK  = (SK + 63) / 64;
    const int ggN   = (N + 63) / 64;
    const int* intra_src = intra_ei;
    const int* intra_dst = intra_ei + EI;
    const int* glob_src  = edge_index;
    const int* glob_dst  = edge_index + EG;

    // ---- weight/bias prep ----
    int wtot = 7 * L * 16384;
    k_convert_w<<<(wtot + B - 1) / B, B, 0, stream>>>(lW1, lW2, gW1, gW2, skipW,
            vvW, kkW, lbn_g, gbn_g, wbuf, L);
    k_bias<<<(L * 128 + B - 1) / B, B, 0, stream>>>(lb2, lbn_g, lbn_b, skipb, vvb,
            kkb, gb2, gbn_g, gbn_b, cb, b2g, L * 128);

    // ---- CSR build ----
    hipMemsetAsync(degI, 0, (size_t)(SK + 3 * N) * sizeof(int), stream);
    k_hist<<<(EI + B - 1) / B, B, 0, stream>>>(intra_dst, degI, EI, 1);
    k_hist<<<(EG + B - 1) / B, B, 0, stream>>>(glob_dst, degG, EG, 1);
    k_hist<<<(SK + B - 1) / B, B, 0, stream>>>(node_ids, degN, SK, 1);
    k_hist<<<(S + B - 1) / B, B, 0, stream>>>(node_ids, degR, S, 16);
    const int T0 = (SK + 1023) / 1024, TN = (N + 1023) / 1024;
    const int nsb = T0 + 3 * TN;
    k_scan_up<<<nsb, 1024, 0, stream>>>(degI, degG, degN, degR,
            startI, startG, startN, startR, tsum, T0, TN, SK, N);
    k_scan_mid<<<1, 256, 0, stream>>>(tsum, toff, startI, startG, startN, startR,
            T0, TN, SK, N);
    k_scan_down<<<nsb, 1024, 0, stream>>>(startI, startG, startN, startR,
            toff, T0, TN, SK, N);
    hipMemsetAsync(degI, 0, (size_t)(SK + 3 * N) * sizeof(int), stream);
    k_fill_edges<<<(EI + B - 1) / B, B, 0, stream>>>(intra_dst, intra_src,
            bond_ids_intra, startI, degI, slotI, EI);
    k_fill_edges<<<(EG + B - 1) / B, B, 0, stream>>>(glob_dst, glob_src,
            bond_ids_global, startG, degG, slotG, EG);
    k_fill<<<(SK + B - 1) / B, B, 0, stream>>>(node_ids, startN, degN, slotN, SK, 1);
    k_fill<<<(S + B - 1) / B, B, 0, stream>>>(node_ids, startR, degR, slotR, S, 16);
    k_gstart<<<(N + 1 + B - 1) / B, B, 0, stream>>>(batch, gs, N, G);

    // ---- init ----
    k_vf<<<(SK + B - 1) / B, B, 0, stream>>>(node_ids, vf, SK);
    k_init_h<<<(SK * 64 + B - 1) / B, B, 0, stream>>>(atom_table, role_table,
            atom_ids, vf, hA, SK);

    ushort_t* hcur = hA;
    ushort_t* zb   = hB;
    auto WB = [&](int fam, int l) { return wbuf + ((size_t)(fam * L + l)) * 16384; };

    for (int l = 0; l < L; ++l) {
        const size_t lb = (size_t)l * HD;
        // 1) combined: zb = hcur + intra agg; nmean = node segmean; rootm = root segmean
        k_gather_all3<<<gwAll, B, 0, stream>>>(hcur, bond_table,
                startI, slotI, zb, SK, startN, slotN, nmean,
                startR, slotR, rootm, N);
        // 2) hmid = relu(zb @ lW1^T + lb1)
        k_gemm1<<<ggSK, B, 0, stream>>>(zb, WB(0, l), lb1 + lb, hmid, SK, 1);
        // 3) nz = nmean + global-GINE agg (deg~16: 16-wide main block)
        k_gine_z7<<<gwN, B, 0, stream>>>(nmean, bond_table, startG, slotG, nz, N);
        // 4+5) h2 = relu(nz @ gW1^T + gb1) @ (gW2*gbn_g)^T + (gb2*gbn_g + gbn_b)
        k_gemm2<<<ggN, B, 0, stream>>>(nz, WB(2, l), gb1 + lb,
                WB(3, l), b2g + lb, h2, N);
        // 6) fused 4-GEMM tail -> zb
        k_gemm_fused<<<ggSK, B, 0, stream>>>(hmid, hcur, rootm, h2, node_ids, vf,
                WB(1, l), WB(4, l), WB(5, l), WB(6, l), cb + lb, zb, SK);
        ushort_t* tmp = hcur; hcur = zb; zb = tmp;
    }

    // final: node_embs = seg_mean(hcur); out = sorted-group sum (no atomics)
    k_segmean3<<<gwN, B, 0, stream>>>(hcur, startN, slotN, nmean, N);
    k_pool2<<<G, B, 0, stream>>>(nmean, gs, (float*)d_out);
}

// Round 10
// 822.952 us; speedup vs baseline: 1.2224x; 1.0580x over previous
//
#include <hip/hip_runtime.h>

typedef unsigned short ushort_t;
typedef unsigned int uint_t;
typedef __attribute__((ext_vector_type(8))) short v8s;   // 8 bf16 MFMA A/B frag
typedef __attribute__((ext_vector_type(4))) float v4f;   // MFMA C/D frag
typedef __attribute__((ext_vector_type(2))) float v2f;   // packed f32 pair

#define HD 128
#define MFMA16(a, b, c) __builtin_amdgcn_mfma_f32_16x16x32_bf16((a), (b), (c), 0, 0, 0)

__device__ __forceinline__ float b2f(ushort_t u) {
    union { uint_t i; float f; } v; v.i = ((uint_t)u) << 16; return v.f;
}
__device__ __forceinline__ ushort_t f2b(float f) {
    union { float f; uint_t i; } v; v.f = f;
    uint_t u = v.i;
    return (ushort_t)((u + 0x7FFFu + ((u >> 16) & 1u)) >> 16);
}
__device__ __forceinline__ v2f b2f2(uint_t u) {
    union { uint_t i; float f; } lo, hi;
    lo.i = u << 16; hi.i = u & 0xFFFF0000u;
    v2f r; r.x = lo.f; r.y = hi.f; return r;
}

// ================= CSR build =================

__global__ __launch_bounds__(256) void k_hist(const int* __restrict__ ids,
        int* __restrict__ deg, int M, int stride) {
    int i = blockIdx.x * blockDim.x + threadIdx.x;
    if (i >= M) return;
    int id = ids[(size_t)i * stride];
    if (id >= 0) atomicAdd(&deg[id], 1);
}

__device__ __forceinline__ void scan_map(int b, int T0, int TN, int& a, int& t) {
    if (b < T0) { a = 0; t = b; }
    else { int r = b - T0; a = 1 + r / TN; t = r % TN; }
}

__global__ __launch_bounds__(1024) void k_scan_up(
        const int* d0, const int* d1, const int* d2, const int* d3,
        int* s0, int* s1, int* s2, int* s3,
        int* __restrict__ tsum, int T0, int TN, int nSK, int nN) {
    int a, t;
    scan_map(blockIdx.x, T0, TN, a, t);
    const int* d = (a == 0) ? d0 : (a == 1) ? d1 : (a == 2) ? d2 : d3;
    int* s = (a == 0) ? s0 : (a == 1) ? s1 : (a == 2) ? s2 : s3;
    int n = (a == 0) ? nSK : nN;
    __shared__ int wsum[16];
    int tdx = threadIdx.x, lane = tdx & 63, wv = tdx >> 6;
    int i = t * 1024 + tdx;
    int v = (i < n) ? d[i] : 0;
    int x = v;
    #pragma unroll
    for (int off = 1; off < 64; off <<= 1) {
        int y = __shfl_up(x, off);
        if (lane >= off) x += y;
    }
    if (lane == 63) wsum[wv] = x;
    __syncthreads();
    int wo = 0, tot = 0;
    #pragma unroll
    for (int ww = 0; ww < 16; ++ww) {
        int sv = wsum[ww];
        if (ww < wv) wo += sv;
        tot += sv;
    }
    if (i < n) s[i] = wo + (x - v);
    if (tdx == 0) tsum[a * 128 + t] = tot;
}

__global__ __launch_bounds__(256) void k_scan_mid(
        const int* __restrict__ tsum, int* __restrict__ toff,
        int* s0, int* s1, int* s2, int* s3, int T0, int TN, int nSK, int nN) {
    int a = threadIdx.x >> 6, lane = threadIdx.x & 63;
    int T = (a == 0) ? T0 : TN;
    const int* ts = tsum + a * 128;
    int* to = toff + a * 128;
    int carry = 0;
    for (int base = 0; base < T; base += 64) {
        int idx = base + lane;
        int v = (idx < T) ? ts[idx] : 0;
        int x = v;
        #pragma unroll
        for (int off = 1; off < 64; off <<= 1) {
            int y = __shfl_up(x, off);
            if (lane >= off) x += y;
        }
        if (idx < T) to[idx] = carry + (x - v);
        carry += __shfl(x, 63);
    }
    if (lane == 0) {
        int* s = (a == 0) ? s0 : (a == 1) ? s1 : (a == 2) ? s2 : s3;
        s[(a == 0) ? nSK : nN] = carry;
    }
}

__global__ __launch_bounds__(1024) void k_scan_down(
        int* s0, int* s1, int* s2, int* s3,
        const int* __restrict__ toff, int T0, int TN, int nSK, int nN) {
    int a, t;
    scan_map(blockIdx.x, T0, TN, a, t);
    int* s = (a == 0) ? s0 : (a == 1) ? s1 : (a == 2) ? s2 : s3;
    int n = (a == 0) ? nSK : nN;
    int i = t * 1024 + threadIdx.x;
    if (i < n) s[i] += toff[a * 128 + t];
}

__global__ __launch_bounds__(256) void k_fill(const int* __restrict__ ids,
        const int* __restrict__ start, int* __restrict__ cursor,
        int* __restrict__ slots, int M, int stride) {
    int i = blockIdx.x * blockDim.x + threadIdx.x;
    if (i >= M) return;
    int id = ids[(size_t)i * stride];
    if (id < 0) return;
    int pos = start[id] + atomicAdd(&cursor[id], 1);
    slots[pos] = i * stride;
}

__global__ __launch_bounds__(256) void k_fill_edges(const int* __restrict__ dst,
        const int* __restrict__ src, const int* __restrict__ bids,
        const int* __restrict__ start, int* __restrict__ cursor,
        int* __restrict__ slots, int E) {
    int e = blockIdx.x * blockDim.x + threadIdx.x;
    if (e >= E) return;
    int d = dst[e];
    if (d < 0) return;
    int pos = start[d] + atomicAdd(&cursor[d], 1);
    slots[pos] = src[e] | (bids[e] << 20);
}

__global__ __launch_bounds__(256) void k_gstart(const int* __restrict__ batch,
        int* __restrict__ gs, int N, int G) {
    int n = blockIdx.x * blockDim.x + threadIdx.x;
    if (n > N) return;
    int bn = (n < N) ? batch[n] : G;
    int bp = (n == 0) ? -1 : batch[n - 1];
    for (int g = bp + 1; g <= bn; ++g)
        if (g <= G) gs[g] = n;
}

// ================= weight/bias prep =================

__global__ __launch_bounds__(256) void k_convert_w(
        const float* lW1, const float* lW2, const float* gW1, const float* gW2,
        const float* skipW, const float* vvW, const float* kkW,
        const float* lbn_g, const float* gbn_g,
        ushort_t* __restrict__ wbuf, int L) {
    int idx = blockIdx.x * blockDim.x + threadIdx.x;
    int total = 7 * L * 16384;
    if (idx >= total) return;
    int fam = idx / (L * 16384);
    int r = idx % (L * 16384);
    int l = r / 16384, e = r % 16384, n = e / 128;
    const float* src;
    float sc = 1.0f;
    switch (fam) {
        case 0: src = lW1; break;
        case 1: src = lW2; sc = lbn_g[l * 128 + n]; break;
        case 2: src = gW1; break;
        case 3: src = gW2; sc = gbn_g[l * 128 + n]; break;
        case 4: src = skipW; break;
        case 5: src = vvW; break;
        default: src = kkW; break;
    }
    wbuf[idx] = f2b(src[(size_t)l * 16384 + e] * sc);
}

__global__ __launch_bounds__(256) void k_bias(
        const float* lb2, const float* lbn_g, const float* lbn_b,
        const float* skipb, const float* vvb, const float* kkb,
        const float* gb2, const float* gbn_g, const float* gbn_b,
        float* __restrict__ cb, float* __restrict__ b2g, int total) {
    int i = blockIdx.x * blockDim.x + threadIdx.x;
    if (i >= total) return;
    cb[i] = lb2[i] * lbn_g[i] + lbn_b[i] + skipb[i] + vvb[i] + kkb[i];
    b2g[i] = gb2[i] * gbn_g[i] + gbn_b[i];
}

// ================= elementwise =================

__global__ __launch_bounds__(256) void k_vf(const int* __restrict__ node_ids,
        float* __restrict__ vf, int SK) {
    int i = blockIdx.x * blockDim.x + threadIdx.x;
    if (i < SK) vf[i] = (node_ids[i] >= 0) ? 1.0f : 0.0f;
}

__global__ __launch_bounds__(256) void k_init_h(const float* __restrict__ at,
        const float* __restrict__ rt, const int* __restrict__ atom_ids,
        const float* __restrict__ vf, ushort_t* __restrict__ h, int SK) {
    int t = blockIdx.x * blockDim.x + threadIdx.x;
    int i = t >> 6, lane = t & 63;
    if (i >= SK) return;
    float2 a = ((const float2*)(at + (size_t)atom_ids[i] * HD))[lane];
    int role = ((i & 15) == 0) ? 1 : 0;
    float2 r = ((const float2*)(rt + (size_t)role * HD))[lane];
    float m = vf[i];
    uint_t o = (uint_t)f2b((a.x + r.x) * m) | ((uint_t)f2b((a.y + r.y) * m) << 16);
    *(uint_t*)(h + (size_t)i * HD + lane * 2) = o;
}

// ---- R2 champion scalar-walk gather (unchanged) ----

#define HE(i) int e##i = slots[p + i];
#define HX(i) uint_t u##i = *(const uint_t*)(Xb + (((uint_t)(e##i & 0xFFFFF)) << 8) + xo);
#define HQ(i) float2 q##i = *(const float2*)(Bb + (((uint_t)e##i >> 20) << 9) + bo);
#define HA(i) { v2f qv; qv.x = q##i.x; qv.y = q##i.y; \
                a += __builtin_elementwise_max(b2f2(u##i) + qv, z); }

__device__ __forceinline__ void gine_tail(const char* __restrict__ Xb,
        const char* __restrict__ Bb, const int* __restrict__ slots,
        int p, int s1, v2f& a, uint_t xo, uint_t bo) {
    const v2f z = {0.f, 0.f};
    for (; p + 7 < s1; p += 8) {
        HE(0) HE(1) HE(2) HE(3) HE(4) HE(5) HE(6) HE(7)
        HX(0) HX(1) HX(2) HX(3) HX(4) HX(5) HX(6) HX(7)
        HQ(0) HQ(1) HQ(2) HQ(3) HQ(4) HQ(5) HQ(6) HQ(7)
        HA(0) HA(1) HA(2) HA(3) HA(4) HA(5) HA(6) HA(7)
    }
    if (p + 3 < s1) {
        HE(0) HE(1) HE(2) HE(3)
        HX(0) HX(1) HX(2) HX(3)
        HQ(0) HQ(1) HQ(2) HQ(3)
        HA(0) HA(1) HA(2) HA(3)
        p += 4;
    }
    if (p + 1 < s1) {
        HE(0) HE(1)
        HX(0) HX(1)
        HQ(0) HQ(1)
        HA(0) HA(1)
        p += 2;
    }
    if (p < s1) {
        HE(0)
        HX(0)
        HQ(0)
        HA(0)
    }
}

__device__ __forceinline__ void gine_finish(const char* __restrict__ Xb,
        int row, v2f a, ushort_t* __restrict__ outz, uint_t xo) {
    uint_t su = *(const uint_t*)(Xb + (((uint_t)row) << 8) + xo);
    v2f sv = b2f2(su);
    float f0 = a.x + sv.x, f1 = a.y + sv.y;
    *(uint_t*)((char*)outz + (((uint_t)row) << 8) + xo) =
        (uint_t)f2b(f0) | ((uint_t)f2b(f1) << 16);
}

__device__ __forceinline__ void gine_row_s(const char* __restrict__ Xb,
        const char* __restrict__ Bb, const int* __restrict__ slots,
        int s0, int s1, int row, ushort_t* __restrict__ outz, uint_t xo, uint_t bo) {
    v2f a = {0.f, 0.f};
    gine_tail(Xb, Bb, slots, s0, s1, a, xo, bo);
    gine_finish(Xb, row, a, outz, xo);
}

// deg~16 variant: 16-edge leading block keeps 16 X-chains in flight per round
__device__ __forceinline__ void gine_row_s16(const char* __restrict__ Xb,
        const char* __restrict__ Bb, const int* __restrict__ slots,
        int s0, int s1, int row, ushort_t* __restrict__ outz, uint_t xo, uint_t bo) {
    const v2f z = {0.f, 0.f};
    v2f a = z;
    int p = s0;
    for (; p + 15 < s1; p += 16) {
        HE(0) HE(1) HE(2) HE(3) HE(4) HE(5) HE(6) HE(7)
        HE(8) HE(9) HE(10) HE(11) HE(12) HE(13) HE(14) HE(15)
        HX(0) HX(1) HX(2) HX(3) HX(4) HX(5) HX(6) HX(7)
        HX(8) HX(9) HX(10) HX(11) HX(12) HX(13) HX(14) HX(15)
        HQ(0) HQ(1) HQ(2) HQ(3) HQ(4) HQ(5) HQ(6) HQ(7)
        HA(0) HA(1) HA(2) HA(3) HA(4) HA(5) HA(6) HA(7)
        HQ(8) HQ(9) HQ(10) HQ(11) HQ(12) HQ(13) HQ(14) HQ(15)
        HA(8) HA(9) HA(10) HA(11) HA(12) HA(13) HA(14) HA(15)
    }
    gine_tail(Xb, Bb, slots, p, s1, a, xo, bo);
    gine_finish(Xb, row, a, outz, xo);
}

#define SE(i) int r##i = slots[p + i];
#define SX(i) uint_t u##i = *(const uint_t*)(Xb + (((uint_t)r##i) << 8) + xo);
#define SA(i) a += b2f2(u##i);

__device__ __forceinline__ void segmean_row_s(const char* __restrict__ Xb,
        const int* __restrict__ slots, int s0, int s1, int row,
        ushort_t* __restrict__ out, uint_t xo) {
    float inv = 1.0f / fmaxf((float)(s1 - s0), 1.0f);
    const v2f z = {0.f, 0.f};
    v2f a = z;
    int p = s0;
    for (; p + 7 < s1; p += 8) {
        SE(0) SE(1) SE(2) SE(3) SE(4) SE(5) SE(6) SE(7)
        SX(0) SX(1) SX(2) SX(3) SX(4) SX(5) SX(6) SX(7)
        SA(0) SA(1) SA(2) SA(3) SA(4) SA(5) SA(6) SA(7)
    }
    if (p + 3 < s1) {
        SE(0) SE(1) SE(2) SE(3)
        SX(0) SX(1) SX(2) SX(3)
        SA(0) SA(1) SA(2) SA(3)
        p += 4;
    }
    if (p + 1 < s1) {
        SE(0) SE(1)
        SX(0) SX(1)
        SA(0) SA(1)
        p += 2;
    }
    if (p < s1) {
        SE(0)
        SX(0)
        SA(0)
    }
    *(uint_t*)((char*)out + (((uint_t)row) << 8) + xo) =
        (uint_t)f2b(a.x * inv) | ((uint_t)f2b(a.y * inv) << 16);
}

// combined: waves [0,SK) intra-GINE; [SK,SK+N) node segmean; [SK+N,SK+2N) root segmean
__global__ __launch_bounds__(256) void k_gather_all3(const ushort_t* __restrict__ X,
        const float* __restrict__ btab,
        const int* __restrict__ startI, const int* __restrict__ slotI,
        ushort_t* __restrict__ outz, int SK,
        const int* __restrict__ startN, const int* __restrict__ slotN,
        ushort_t* __restrict__ nmean,
        const int* __restrict__ startR, const int* __restrict__ slotR,
        ushort_t* __restrict__ rootm, int N) {
    int w = __builtin_amdgcn_readfirstlane((blockIdx.x * 256 + threadIdx.x) >> 6);
    uint_t lane = threadIdx.x & 63;
    uint_t xo = lane * 4u, bo = lane * 8u;
    const char* Xb = (const char*)X;
    if (w < SK) {
        gine_row_s(Xb, (const char*)btab, slotI, startI[w], startI[w + 1], w,
                   outz, xo, bo);
    } else if (w < SK + N) {
        int r = w - SK;
        segmean_row_s(Xb, slotN, startN[r], startN[r + 1], r, nmean, xo);
    } else if (w < SK + 2 * N) {
        int r = w - SK - N;
        segmean_row_s(Xb, slotR, startR[r], startR[r + 1], r, rootm, xo);
    }
}

__global__ __launch_bounds__(256) void k_gine_z7(const ushort_t* __restrict__ X,
        const float* __restrict__ btab, const int* __restrict__ start,
        const int* __restrict__ slots, ushort_t* __restrict__ outz, int Nrows) {
    int w = __builtin_amdgcn_readfirstlane((blockIdx.x * 256 + threadIdx.x) >> 6);
    if (w >= Nrows) return;
    uint_t lane = threadIdx.x & 63;
    gine_row_s16((const char*)X, (const char*)btab, slots, start[w], start[w + 1],
                 w, outz, lane * 4u, lane * 8u);
}

__global__ __launch_bounds__(256) void k_segmean3(const ushort_t* __restrict__ X,
        const int* __restrict__ start, const int* __restrict__ slots,
        ushort_t* __restrict__ out, int Nrows) {
    int w = __builtin_amdgcn_readfirstlane((blockIdx.x * 256 + threadIdx.x) >> 6);
    if (w >= Nrows) return;
    uint_t lane = threadIdx.x & 63;
    segmean_row_s((const char*)X, slots, start[w], start[w + 1], w, out, lane * 4u);
}

// sorted-batch pool: one block per group, contiguous node range, no atomics
__global__ __launch_bounds__(256) void k_pool2(const ushort_t* __restrict__ xsum,
        const int* __restrict__ gs, float* __restrict__ out) {
    int g = blockIdx.x;
    int t = threadIdx.x, wv = t >> 6, lane = t & 63;
    int n0 = gs[g], n1 = gs[g + 1];
    float a0 = 0.f, a1 = 0.f;
    for (int n = n0 + wv; n < n1; n += 4) {
        uint_t u = *(const uint_t*)(xsum + (size_t)n * HD + lane * 2);
        a0 += b2f((ushort_t)(u & 0xFFFF));
        a1 += b2f((ushort_t)(u >> 16));
    }
    __shared__ float red[4][128];
    red[wv][lane * 2] = a0;
    red[wv][lane * 2 + 1] = a1;
    __syncthreads();
    if (wv == 0) {
        float s0 = red[0][lane * 2] + red[1][lane * 2]
                 + red[2][lane * 2] + red[3][lane * 2];
        float s1 = red[0][lane * 2 + 1] + red[1][lane * 2 + 1]
                 + red[2][lane * 2 + 1] + red[3][lane * 2 + 1];
        *(float2*)(out + (size_t)g * HD + lane * 2) = make_float2(s0, s1);
    }
}

// ---- stage one 128x128 bf16 weight into XOR-swizzled LDS ----
__device__ __forceinline__ void stage_w(ushort_t* Wl, const ushort_t* Wb, int t) {
    #pragma unroll
    for (int it = 0; it < 8; ++it) {
        int idx = it * 256 + t;
        uint4 v = *(const uint4*)(Wb + (size_t)idx * 8);
        int row = idx >> 4, u = idx & 15;
        *(uint4*)&Wl[row * 128 + ((u ^ (row & 7)) << 3)] = v;
    }
}

#define WREAD(nt, c) (*(const v8s*)&Wl[((nt) * 16 + m) * 128 + \
        ((((c) * 4 + quad) ^ msw) << 3)])

// ========== fused double GEMM: C = (relu(A@W1^T+b1)) @ W2^T + b2 ==========
__global__ __launch_bounds__(256) void k_gemm2(const ushort_t* __restrict__ A,
        const ushort_t* __restrict__ W1b, const float* __restrict__ b1,
        const ushort_t* __restrict__ W2b, const float* __restrict__ b2,
        ushort_t* __restrict__ C, int M) {
    __shared__ ushort_t Wl[128 * 128];
    const int t = threadIdx.x;
    stage_w(Wl, W1b, t);
    int lane = t & 63, wave = t >> 6;
    int m = lane & 15, quad = lane >> 4;
    int msw = m & 7;
    int row = blockIdx.x * 64 + wave * 16 + m;
    int ar = row < M ? row : M - 1;
    const v8s* Ar = (const v8s*)(A + (size_t)ar * HD);
    v8s bfrag[4];
    #pragma unroll
    for (int c = 0; c < 4; ++c) bfrag[c] = Ar[c * 4 + quad];
    __syncthreads();
    v4f acc[8];
    #pragma unroll
    for (int nt = 0; nt < 8; ++nt) acc[nt] = (v4f){0.f, 0.f, 0.f, 0.f};
    #pragma unroll
    for (int nt = 0; nt < 8; ++nt) {
        #pragma unroll
        for (int c = 0; c < 4; ++c)
            acc[nt] = MFMA16(WREAD(nt, c), bfrag[c], acc[nt]);
    }
    __syncthreads();                       // all waves done reading W1
    // write nmid = relu(acc+b1) as bf16 into Wl rows [wave*16+m], swizzled
    int lrow = wave * 16 + m;
    #pragma unroll
    for (int nt = 0; nt < 8; ++nt) {
        int col = nt * 16 + quad * 4;
        float4 b = *(const float4*)(b1 + col);
        float v0 = fmaxf(acc[nt][0] + b.x, 0.f);
        float v1 = fmaxf(acc[nt][1] + b.y, 0.f);
        float v2 = fmaxf(acc[nt][2] + b.z, 0.f);
        float v3 = fmaxf(acc[nt][3] + b.w, 0.f);
        uint2 o;
        o.x = (uint_t)f2b(v0) | ((uint_t)f2b(v1) << 16);
        o.y = (uint_t)f2b(v2) | ((uint_t)f2b(v3) << 16);
        *(uint2*)&Wl[lrow * 128 + (((2 * nt + (quad >> 1)) ^ msw) << 3)
                     + ((quad & 1) << 2)] = o;
    }
    // intra-wave read-back of own rows (same swizzle)
    v8s bfrag2[4];
    #pragma unroll
    for (int c = 0; c < 4; ++c)
        bfrag2[c] = *(const v8s*)&Wl[lrow * 128 + (((c * 4 + quad) ^ msw) << 3)];
    __syncthreads();                       // all waves read nmid before W2 overwrites
    stage_w(Wl, W2b, t);
    #pragma unroll
    for (int nt = 0; nt < 8; ++nt) acc[nt] = (v4f){0.f, 0.f, 0.f, 0.f};
    __syncthreads();
    #pragma unroll
    for (int nt = 0; nt < 8; ++nt) {
        #pragma unroll
        for (int c = 0; c < 4; ++c)
            acc[nt] = MFMA16(WREAD(nt, c), bfrag2[c], acc[nt]);
    }
    if (row < M) {
        ushort_t* Cr = C + (size_t)row * HD;
        #pragma unroll
        for (int nt = 0; nt < 8; ++nt) {
            int col = nt * 16 + quad * 4;
            float4 b = *(const float4*)(b2 + col);
            float v0 = acc[nt][0] + b.x, v1 = acc[nt][1] + b.y;
            float v2 = acc[nt][2] + b.z, v3 = acc[nt][3] + b.w;
            uint2 o;
            o.x = (uint_t)f2b(v0) | ((uint_t)f2b(v1) << 16);
            o.y = (uint_t)f2b(v2) | ((uint_t)f2b(v3) << 16);
            *(uint2*)(Cr + col) = o;
        }
    }
}

// ================= R10 mega kernel: 5-phase fused layer tail =================
// hmid = relu(zb@lW1^T+lb1) computed IN-KERNEL (k_gemm2 trick at SK scale),
// then acc = hmid@W2g + h@Wsk + rootm@Wvv + h_root@Wkk; epilogue adds cb + h2,
// relu, *vf. Writes hout in-place over zb (each block reads its own rows in
// phase 0 before writing them last). Saves 65.6 MB/layer hmid round-trip.
__global__ __launch_bounds__(256) void k_gemm_mega(
        const ushort_t* __restrict__ zb, const ushort_t* __restrict__ h,
        const ushort_t* __restrict__ rootm, const ushort_t* __restrict__ h2,
        const int* __restrict__ node_ids, const float* __restrict__ vf,
        const ushort_t* __restrict__ W1l, const float* __restrict__ lb1,
        const ushort_t* __restrict__ W2g, const ushort_t* __restrict__ Wsk,
        const ushort_t* __restrict__ Wvv, const ushort_t* __restrict__ Wkk,
        const float* __restrict__ cb, ushort_t* __restrict__ hout, int M) {
    __shared__ ushort_t Wl[128 * 128];
    const int t = threadIdx.x;
    int lane = t & 63, wave = t >> 6;
    int m = lane & 15, quad = lane >> 4;
    int msw = m & 7;
    int row = blockIdx.x * 64 + wave * 16 + m;
    int nid = node_ids[row];
    int nc = nid > 0 ? nid : 0;
    int lrow = wave * 16 + m;
    v4f acc[8];

    // ---- phase 0: hmid = relu(zb@W1l + lb1), kept via swizzled-LDS round-trip
    stage_w(Wl, W1l, t);
    {
        const v8s* Ar = (const v8s*)(zb + (size_t)row * HD);
        v8s bfrag[4];
        #pragma unroll
        for (int c = 0; c < 4; ++c) bfrag[c] = Ar[c * 4 + quad];
        __syncthreads();
        #pragma unroll
        for (int nt = 0; nt < 8; ++nt) acc[nt] = (v4f){0.f, 0.f, 0.f, 0.f};
        #pragma unroll
        for (int nt = 0; nt < 8; ++nt) {
            #pragma unroll
            for (int c = 0; c < 4; ++c)
                acc[nt] = MFMA16(WREAD(nt, c), bfrag[c], acc[nt]);
        }
    }
    __syncthreads();                       // all waves done reading W1l
    #pragma unroll
    for (int nt = 0; nt < 8; ++nt) {
        int col = nt * 16 + quad * 4;
        float4 b = *(const float4*)(lb1 + col);
        float v0 = fmaxf(acc[nt][0] + b.x, 0.f);
        float v1 = fmaxf(acc[nt][1] + b.y, 0.f);
        float v2 = fmaxf(acc[nt][2] + b.z, 0.f);
        float v3 = fmaxf(acc[nt][3] + b.w, 0.f);
        uint2 o;
        o.x = (uint_t)f2b(v0) | ((uint_t)f2b(v1) << 16);
        o.y = (uint_t)f2b(v2) | ((uint_t)f2b(v3) << 16);
        *(uint2*)&Wl[lrow * 128 + (((2 * nt + (quad >> 1)) ^ msw) << 3)
                     + ((quad & 1) << 2)] = o;
    }
    v8s hfrag[4];                          // own-wave read-back (RAW same wave)
    #pragma unroll
    for (int c = 0; c < 4; ++c)
        hfrag[c] = *(const v8s*)&Wl[lrow * 128 + (((c * 4 + quad) ^ msw) << 3)];
    __syncthreads();                       // all read-backs done before overwrite

    // ---- phases 1-4: accumulate 4 GEMMs
    const ushort_t* Ws[4] = {W2g, Wsk, Wvv, Wkk};
    const ushort_t* Asrc[4];
    Asrc[0] = nullptr;                     // hfrag (in registers)
    Asrc[1] = h + (size_t)row * HD;
    Asrc[2] = rootm + (size_t)nc * HD;
    Asrc[3] = h + (size_t)(row & ~15) * HD;
    #pragma unroll
    for (int nt = 0; nt < 8; ++nt) acc[nt] = (v4f){0.f, 0.f, 0.f, 0.f};
    for (int ph = 0; ph < 4; ++ph) {
        if (ph) __syncthreads();
        stage_w(Wl, Ws[ph], t);
        v8s bfrag[4];
        if (ph == 0) {
            #pragma unroll
            for (int c = 0; c < 4; ++c) bfrag[c] = hfrag[c];
        } else {
            const v8s* Ar = (const v8s*)Asrc[ph];
            #pragma unroll
            for (int c = 0; c < 4; ++c) bfrag[c] = Ar[c * 4 + quad];
        }
        __syncthreads();
        #pragma unroll
        for (int nt = 0; nt < 8; ++nt) {
            #pragma unroll
            for (int c = 0; c < 4; ++c)
                acc[nt] = MFMA16(WREAD(nt, c), bfrag[c], acc[nt]);
        }
    }

    // ---- epilogue
    float vfm = vf[row];
    const ushort_t* h2r = h2 + (size_t)nc * HD;
    ushort_t* Cr = hout + (size_t)row * HD;
    #pragma unroll
    for (int nt = 0; nt < 8; ++nt) {
        int col = nt * 16 + quad * 4;
        float4 b = *(const float4*)(cb + col);
        uint2 hh = *(const uint2*)(h2r + col);
        float v0 = acc[nt][0] + b.x + b2f((ushort_t)(hh.x & 0xFFFF));
        float v1 = acc[nt][1] + b.y + b2f((ushort_t)(hh.x >> 16));
        float v2 = acc[nt][2] + b.z + b2f((ushort_t)(hh.y & 0xFFFF));
        float v3 = acc[nt][3] + b.w + b2f((ushort_t)(hh.y >> 16));
        v0 = fmaxf(v0, 0.f) * vfm; v1 = fmaxf(v1, 0.f) * vfm;
        v2 = fmaxf(v2, 0.f) * vfm; v3 = fmaxf(v3, 0.f) * vfm;
        uint2 o;
        o.x = (uint_t)f2b(v0) | ((uint_t)f2b(v1) << 16);
        o.y = (uint_t)f2b(v2) | ((uint_t)f2b(v3) << 16);
        *(uint2*)(Cr + col) = o;
    }
}

// ================= launcher =================

extern "C" void kernel_launch(void* const* d_in, const int* in_sizes, int n_in,
                              void* d_out, int out_size, void* d_ws, size_t ws_size,
                              hipStream_t stream) {
    (void)n_in; (void)ws_size;
    const float* atom_table = (const float*)d_in[0];
    const float* bond_table = (const float*)d_in[1];
    const float* role_table = (const float*)d_in[2];
    const float* lW1 = (const float*)d_in[3];
    const float* lb1 = (const float*)d_in[4];
    const float* lW2 = (const float*)d_in[5];
    const float* lb2 = (const float*)d_in[6];
    const float* gW1 = (const float*)d_in[7];
    const float* gb1 = (const float*)d_in[8];
    const float* gW2 = (const float*)d_in[9];
    const float* gb2 = (const float*)d_in[10];
    const float* lbn_g = (const float*)d_in[11];
    const float* lbn_b = (const float*)d_in[12];
    const float* gbn_g = (const float*)d_in[13];
    const float* gbn_b = (const float*)d_in[14];
    const float* skipW = (const float*)d_in[15];
    const float* skipb = (const float*)d_in[16];
    const float* vvW = (const float*)d_in[17];
    const float* vvb = (const float*)d_in[18];
    const float* kkW = (const float*)d_in[19];
    const float* kkb = (const float*)d_in[20];
    const int* atom_ids = (const int*)d_in[21];
    const int* bond_ids_intra = (const int*)d_in[22];
    const int* bond_ids_global = (const int*)d_in[23];
    const int* intra_ei = (const int*)d_in[24];
    const int* node_ids = (const int*)d_in[25];
    const int* edge_index = (const int*)d_in[26];
    const int* batch = (const int*)d_in[28];

    const int SK = in_sizes[21];
    const int EI = in_sizes[22];
    const int EG = in_sizes[23];
    const int N  = in_sizes[28];
    const int L  = in_sizes[4] / HD;
    const int S  = SK / 16;
    const int G  = out_size / HD;

    // ---- workspace layout ----
    ushort_t* us = (ushort_t*)d_ws;
    ushort_t* hA    = us;
    ushort_t* hB    = hA + (size_t)SK * HD;
    ushort_t* hmid  = hB + (size_t)SK * HD;   // (unused after R10; kept for layout)
    ushort_t* nmean = hmid + (size_t)SK * HD;
    ushort_t* nz    = nmean + (size_t)N * HD;
    ushort_t* nmid  = nz + (size_t)N * HD;
    ushort_t* h2    = nmid + (size_t)N * HD;
    ushort_t* rootm = h2 + (size_t)N * HD;
    ushort_t* wbuf  = rootm + (size_t)N * HD;
    float* fp = (float*)(wbuf + (size_t)7 * L * 16384);
    float* vf  = fp;
    float* cb  = vf + SK;
    float* b2g = cb + (size_t)L * 128;
    int* ip = (int*)(b2g + (size_t)L * 128);
    int* degI   = ip;
    int* degG   = degI + SK;
    int* degN   = degG + N;
    int* degR   = degN + N;
    int* startI = degR + N;
    int* startG = startI + SK + 1;
    int* startN = startG + N + 1;
    int* startR = startN + N + 1;
    int* slotI  = startR + N + 1;
    int* slotG  = slotI + EI;
    int* slotN  = slotG + EG;
    int* slotR  = slotN + SK;
    int* tsum   = slotR + S;        // 4*128
    int* toff   = tsum + 512;       // 4*128
    int* gs     = toff + 512;       // G+1

    const int B = 256;
    const int gwAll = ((SK + 2 * N) * 64 + B - 1) / B;
    const int gwN   = (N * 64 + B - 1) / B;
    const int ggSK  = (SK + 63) / 64;
    const int ggN   = (N + 63) / 64;
    const int* intra_src = intra_ei;
    const int* intra_dst = intra_ei + EI;
    const int* glob_src  = edge_index;
    const int* glob_dst  = edge_index + EG;

    // ---- weight/bias prep ----
    int wtot = 7 * L * 16384;
    k_convert_w<<<(wtot + B - 1) / B, B, 0, stream>>>(lW1, lW2, gW1, gW2, skipW,
            vvW, kkW, lbn_g, gbn_g, wbuf, L);
    k_bias<<<(L * 128 + B - 1) / B, B, 0, stream>>>(lb2, lbn_g, lbn_b, skipb, vvb,
            kkb, gb2, gbn_g, gbn_b, cb, b2g, L * 128);

    // ---- CSR build ----
    hipMemsetAsync(degI, 0, (size_t)(SK + 3 * N) * sizeof(int), stream);
    k_hist<<<(EI + B - 1) / B, B, 0, stream>>>(intra_dst, degI, EI, 1);
    k_hist<<<(EG + B - 1) / B, B, 0, stream>>>(glob_dst, degG, EG, 1);
    k_hist<<<(SK + B - 1) / B, B, 0, stream>>>(node_ids, degN, SK, 1);
    k_hist<<<(S + B - 1) / B, B, 0, stream>>>(node_ids, degR, S, 16);
    const int T0 = (SK + 1023) / 1024, TN = (N + 1023) / 1024;
    const int nsb = T0 + 3 * TN;
    k_scan_up<<<nsb, 1024, 0, stream>>>(degI, degG, degN, degR,
            startI, startG, startN, startR, tsum, T0, TN, SK, N);
    k_scan_mid<<<1, 256, 0, stream>>>(tsum, toff, startI, startG, startN, startR,
            T0, TN, SK, N);
    k_scan_down<<<nsb, 1024, 0, stream>>>(startI, startG, startN, startR,
            toff, T0, TN, SK, N);
    hipMemsetAsync(degI, 0, (size_t)(SK + 3 * N) * sizeof(int), stream);
    k_fill_edges<<<(EI + B - 1) / B, B, 0, stream>>>(intra_dst, intra_src,
            bond_ids_intra, startI, degI, slotI, EI);
    k_fill_edges<<<(EG + B - 1) / B, B, 0, stream>>>(glob_dst, glob_src,
            bond_ids_global, startG, degG, slotG, EG);
    k_fill<<<(SK + B - 1) / B, B, 0, stream>>>(node_ids, startN, degN, slotN, SK, 1);
    k_fill<<<(S + B - 1) / B, B, 0, stream>>>(node_ids, startR, degR, slotR, S, 16);
    k_gstart<<<(N + 1 + B - 1) / B, B, 0, stream>>>(batch, gs, N, G);

    // ---- init ----
    k_vf<<<(SK + B - 1) / B, B, 0, stream>>>(node_ids, vf, SK);
    k_init_h<<<(SK * 64 + B - 1) / B, B, 0, stream>>>(atom_table, role_table,
            atom_ids, vf, hA, SK);

    ushort_t* hcur = hA;
    ushort_t* zb   = hB;
    auto WB = [&](int fam, int l) { return wbuf + ((size_t)(fam * L + l)) * 16384; };

    for (int l = 0; l < L; ++l) {
        const size_t lb = (size_t)l * HD;
        // 1) combined: zb = hcur + intra agg; nmean = node segmean; rootm = root segmean
        k_gather_all3<<<gwAll, B, 0, stream>>>(hcur, bond_table,
                startI, slotI, zb, SK, startN, slotN, nmean,
                startR, slotR, rootm, N);
        // 2) nz = nmean + global-GINE agg (deg~16: 16-wide main block)
        k_gine_z7<<<gwN, B, 0, stream>>>(nmean, bond_table, startG, slotG, nz, N);
        // 3) h2 = relu(nz @ gW1^T + gb1) @ (gW2*gbn_g)^T + (gb2*gbn_g + gbn_b)
        k_gemm2<<<ggN, B, 0, stream>>>(nz, WB(2, l), gb1 + lb,
                WB(3, l), b2g + lb, h2, N);
        // 4) 5-phase mega: hmid in-kernel + 4-GEMM tail + epilogue -> zb (in place)
        k_gemm_mega<<<ggSK, B, 0, stream>>>(zb, hcur, rootm, h2, node_ids, vf,
                WB(0, l), lb1 + lb, WB(1, l), WB(4, l), WB(5, l), WB(6, l),
                cb + lb, zb, SK);
        ushort_t* tmp = hcur; hcur = zb; zb = tmp;
    }

    // final: node_embs = seg_mean(hcur); out = sorted-group sum (no atomics)
    k_segmean3<<<gwN, B, 0, stream>>>(hcur, startN, slotN, nmean, N);
    k_pool2<<<G, B, 0, stream>>>(nmean, gs, (float*)d_out);
}

// Round 11
// 820.829 us; speedup vs baseline: 1.2256x; 1.0026x over previous
//
#include <hip/hip_runtime.h>

typedef unsigned short ushort_t;
typedef unsigned int uint_t;
typedef __attribute__((ext_vector_type(8))) short v8s;   // 8 bf16 MFMA A/B frag
typedef __attribute__((ext_vector_type(4))) float v4f;   // MFMA C/D frag
typedef __attribute__((ext_vector_type(2))) float v2f;   // packed f32 pair

#define HD 128
#define MFMA16(a, b, c) __builtin_amdgcn_mfma_f32_16x16x32_bf16((a), (b), (c), 0, 0, 0)

__device__ __forceinline__ float b2f(ushort_t u) {
    union { uint_t i; float f; } v; v.i = ((uint_t)u) << 16; return v.f;
}
__device__ __forceinline__ ushort_t f2b(float f) {
    union { float f; uint_t i; } v; v.f = f;
    uint_t u = v.i;
    return (ushort_t)((u + 0x7FFFu + ((u >> 16) & 1u)) >> 16);
}
__device__ __forceinline__ v2f b2f2(uint_t u) {
    union { uint_t i; float f; } lo, hi;
    lo.i = u << 16; hi.i = u & 0xFFFF0000u;
    v2f r; r.x = lo.f; r.y = hi.f; return r;
}

// ================= CSR build (R11: 4-wide batched, single-atomic fill) =====

__global__ __launch_bounds__(256) void k_hist(const int* __restrict__ ids,
        int* __restrict__ deg, int M, int stride) {
    int t = blockIdx.x * 1024 + threadIdx.x;
    int i0 = t, i1 = t + 256, i2 = t + 512, i3 = t + 768;
    int d0 = (i0 < M) ? ids[(size_t)i0 * stride] : -1;
    int d1 = (i1 < M) ? ids[(size_t)i1 * stride] : -1;
    int d2 = (i2 < M) ? ids[(size_t)i2 * stride] : -1;
    int d3 = (i3 < M) ? ids[(size_t)i3 * stride] : -1;
    if (d0 >= 0) atomicAdd(&deg[d0], 1);
    if (d1 >= 0) atomicAdd(&deg[d1], 1);
    if (d2 >= 0) atomicAdd(&deg[d2], 1);
    if (d3 >= 0) atomicAdd(&deg[d3], 1);
}

__device__ __forceinline__ void scan_map(int b, int T0, int TN, int& a, int& t) {
    if (b < T0) { a = 0; t = b; }
    else { int r = b - T0; a = 1 + r / TN; t = r % TN; }
}

__global__ __launch_bounds__(1024) void k_scan_up(
        const int* d0, const int* d1, const int* d2, const int* d3,
        int* s0, int* s1, int* s2, int* s3,
        int* __restrict__ tsum, int T0, int TN, int nSK, int nN) {
    int a, t;
    scan_map(blockIdx.x, T0, TN, a, t);
    const int* d = (a == 0) ? d0 : (a == 1) ? d1 : (a == 2) ? d2 : d3;
    int* s = (a == 0) ? s0 : (a == 1) ? s1 : (a == 2) ? s2 : s3;
    int n = (a == 0) ? nSK : nN;
    __shared__ int wsum[16];
    int tdx = threadIdx.x, lane = tdx & 63, wv = tdx >> 6;
    int i = t * 1024 + tdx;
    int v = (i < n) ? d[i] : 0;
    int x = v;
    #pragma unroll
    for (int off = 1; off < 64; off <<= 1) {
        int y = __shfl_up(x, off);
        if (lane >= off) x += y;
    }
    if (lane == 63) wsum[wv] = x;
    __syncthreads();
    int wo = 0, tot = 0;
    #pragma unroll
    for (int ww = 0; ww < 16; ++ww) {
        int sv = wsum[ww];
        if (ww < wv) wo += sv;
        tot += sv;
    }
    if (i < n) s[i] = wo + (x - v);
    if (tdx == 0) tsum[a * 128 + t] = tot;
}

__global__ __launch_bounds__(256) void k_scan_mid(
        const int* __restrict__ tsum, int* __restrict__ toff,
        int* s0, int* s1, int* s2, int* s3, int T0, int TN, int nSK, int nN) {
    int a = threadIdx.x >> 6, lane = threadIdx.x & 63;
    int T = (a == 0) ? T0 : TN;
    const int* ts = tsum + a * 128;
    int* to = toff + a * 128;
    int carry = 0;
    for (int base = 0; base < T; base += 64) {
        int idx = base + lane;
        int v = (idx < T) ? ts[idx] : 0;
        int x = v;
        #pragma unroll
        for (int off = 1; off < 64; off <<= 1) {
            int y = __shfl_up(x, off);
            if (lane >= off) x += y;
        }
        if (idx < T) to[idx] = carry + (x - v);
        carry += __shfl(x, 63);
    }
    if (lane == 0) {
        int* s = (a == 0) ? s0 : (a == 1) ? s1 : (a == 2) ? s2 : s3;
        s[(a == 0) ? nSK : nN] = carry;
    }
}

__global__ __launch_bounds__(1024) void k_scan_down(
        int* s0, int* s1, int* s2, int* s3,
        const int* __restrict__ toff, int T0, int TN, int nSK, int nN) {
    int a, t;
    scan_map(blockIdx.x, T0, TN, a, t);
    int* s = (a == 0) ? s0 : (a == 1) ? s1 : (a == 2) ? s2 : s3;
    int n = (a == 0) ? nSK : nN;
    int i = t * 1024 + threadIdx.x;
    if (i < n) s[i] += toff[a * 128 + t];
}

// cursor[i] = start value for the matching array (deg block reused as cursors)
__global__ __launch_bounds__(256) void k_copy_cur(int* __restrict__ cur,
        const int* __restrict__ startI, const int* __restrict__ startG,
        const int* __restrict__ startN, const int* __restrict__ startR,
        int nSK, int nN) {
    int i = blockIdx.x * blockDim.x + threadIdx.x;
    int tot = nSK + 3 * nN;
    if (i >= tot) return;
    int v;
    if (i < nSK) v = startI[i];
    else if (i < nSK + nN) v = startG[i - nSK];
    else if (i < nSK + 2 * nN) v = startN[i - nSK - nN];
    else v = startR[i - nSK - 2 * nN];
    cur[i] = v;
}

// single-atomic fill: cursor preloaded with start; 4 edges/thread batched
__global__ __launch_bounds__(256) void k_fill(const int* __restrict__ ids,
        int* __restrict__ cursor, int* __restrict__ slots, int M, int stride) {
    int t = blockIdx.x * 1024 + threadIdx.x;
    int i0 = t, i1 = t + 256, i2 = t + 512, i3 = t + 768;
    int d0 = (i0 < M) ? ids[(size_t)i0 * stride] : -1;
    int d1 = (i1 < M) ? ids[(size_t)i1 * stride] : -1;
    int d2 = (i2 < M) ? ids[(size_t)i2 * stride] : -1;
    int d3 = (i3 < M) ? ids[(size_t)i3 * stride] : -1;
    int p0 = (d0 >= 0) ? atomicAdd(&cursor[d0], 1) : 0;
    int p1 = (d1 >= 0) ? atomicAdd(&cursor[d1], 1) : 0;
    int p2 = (d2 >= 0) ? atomicAdd(&cursor[d2], 1) : 0;
    int p3 = (d3 >= 0) ? atomicAdd(&cursor[d3], 1) : 0;
    if (d0 >= 0) slots[p0] = i0 * stride;
    if (d1 >= 0) slots[p1] = i1 * stride;
    if (d2 >= 0) slots[p2] = i2 * stride;
    if (d3 >= 0) slots[p3] = i3 * stride;
}

__global__ __launch_bounds__(256) void k_fill_edges(const int* __restrict__ dst,
        const int* __restrict__ src, const int* __restrict__ bids,
        int* __restrict__ cursor, int* __restrict__ slots, int E) {
    int t = blockIdx.x * 1024 + threadIdx.x;
    int e0 = t, e1 = t + 256, e2 = t + 512, e3 = t + 768;
    int d0 = (e0 < E) ? dst[e0] : -1;
    int d1 = (e1 < E) ? dst[e1] : -1;
    int d2 = (e2 < E) ? dst[e2] : -1;
    int d3 = (e3 < E) ? dst[e3] : -1;
    int s0 = (d0 >= 0) ? (src[e0] | (bids[e0] << 20)) : 0;
    int s1 = (d1 >= 0) ? (src[e1] | (bids[e1] << 20)) : 0;
    int s2 = (d2 >= 0) ? (src[e2] | (bids[e2] << 20)) : 0;
    int s3 = (d3 >= 0) ? (src[e3] | (bids[e3] << 20)) : 0;
    int p0 = (d0 >= 0) ? atomicAdd(&cursor[d0], 1) : 0;
    int p1 = (d1 >= 0) ? atomicAdd(&cursor[d1], 1) : 0;
    int p2 = (d2 >= 0) ? atomicAdd(&cursor[d2], 1) : 0;
    int p3 = (d3 >= 0) ? atomicAdd(&cursor[d3], 1) : 0;
    if (d0 >= 0) slots[p0] = s0;
    if (d1 >= 0) slots[p1] = s1;
    if (d2 >= 0) slots[p2] = s2;
    if (d3 >= 0) slots[p3] = s3;
}

__global__ __launch_bounds__(256) void k_gstart(const int* __restrict__ batch,
        int* __restrict__ gs, int N, int G) {
    int n = blockIdx.x * blockDim.x + threadIdx.x;
    if (n > N) return;
    int bn = (n < N) ? batch[n] : G;
    int bp = (n == 0) ? -1 : batch[n - 1];
    for (int g = bp + 1; g <= bn; ++g)
        if (g <= G) gs[g] = n;
}

// ================= weight/bias prep =================

__global__ __launch_bounds__(256) void k_convert_w(
        const float* lW1, const float* lW2, const float* gW1, const float* gW2,
        const float* skipW, const float* vvW, const float* kkW,
        const float* lbn_g, const float* gbn_g,
        ushort_t* __restrict__ wbuf, int L) {
    int idx = blockIdx.x * blockDim.x + threadIdx.x;
    int total = 7 * L * 16384;
    if (idx >= total) return;
    int fam = idx / (L * 16384);
    int r = idx % (L * 16384);
    int l = r / 16384, e = r % 16384, n = e / 128;
    const float* src;
    float sc = 1.0f;
    switch (fam) {
        case 0: src = lW1; break;
        case 1: src = lW2; sc = lbn_g[l * 128 + n]; break;
        case 2: src = gW1; break;
        case 3: src = gW2; sc = gbn_g[l * 128 + n]; break;
        case 4: src = skipW; break;
        case 5: src = vvW; break;
        default: src = kkW; break;
    }
    wbuf[idx] = f2b(src[(size_t)l * 16384 + e] * sc);
}

__global__ __launch_bounds__(256) void k_bias(
        const float* lb2, const float* lbn_g, const float* lbn_b,
        const float* skipb, const float* vvb, const float* kkb,
        const float* gb2, const float* gbn_g, const float* gbn_b,
        float* __restrict__ cb, float* __restrict__ b2g, int total) {
    int i = blockIdx.x * blockDim.x + threadIdx.x;
    if (i >= total) return;
    cb[i] = lb2[i] * lbn_g[i] + lbn_b[i] + skipb[i] + vvb[i] + kkb[i];
    b2g[i] = gb2[i] * gbn_g[i] + gbn_b[i];
}

// ================= elementwise =================

__global__ __launch_bounds__(256) void k_vf(const int* __restrict__ node_ids,
        float* __restrict__ vf, int SK) {
    int i = blockIdx.x * blockDim.x + threadIdx.x;
    if (i < SK) vf[i] = (node_ids[i] >= 0) ? 1.0f : 0.0f;
}

__global__ __launch_bounds__(256) void k_init_h(const float* __restrict__ at,
        const float* __restrict__ rt, const int* __restrict__ atom_ids,
        const float* __restrict__ vf, ushort_t* __restrict__ h, int SK) {
    int t = blockIdx.x * blockDim.x + threadIdx.x;
    int i = t >> 6, lane = t & 63;
    if (i >= SK) return;
    float2 a = ((const float2*)(at + (size_t)atom_ids[i] * HD))[lane];
    int role = ((i & 15) == 0) ? 1 : 0;
    float2 r = ((const float2*)(rt + (size_t)role * HD))[lane];
    float m = vf[i];
    uint_t o = (uint_t)f2b((a.x + r.x) * m) | ((uint_t)f2b((a.y + r.y) * m) << 16);
    *(uint_t*)(h + (size_t)i * HD + lane * 2) = o;
}

// ---- R2 champion scalar-walk gather (unchanged) ----

#define HE(i) int e##i = slots[p + i];
#define HX(i) uint_t u##i = *(const uint_t*)(Xb + (((uint_t)(e##i & 0xFFFFF)) << 8) + xo);
#define HQ(i) float2 q##i = *(const float2*)(Bb + (((uint_t)e##i >> 20) << 9) + bo);
#define HA(i) { v2f qv; qv.x = q##i.x; qv.y = q##i.y; \
                a += __builtin_elementwise_max(b2f2(u##i) + qv, z); }

__device__ __forceinline__ void gine_tail(const char* __restrict__ Xb,
        const char* __restrict__ Bb, const int* __restrict__ slots,
        int p, int s1, v2f& a, uint_t xo, uint_t bo) {
    const v2f z = {0.f, 0.f};
    for (; p + 7 < s1; p += 8) {
        HE(0) HE(1) HE(2) HE(3) HE(4) HE(5) HE(6) HE(7)
        HX(0) HX(1) HX(2) HX(3) HX(4) HX(5) HX(6) HX(7)
        HQ(0) HQ(1) HQ(2) HQ(3) HQ(4) HQ(5) HQ(6) HQ(7)
        HA(0) HA(1) HA(2) HA(3) HA(4) HA(5) HA(6) HA(7)
    }
    if (p + 3 < s1) {
        HE(0) HE(1) HE(2) HE(3)
        HX(0) HX(1) HX(2) HX(3)
        HQ(0) HQ(1) HQ(2) HQ(3)
        HA(0) HA(1) HA(2) HA(3)
        p += 4;
    }
    if (p + 1 < s1) {
        HE(0) HE(1)
        HX(0) HX(1)
        HQ(0) HQ(1)
        HA(0) HA(1)
        p += 2;
    }
    if (p < s1) {
        HE(0)
        HX(0)
        HQ(0)
        HA(0)
    }
}

__device__ __forceinline__ void gine_finish(const char* __restrict__ Xb,
        int row, v2f a, ushort_t* __restrict__ outz, uint_t xo) {
    uint_t su = *(const uint_t*)(Xb + (((uint_t)row) << 8) + xo);
    v2f sv = b2f2(su);
    float f0 = a.x + sv.x, f1 = a.y + sv.y;
    *(uint_t*)((char*)outz + (((uint_t)row) << 8) + xo) =
        (uint_t)f2b(f0) | ((uint_t)f2b(f1) << 16);
}

__device__ __forceinline__ void gine_row_s(const char* __restrict__ Xb,
        const char* __restrict__ Bb, const int* __restrict__ slots,
        int s0, int s1, int row, ushort_t* __restrict__ outz, uint_t xo, uint_t bo) {
    v2f a = {0.f, 0.f};
    gine_tail(Xb, Bb, slots, s0, s1, a, xo, bo);
    gine_finish(Xb, row, a, outz, xo);
}

// deg~16 variant: 16-edge leading block keeps 16 X-chains in flight per round
__device__ __forceinline__ void gine_row_s16(const char* __restrict__ Xb,
        const char* __restrict__ Bb, const int* __restrict__ slots,
        int s0, int s1, int row, ushort_t* __restrict__ outz, uint_t xo, uint_t bo) {
    const v2f z = {0.f, 0.f};
    v2f a = z;
    int p = s0;
    for (; p + 15 < s1; p += 16) {
        HE(0) HE(1) HE(2) HE(3) HE(4) HE(5) HE(6) HE(7)
        HE(8) HE(9) HE(10) HE(11) HE(12) HE(13) HE(14) HE(15)
        HX(0) HX(1) HX(2) HX(3) HX(4) HX(5) HX(6) HX(7)
        HX(8) HX(9) HX(10) HX(11) HX(12) HX(13) HX(14) HX(15)
        HQ(0) HQ(1) HQ(2) HQ(3) HQ(4) HQ(5) HQ(6) HQ(7)
        HA(0) HA(1) HA(2) HA(3) HA(4) HA(5) HA(6) HA(7)
        HQ(8) HQ(9) HQ(10) HQ(11) HQ(12) HQ(13) HQ(14) HQ(15)
        HA(8) HA(9) HA(10) HA(11) HA(12) HA(13) HA(14) HA(15)
    }
    gine_tail(Xb, Bb, slots, p, s1, a, xo, bo);
    gine_finish(Xb, row, a, outz, xo);
}

#define SE(i) int r##i = slots[p + i];
#define SX(i) uint_t u##i = *(const uint_t*)(Xb + (((uint_t)r##i) << 8) + xo);
#define SA(i) a += b2f2(u##i);

__device__ __forceinline__ void segmean_row_s(const char* __restrict__ Xb,
        const int* __restrict__ slots, int s0, int s1, int row,
        ushort_t* __restrict__ out, uint_t xo) {
    float inv = 1.0f / fmaxf((float)(s1 - s0), 1.0f);
    const v2f z = {0.f, 0.f};
    v2f a = z;
    int p = s0;
    for (; p + 7 < s1; p += 8) {
        SE(0) SE(1) SE(2) SE(3) SE(4) SE(5) SE(6) SE(7)
        SX(0) SX(1) SX(2) SX(3) SX(4) SX(5) SX(6) SX(7)
        SA(0) SA(1) SA(2) SA(3) SA(4) SA(5) SA(6) SA(7)
    }
    if (p + 3 < s1) {
        SE(0) SE(1) SE(2) SE(3)
        SX(0) SX(1) SX(2) SX(3)
        SA(0) SA(1) SA(2) SA(3)
        p += 4;
    }
    if (p + 1 < s1) {
        SE(0) SE(1)
        SX(0) SX(1)
        SA(0) SA(1)
        p += 2;
    }
    if (p < s1) {
        SE(0)
        SX(0)
        SA(0)
    }
    *(uint_t*)((char*)out + (((uint_t)row) << 8) + xo) =
        (uint_t)f2b(a.x * inv) | ((uint_t)f2b(a.y * inv) << 16);
}

// combined: waves [0,SK) intra-GINE; [SK,SK+N) node segmean; [SK+N,SK+2N) root segmean
__global__ __launch_bounds__(256) void k_gather_all3(const ushort_t* __restrict__ X,
        const float* __restrict__ btab,
        const int* __restrict__ startI, const int* __restrict__ slotI,
        ushort_t* __restrict__ outz, int SK,
        const int* __restrict__ startN, const int* __restrict__ slotN,
        ushort_t* __restrict__ nmean,
        const int* __restrict__ startR, const int* __restrict__ slotR,
        ushort_t* __restrict__ rootm, int N) {
    int w = __builtin_amdgcn_readfirstlane((blockIdx.x * 256 + threadIdx.x) >> 6);
    uint_t lane = threadIdx.x & 63;
    uint_t xo = lane * 4u, bo = lane * 8u;
    const char* Xb = (const char*)X;
    if (w < SK) {
        gine_row_s(Xb, (const char*)btab, slotI, startI[w], startI[w + 1], w,
                   outz, xo, bo);
    } else if (w < SK + N) {
        int r = w - SK;
        segmean_row_s(Xb, slotN, startN[r], startN[r + 1], r, nmean, xo);
    } else if (w < SK + 2 * N) {
        int r = w - SK - N;
        segmean_row_s(Xb, slotR, startR[r], startR[r + 1], r, rootm, xo);
    }
}

__global__ __launch_bounds__(256) void k_gine_z7(const ushort_t* __restrict__ X,
        const float* __restrict__ btab, const int* __restrict__ start,
        const int* __restrict__ slots, ushort_t* __restrict__ outz, int Nrows) {
    int w = __builtin_amdgcn_readfirstlane((blockIdx.x * 256 + threadIdx.x) >> 6);
    if (w >= Nrows) return;
    uint_t lane = threadIdx.x & 63;
    gine_row_s16((const char*)X, (const char*)btab, slots, start[w], start[w + 1],
                 w, outz, lane * 4u, lane * 8u);
}

__global__ __launch_bounds__(256) void k_segmean3(const ushort_t* __restrict__ X,
        const int* __restrict__ start, const int* __restrict__ slots,
        ushort_t* __restrict__ out, int Nrows) {
    int w = __builtin_amdgcn_readfirstlane((blockIdx.x * 256 + threadIdx.x) >> 6);
    if (w >= Nrows) return;
    uint_t lane = threadIdx.x & 63;
    segmean_row_s((const char*)X, slots, start[w], start[w + 1], w, out, lane * 4u);
}

// sorted-batch pool: one block per group, contiguous node range, no atomics
__global__ __launch_bounds__(256) void k_pool2(const ushort_t* __restrict__ xsum,
        const int* __restrict__ gs, float* __restrict__ out) {
    int g = blockIdx.x;
    int t = threadIdx.x, wv = t >> 6, lane = t & 63;
    int n0 = gs[g], n1 = gs[g + 1];
    float a0 = 0.f, a1 = 0.f;
    for (int n = n0 + wv; n < n1; n += 4) {
        uint_t u = *(const uint_t*)(xsum + (size_t)n * HD + lane * 2);
        a0 += b2f((ushort_t)(u & 0xFFFF));
        a1 += b2f((ushort_t)(u >> 16));
    }
    __shared__ float red[4][128];
    red[wv][lane * 2] = a0;
    red[wv][lane * 2 + 1] = a1;
    __syncthreads();
    if (wv == 0) {
        float s0 = red[0][lane * 2] + red[1][lane * 2]
                 + red[2][lane * 2] + red[3][lane * 2];
        float s1 = red[0][lane * 2 + 1] + red[1][lane * 2 + 1]
                 + red[2][lane * 2 + 1] + red[3][lane * 2 + 1];
        *(float2*)(out + (size_t)g * HD + lane * 2) = make_float2(s0, s1);
    }
}

// ---- stage one 128x128 bf16 weight into XOR-swizzled LDS ----
__device__ __forceinline__ void stage_w(ushort_t* Wl, const ushort_t* Wb, int t) {
    #pragma unroll
    for (int it = 0; it < 8; ++it) {
        int idx = it * 256 + t;
        uint4 v = *(const uint4*)(Wb + (size_t)idx * 8);
        int row = idx >> 4, u = idx & 15;
        *(uint4*)&Wl[row * 128 + ((u ^ (row & 7)) << 3)] = v;
    }
}

#define WREAD(nt, c) (*(const v8s*)&Wl[((nt) * 16 + m) * 128 + \
        ((((c) * 4 + quad) ^ msw) << 3)])

// ========== fused double GEMM: C = (relu(A@W1^T+b1)) @ W2^T + b2 ==========
__global__ __launch_bounds__(256) void k_gemm2(const ushort_t* __restrict__ A,
        const ushort_t* __restrict__ W1b, const float* __restrict__ b1,
        const ushort_t* __restrict__ W2b, const float* __restrict__ b2,
        ushort_t* __restrict__ C, int M) {
    __shared__ ushort_t Wl[128 * 128];
    const int t = threadIdx.x;
    stage_w(Wl, W1b, t);
    int lane = t & 63, wave = t >> 6;
    int m = lane & 15, quad = lane >> 4;
    int msw = m & 7;
    int row = blockIdx.x * 64 + wave * 16 + m;
    int ar = row < M ? row : M - 1;
    const v8s* Ar = (const v8s*)(A + (size_t)ar * HD);
    v8s bfrag[4];
    #pragma unroll
    for (int c = 0; c < 4; ++c) bfrag[c] = Ar[c * 4 + quad];
    __syncthreads();
    v4f acc[8];
    #pragma unroll
    for (int nt = 0; nt < 8; ++nt) acc[nt] = (v4f){0.f, 0.f, 0.f, 0.f};
    #pragma unroll
    for (int nt = 0; nt < 8; ++nt) {
        #pragma unroll
        for (int c = 0; c < 4; ++c)
            acc[nt] = MFMA16(WREAD(nt, c), bfrag[c], acc[nt]);
    }
    __syncthreads();                       // all waves done reading W1
    int lrow = wave * 16 + m;
    #pragma unroll
    for (int nt = 0; nt < 8; ++nt) {
        int col = nt * 16 + quad * 4;
        float4 b = *(const float4*)(b1 + col);
        float v0 = fmaxf(acc[nt][0] + b.x, 0.f);
        float v1 = fmaxf(acc[nt][1] + b.y, 0.f);
        float v2 = fmaxf(acc[nt][2] + b.z, 0.f);
        float v3 = fmaxf(acc[nt][3] + b.w, 0.f);
        uint2 o;
        o.x = (uint_t)f2b(v0) | ((uint_t)f2b(v1) << 16);
        o.y = (uint_t)f2b(v2) | ((uint_t)f2b(v3) << 16);
        *(uint2*)&Wl[lrow * 128 + (((2 * nt + (quad >> 1)) ^ msw) << 3)
                     + ((quad & 1) << 2)] = o;
    }
    v8s bfrag2[4];
    #pragma unroll
    for (int c = 0; c < 4; ++c)
        bfrag2[c] = *(const v8s*)&Wl[lrow * 128 + (((c * 4 + quad) ^ msw) << 3)];
    __syncthreads();                       // all waves read nmid before W2 overwrites
    stage_w(Wl, W2b, t);
    #pragma unroll
    for (int nt = 0; nt < 8; ++nt) acc[nt] = (v4f){0.f, 0.f, 0.f, 0.f};
    __syncthreads();
    #pragma unroll
    for (int nt = 0; nt < 8; ++nt) {
        #pragma unroll
        for (int c = 0; c < 4; ++c)
            acc[nt] = MFMA16(WREAD(nt, c), bfrag2[c], acc[nt]);
    }
    if (row < M) {
        ushort_t* Cr = C + (size_t)row * HD;
        #pragma unroll
        for (int nt = 0; nt < 8; ++nt) {
            int col = nt * 16 + quad * 4;
            float4 b = *(const float4*)(b2 + col);
            float v0 = acc[nt][0] + b.x, v1 = acc[nt][1] + b.y;
            float v2 = acc[nt][2] + b.z, v3 = acc[nt][3] + b.w;
            uint2 o;
            o.x = (uint_t)f2b(v0) | ((uint_t)f2b(v1) << 16);
            o.y = (uint_t)f2b(v2) | ((uint_t)f2b(v3) << 16);
            *(uint2*)(Cr + col) = o;
        }
    }
}

// ================= R10 mega kernel: 5-phase fused layer tail =================
__global__ __launch_bounds__(256) void k_gemm_mega(
        const ushort_t* __restrict__ zb, const ushort_t* __restrict__ h,
        const ushort_t* __restrict__ rootm, const ushort_t* __restrict__ h2,
        const int* __restrict__ node_ids, const float* __restrict__ vf,
        const ushort_t* __restrict__ W1l, const float* __restrict__ lb1,
        const ushort_t* __restrict__ W2g, const ushort_t* __restrict__ Wsk,
        const ushort_t* __restrict__ Wvv, const ushort_t* __restrict__ Wkk,
        const float* __restrict__ cb, ushort_t* __restrict__ hout, int M) {
    __shared__ ushort_t Wl[128 * 128];
    const int t = threadIdx.x;
    int lane = t & 63, wave = t >> 6;
    int m = lane & 15, quad = lane >> 4;
    int msw = m & 7;
    int row = blockIdx.x * 64 + wave * 16 + m;
    int nid = node_ids[row];
    int nc = nid > 0 ? nid : 0;
    int lrow = wave * 16 + m;
    v4f acc[8];

    // ---- phase 0: hmid = relu(zb@W1l + lb1), kept via swizzled-LDS round-trip
    stage_w(Wl, W1l, t);
    {
        const v8s* Ar = (const v8s*)(zb + (size_t)row * HD);
        v8s bfrag[4];
        #pragma unroll
        for (int c = 0; c < 4; ++c) bfrag[c] = Ar[c * 4 + quad];
        __syncthreads();
        #pragma unroll
        for (int nt = 0; nt < 8; ++nt) acc[nt] = (v4f){0.f, 0.f, 0.f, 0.f};
        #pragma unroll
        for (int nt = 0; nt < 8; ++nt) {
            #pragma unroll
            for (int c = 0; c < 4; ++c)
                acc[nt] = MFMA16(WREAD(nt, c), bfrag[c], acc[nt]);
        }
    }
    __syncthreads();                       // all waves done reading W1l
    #pragma unroll
    for (int nt = 0; nt < 8; ++nt) {
        int col = nt * 16 + quad * 4;
        float4 b = *(const float4*)(lb1 + col);
        float v0 = fmaxf(acc[nt][0] + b.x, 0.f);
        float v1 = fmaxf(acc[nt][1] + b.y, 0.f);
        float v2 = fmaxf(acc[nt][2] + b.z, 0.f);
        float v3 = fmaxf(acc[nt][3] + b.w, 0.f);
        uint2 o;
        o.x = (uint_t)f2b(v0) | ((uint_t)f2b(v1) << 16);
        o.y = (uint_t)f2b(v2) | ((uint_t)f2b(v3) << 16);
        *(uint2*)&Wl[lrow * 128 + (((2 * nt + (quad >> 1)) ^ msw) << 3)
                     + ((quad & 1) << 2)] = o;
    }
    v8s hfrag[4];                          // own-wave read-back (RAW same wave)
    #pragma unroll
    for (int c = 0; c < 4; ++c)
        hfrag[c] = *(const v8s*)&Wl[lrow * 128 + (((c * 4 + quad) ^ msw) << 3)];
    __syncthreads();                       // all read-backs done before overwrite

    // ---- phases 1-4: accumulate 4 GEMMs
    const ushort_t* Ws[4] = {W2g, Wsk, Wvv, Wkk};
    const ushort_t* Asrc[4];
    Asrc[0] = nullptr;                     // hfrag (in registers)
    Asrc[1] = h + (size_t)row * HD;
    Asrc[2] = rootm + (size_t)nc * HD;
    Asrc[3] = h + (size_t)(row & ~15) * HD;
    #pragma unroll
    for (int nt = 0; nt < 8; ++nt) acc[nt] = (v4f){0.f, 0.f, 0.f, 0.f};
    for (int ph = 0; ph < 4; ++ph) {
        if (ph) __syncthreads();
        stage_w(Wl, Ws[ph], t);
        v8s bfrag[4];
        if (ph == 0) {
            #pragma unroll
            for (int c = 0; c < 4; ++c) bfrag[c] = hfrag[c];
        } else {
            const v8s* Ar = (const v8s*)Asrc[ph];
            #pragma unroll
            for (int c = 0; c < 4; ++c) bfrag[c] = Ar[c * 4 + quad];
        }
        __syncthreads();
        #pragma unroll
        for (int nt = 0; nt < 8; ++nt) {
            #pragma unroll
            for (int c = 0; c < 4; ++c)
                acc[nt] = MFMA16(WREAD(nt, c), bfrag[c], acc[nt]);
        }
    }

    // ---- epilogue
    float vfm = vf[row];
    const ushort_t* h2r = h2 + (size_t)nc * HD;
    ushort_t* Cr = hout + (size_t)row * HD;
    #pragma unroll
    for (int nt = 0; nt < 8; ++nt) {
        int col = nt * 16 + quad * 4;
        float4 b = *(const float4*)(cb + col);
        uint2 hh = *(const uint2*)(h2r + col);
        float v0 = acc[nt][0] + b.x + b2f((ushort_t)(hh.x & 0xFFFF));
        float v1 = acc[nt][1] + b.y + b2f((ushort_t)(hh.x >> 16));
        float v2 = acc[nt][2] + b.z + b2f((ushort_t)(hh.y & 0xFFFF));
        float v3 = acc[nt][3] + b.w + b2f((ushort_t)(hh.y >> 16));
        v0 = fmaxf(v0, 0.f) * vfm; v1 = fmaxf(v1, 0.f) * vfm;
        v2 = fmaxf(v2, 0.f) * vfm; v3 = fmaxf(v3, 0.f) * vfm;
        uint2 o;
        o.x = (uint_t)f2b(v0) | ((uint_t)f2b(v1) << 16);
        o.y = (uint_t)f2b(v2) | ((uint_t)f2b(v3) << 16);
        *(uint2*)(Cr + col) = o;
    }
}

// ================= launcher =================

extern "C" void kernel_launch(void* const* d_in, const int* in_sizes, int n_in,
                              void* d_out, int out_size, void* d_ws, size_t ws_size,
                              hipStream_t stream) {
    (void)n_in; (void)ws_size;
    const float* atom_table = (const float*)d_in[0];
    const float* bond_table = (const float*)d_in[1];
    const float* role_table = (const float*)d_in[2];
    const float* lW1 = (const float*)d_in[3];
    const float* lb1 = (const float*)d_in[4];
    const float* lW2 = (const float*)d_in[5];
    const float* lb2 = (const float*)d_in[6];
    const float* gW1 = (const float*)d_in[7];
    const float* gb1 = (const float*)d_in[8];
    const float* gW2 = (const float*)d_in[9];
    const float* gb2 = (const float*)d_in[10];
    const float* lbn_g = (const float*)d_in[11];
    const float* lbn_b = (const float*)d_in[12];
    const float* gbn_g = (const float*)d_in[13];
    const float* gbn_b = (const float*)d_in[14];
    const float* skipW = (const float*)d_in[15];
    const float* skipb = (const float*)d_in[16];
    const float* vvW = (const float*)d_in[17];
    const float* vvb = (const float*)d_in[18];
    const float* kkW = (const float*)d_in[19];
    const float* kkb = (const float*)d_in[20];
    const int* atom_ids = (const int*)d_in[21];
    const int* bond_ids_intra = (const int*)d_in[22];
    const int* bond_ids_global = (const int*)d_in[23];
    const int* intra_ei = (const int*)d_in[24];
    const int* node_ids = (const int*)d_in[25];
    const int* edge_index = (const int*)d_in[26];
    const int* batch = (const int*)d_in[28];

    const int SK = in_sizes[21];
    const int EI = in_sizes[22];
    const int EG = in_sizes[23];
    const int N  = in_sizes[28];
    const int L  = in_sizes[4] / HD;
    const int S  = SK / 16;
    const int G  = out_size / HD;

    // ---- workspace layout ----
    ushort_t* us = (ushort_t*)d_ws;
    ushort_t* hA    = us;
    ushort_t* hB    = hA + (size_t)SK * HD;
    ushort_t* hmid  = hB + (size_t)SK * HD;   // (unused after R10; kept for layout)
    ushort_t* nmean = hmid + (size_t)SK * HD;
    ushort_t* nz    = nmean + (size_t)N * HD;
    ushort_t* nmid  = nz + (size_t)N * HD;
    ushort_t* h2    = nmid + (size_t)N * HD;
    ushort_t* rootm = h2 + (size_t)N * HD;
    ushort_t* wbuf  = rootm + (size_t)N * HD;
    float* fp = (float*)(wbuf + (size_t)7 * L * 16384);
    float* vf  = fp;
    float* cb  = vf + SK;
    float* b2g = cb + (size_t)L * 128;
    int* ip = (int*)(b2g + (size_t)L * 128);
    int* degI   = ip;
    int* degG   = degI + SK;
    int* degN   = degG + N;
    int* degR   = degN + N;
    int* startI = degR + N;
    int* startG = startI + SK + 1;
    int* startN = startG + N + 1;
    int* startR = startN + N + 1;
    int* slotI  = startR + N + 1;
    int* slotG  = slotI + EI;
    int* slotN  = slotG + EG;
    int* slotR  = slotN + SK;
    int* tsum   = slotR + S;        // 4*128
    int* toff   = tsum + 512;       // 4*128
    int* gs     = toff + 512;       // G+1

    const int B = 256;
    const int gwAll = ((SK + 2 * N) * 64 + B - 1) / B;
    const int gwN   = (N * 64 + B - 1) / B;
    const int ggSK  = (SK + 63) / 64;
    const int ggN   = (N + 63) / 64;
    const int* intra_src = intra_ei;
    const int* intra_dst = intra_ei + EI;
    const int* glob_src  = edge_index;
    const int* glob_dst  = edge_index + EG;

    // ---- weight/bias prep ----
    int wtot = 7 * L * 16384;
    k_convert_w<<<(wtot + B - 1) / B, B, 0, stream>>>(lW1, lW2, gW1, gW2, skipW,
            vvW, kkW, lbn_g, gbn_g, wbuf, L);
    k_bias<<<(L * 128 + B - 1) / B, B, 0, stream>>>(lb2, lbn_g, lbn_b, skipb, vvb,
            kkb, gb2, gbn_g, gbn_b, cb, b2g, L * 128);

    // ---- CSR build (4-wide hist/fill, single-atomic fill) ----
    hipMemsetAsync(degI, 0, (size_t)(SK + 3 * N) * sizeof(int), stream);
    k_hist<<<(EI + 1023) / 1024, B, 0, stream>>>(intra_dst, degI, EI, 1);
    k_hist<<<(EG + 1023) / 1024, B, 0, stream>>>(glob_dst, degG, EG, 1);
    k_hist<<<(SK + 1023) / 1024, B, 0, stream>>>(node_ids, degN, SK, 1);
    k_hist<<<(S + 1023) / 1024, B, 0, stream>>>(node_ids, degR, S, 16);
    const int T0 = (SK + 1023) / 1024, TN = (N + 1023) / 1024;
    const int nsb = T0 + 3 * TN;
    k_scan_up<<<nsb, 1024, 0, stream>>>(degI, degG, degN, degR,
            startI, startG, startN, startR, tsum, T0, TN, SK, N);
    k_scan_mid<<<1, 256, 0, stream>>>(tsum, toff, startI, startG, startN, startR,
            T0, TN, SK, N);
    k_scan_down<<<nsb, 1024, 0, stream>>>(startI, startG, startN, startR,
            toff, T0, TN, SK, N);
    // cursors = start values (deg block reused); single atomic per element in fills
    k_copy_cur<<<(SK + 3 * N + B - 1) / B, B, 0, stream>>>(degI,
            startI, startG, startN, startR, SK, N);
    k_fill_edges<<<(EI + 1023) / 1024, B, 0, stream>>>(intra_dst, intra_src,
            bond_ids_intra, degI, slotI, EI);
    k_fill_edges<<<(EG + 1023) / 1024, B, 0, stream>>>(glob_dst, glob_src,
            bond_ids_global, degG, slotG, EG);
    k_fill<<<(SK + 1023) / 1024, B, 0, stream>>>(node_ids, degN, slotN, SK, 1);
    k_fill<<<(S + 1023) / 1024, B, 0, stream>>>(node_ids, degR, slotR, S, 16);
    k_gstart<<<(N + 1 + B - 1) / B, B, 0, stream>>>(batch, gs, N, G);

    // ---- init ----
    k_vf<<<(SK + B - 1) / B, B, 0, stream>>>(node_ids, vf, SK);
    k_init_h<<<(SK * 64 + B - 1) / B, B, 0, stream>>>(atom_table, role_table,
            atom_ids, vf, hA, SK);

    ushort_t* hcur = hA;
    ushort_t* zb   = hB;
    auto WB = [&](int fam, int l) { return wbuf + ((size_t)(fam * L + l)) * 16384; };

    for (int l = 0; l < L; ++l) {
        const size_t lb = (size_t)l * HD;
        // 1) combined: zb = hcur + intra agg; nmean = node segmean; rootm = root segmean
        k_gather_all3<<<gwAll, B, 0, stream>>>(hcur, bond_table,
                startI, slotI, zb, SK, startN, slotN, nmean,
                startR, slotR, rootm, N);
        // 2) nz = nmean + global-GINE agg (deg~16: 16-wide main block)
        k_gine_z7<<<gwN, B, 0, stream>>>(nmean, bond_table, startG, slotG, nz, N);
        // 3) h2 = relu(nz @ gW1^T + gb1) @ (gW2*gbn_g)^T + (gb2*gbn_g + gbn_b)
        k_gemm2<<<ggN, B, 0, stream>>>(nz, WB(2, l), gb1 + lb,
                WB(3, l), b2g + lb, h2, N);
        // 4) 5-phase mega: hmid in-kernel + 4-GEMM tail + epilogue -> zb (in place)
        k_gemm_mega<<<ggSK, B, 0, stream>>>(zb, hcur, rootm, h2, node_ids, vf,
                WB(0, l), lb1 + lb, WB(1, l), WB(4, l), WB(5, l), WB(6, l),
                cb + lb, zb, SK);
        ushort_t* tmp = hcur; hcur = zb; zb = tmp;
    }

    // final: node_embs = seg_mean(hcur); out = sorted-group sum (no atomics)
    k_segmean3<<<gwN, B, 0, stream>>>(hcur, startN, slotN, nmean, N);
    k_pool2<<<G, B, 0, stream>>>(nmean, gs, (float*)d_out);
}